// Round 2
// baseline (2999.185 us; speedup 1.0000x reference)
//
#include <hip/hip_runtime.h>
#include <math.h>

#define NN 50000
#define EE 400000
#define NE 450000          // EE + NN self loops
#define IN_F 128
#define NEG_SLOPE 0.2f
#define EPSV 1e-6f

typedef unsigned short bf16u;

__device__ __forceinline__ float bf2f(unsigned int u) {
    return __uint_as_float(u << 16);
}
__device__ __forceinline__ bf16u f2bf(float f) {
    unsigned int u = __float_as_uint(f);
    unsigned int r = (u + 0x7FFFu + ((u >> 16) & 1u)) >> 16;
    return (bf16u)r;
}

// ============================ CSR build ============================
__global__ void k_zero_i32(int* p, int n) {
    int i = blockIdx.x * 256 + threadIdx.x;
    if (i < n) p[i] = 0;
}

__global__ void k_deg(const int* __restrict__ ei, int* __restrict__ deg) {
    int i = blockIdx.x * 256 + threadIdx.x;
    if (i >= NE) return;
    int d = (i < EE) ? ei[EE + i] : (i - EE);
    atomicAdd(&deg[d], 1);
}

__global__ __launch_bounds__(256) void k_scan1(const int* __restrict__ deg,
                                               int* __restrict__ incl,
                                               int* __restrict__ bsums, int n) {
    __shared__ int sm[1024];
    int base = blockIdx.x * 1024;
    for (int i = threadIdx.x; i < 1024; i += 256)
        sm[i] = (base + i < n) ? deg[base + i] : 0;
    __syncthreads();
    for (int off = 1; off < 1024; off <<= 1) {
        int v[4];
#pragma unroll
        for (int j = 0; j < 4; j++) {
            int i = threadIdx.x + 256 * j;
            v[j] = (i >= off) ? sm[i - off] : 0;
        }
        __syncthreads();
#pragma unroll
        for (int j = 0; j < 4; j++) {
            int i = threadIdx.x + 256 * j;
            sm[i] += v[j];
        }
        __syncthreads();
    }
    for (int i = threadIdx.x; i < 1024; i += 256)
        if (base + i < n) incl[base + i] = sm[i];
    if (threadIdx.x == 0) bsums[blockIdx.x] = sm[1023];
}

__global__ void k_scan2(int* bsums, int nb) {
    if (threadIdx.x == 0 && blockIdx.x == 0) {
        int run = 0;
        for (int i = 0; i < nb; i++) { int v = bsums[i]; bsums[i] = run; run += v; }
    }
}

__global__ void k_scan3(const int* __restrict__ deg, int* __restrict__ rowptr,
                        int* __restrict__ cursor, const int* __restrict__ bsums,
                        int n, int ne) {
    int i = blockIdx.x * 256 + threadIdx.x;
    if (i < n) {
        int excl = rowptr[i] + bsums[i >> 10] - deg[i];
        rowptr[i] = excl;
        cursor[i] = excl;
    }
    if (i == n) rowptr[n] = ne;
}

__global__ void k_scatter(const int* __restrict__ ei, int* __restrict__ cursor,
                          int* __restrict__ col) {
    int i = blockIdx.x * 256 + threadIdx.x;
    if (i >= NE) return;
    int s, d;
    if (i < EE) { s = ei[i]; d = ei[EE + i]; }
    else        { s = i - EE; d = i - EE; }
    int p = atomicAdd(&cursor[d], 1);
    col[p] = s;
}

// ============================ cast x -> bf16 h ============================
__global__ void k_cast(const float* __restrict__ x, bf16u* __restrict__ h, int total) {
    int i = blockIdx.x * 256 + threadIdx.x;
    if (i < total) h[i] = f2bf(x[i]);
}

// ============================ residual head ============================
__global__ __launch_bounds__(256) void k_residual(const float* __restrict__ x,
                                                  const float* __restrict__ rw,
                                                  const float* __restrict__ rb,
                                                  float* __restrict__ res) {
    int gw = (blockIdx.x * 256 + threadIdx.x) >> 6;
    int lane = threadIdx.x & 63;
    if (gw >= NN) return;
    float a0 = 0.f, a1 = 0.f, a2 = 0.f;
    for (int k = lane; k < IN_F; k += 64) {
        float xv = x[(size_t)gw * IN_F + k];
        a0 += xv * rw[0 * IN_F + k];
        a1 += xv * rw[1 * IN_F + k];
        a2 += xv * rw[2 * IN_F + k];
    }
#pragma unroll
    for (int off = 32; off; off >>= 1) {
        a0 += __shfl_down(a0, off);
        a1 += __shfl_down(a1, off);
        a2 += __shfl_down(a2, off);
    }
    if (lane == 0) {
        res[gw * 3 + 0] = a0 + rb[0];
        res[gw * 3 + 1] = a1 + rb[1];
        res[gw * 3 + 2] = a2 + rb[2];
    }
}

// ============================ LN row stats ============================
// one wave per row: stats[row] = {mu, rstd}
__global__ __launch_bounds__(256) void k_lnstats(const bf16u* __restrict__ in,
                                                 float* __restrict__ stats, int n, int ci) {
    int row = (blockIdx.x * 256 + threadIdx.x) >> 6;
    int lane = threadIdx.x & 63;
    if (row >= n) return;
    const bf16u* ip = in + (size_t)row * ci;
    float s = 0.f, s2 = 0.f;
    for (int k = lane; k < ci; k += 64) {
        float v = bf2f(ip[k]);
        s += v; s2 += v * v;
    }
#pragma unroll
    for (int off = 32; off; off >>= 1) {
        s  += __shfl_down(s, off);
        s2 += __shfl_down(s2, off);
    }
    if (lane == 0) {
        float mu = s / ci;
        float var = s2 / ci - mu * mu;
        stats[row * 2 + 0] = mu;
        stats[row * 2 + 1] = rsqrtf(var + EPSV);
    }
}

// ============================ GEMM with fused LN on A ============================
// C[n,K] = LN(A)[n,ci] @ B[K,ci]^T ; A bf16, B f32, C bf16
__global__ __launch_bounds__(256) void k_gemm_ln(const bf16u* __restrict__ A,
                                                 const float* __restrict__ stats,
                                                 const float* __restrict__ g,
                                                 const float* __restrict__ b,
                                                 const float* __restrict__ B,
                                                 bf16u* __restrict__ C,
                                                 int n, int ci, int K) {
    __shared__ __align__(16) float As[64][20];
    __shared__ __align__(16) float Bs[64][20];
    int tid = threadIdx.x;
    int tx = tid & 15, ty = tid >> 4;
    int row0 = blockIdx.x * 64, col0 = blockIdx.y * 64;
    int lr = tid >> 2, lc = (tid & 3) * 4;
    float acc[4][4] = {};
    for (int k0 = 0; k0 < ci; k0 += 16) {
        float a4[4] = {0.f, 0.f, 0.f, 0.f};
        float4 bv = make_float4(0.f, 0.f, 0.f, 0.f);
        int ar = row0 + lr;
        if (ar < n) {
            uint2 raw = *(const uint2*)(A + (size_t)ar * ci + k0 + lc);
            float mu = stats[ar * 2 + 0], rstd = stats[ar * 2 + 1];
            float4 gv = *(const float4*)(g + k0 + lc);
            float4 bb = *(const float4*)(b + k0 + lc);
            a4[0] = (bf2f(raw.x & 0xFFFFu) - mu) * rstd * gv.x + bb.x;
            a4[1] = (bf2f(raw.x >> 16)     - mu) * rstd * gv.y + bb.y;
            a4[2] = (bf2f(raw.y & 0xFFFFu) - mu) * rstd * gv.z + bb.z;
            a4[3] = (bf2f(raw.y >> 16)     - mu) * rstd * gv.w + bb.w;
        }
        int br = col0 + lr;
        if (br < K) bv = *(const float4*)(B + (size_t)br * ci + k0 + lc);
        __syncthreads();
        As[lr][lc + 0] = a4[0]; As[lr][lc + 1] = a4[1]; As[lr][lc + 2] = a4[2]; As[lr][lc + 3] = a4[3];
        Bs[lr][lc + 0] = bv.x;  Bs[lr][lc + 1] = bv.y;  Bs[lr][lc + 2] = bv.z;  Bs[lr][lc + 3] = bv.w;
        __syncthreads();
#pragma unroll
        for (int kk = 0; kk < 16; kk += 4) {
            float a[4][4], bq[4][4];
#pragma unroll
            for (int i = 0; i < 4; i++) {
                float4 t = *(const float4*)&As[ty + 16 * i][kk];
                a[i][0] = t.x; a[i][1] = t.y; a[i][2] = t.z; a[i][3] = t.w;
            }
#pragma unroll
            for (int j = 0; j < 4; j++) {
                float4 t = *(const float4*)&Bs[tx + 16 * j][kk];
                bq[j][0] = t.x; bq[j][1] = t.y; bq[j][2] = t.z; bq[j][3] = t.w;
            }
#pragma unroll
            for (int q = 0; q < 4; q++)
#pragma unroll
                for (int i = 0; i < 4; i++)
#pragma unroll
                    for (int j = 0; j < 4; j++)
                        acc[i][j] += a[i][q] * bq[j][q];
        }
    }
#pragma unroll
    for (int i = 0; i < 4; i++) {
        int r = row0 + ty + 16 * i;
        if (r >= n) continue;
#pragma unroll
        for (int j = 0; j < 4; j++) {
            int c = col0 + tx + 16 * j;
            if (c < K) C[(size_t)r * K + c] = f2bf(acc[i][j]);
        }
    }
}

// ============================ attention logits ============================
__global__ __launch_bounds__(256) void k_al(const bf16u* __restrict__ hlin,
                                            const float* __restrict__ asr,
                                            const float* __restrict__ adt,
                                            float* __restrict__ alsrc,
                                            float* __restrict__ aldst,
                                            int n, int heads, int co) {
    int row = (blockIdx.x * 256 + threadIdx.x) >> 6;
    int lane = threadIdx.x & 63;
    if (row >= n) return;
    int K = heads * co;
    for (int h = 0; h < heads; h++) {
        float s1 = 0.f, s2 = 0.f;
        for (int c = lane; c < co; c += 64) {
            float v = bf2f(hlin[(size_t)row * K + h * co + c]);
            s1 += v * asr[h * co + c];
            s2 += v * adt[h * co + c];
        }
#pragma unroll
        for (int off = 32; off; off >>= 1) {
            s1 += __shfl_down(s1, off);
            s2 += __shfl_down(s2, off);
        }
        if (lane == 0) {
            alsrc[row * heads + h] = s1;
            aldst[row * heads + h] = s2;
        }
    }
}

// ============================ softmax + aggregate + fused epilogue ============================
// one wave per (node, head). epilogue:
//   isfinal: out_f32[node*3+lane] = acc + bias + resid
//   else:    h_out = f2bf( gelu(acc+bias) + (dores ? h_in : 0) )   (in-place safe)
__global__ __launch_bounds__(256) void k_agg(const bf16u* __restrict__ hlin,
                                             const float* __restrict__ alsrc,
                                             const float* __restrict__ aldst,
                                             const int* __restrict__ rowptr,
                                             const int* __restrict__ col,
                                             const float* __restrict__ bias,
                                             bf16u* __restrict__ hio,
                                             float* __restrict__ outf,
                                             const float* __restrict__ resid,
                                             int n, int heads, int co,
                                             int dores, int isfinal) {
    int gw = (blockIdx.x * 256 + threadIdx.x) >> 6;
    int lane = threadIdx.x & 63;
    int node = gw / heads;
    int h = gw - node * heads;
    if (node >= n) return;
    int K = heads * co;
    int beg = rowptr[node], end = rowptr[node + 1];
    float ad = aldst[node * heads + h];

    float m = -INFINITY;
    for (int e = beg + lane; e < end; e += 64) {
        float v = alsrc[col[e] * heads + h] + ad;
        v = (v >= 0.f) ? v : NEG_SLOPE * v;
        m = fmaxf(m, v);
    }
#pragma unroll
    for (int off = 32; off; off >>= 1) m = fmaxf(m, __shfl_down(m, off));
    m = __shfl(m, 0);

    float s = 0.f;
    for (int e = beg + lane; e < end; e += 64) {
        float v = alsrc[col[e] * heads + h] + ad;
        v = (v >= 0.f) ? v : NEG_SLOPE * v;
        s += expf(v - m);
    }
#pragma unroll
    for (int off = 32; off; off >>= 1) s += __shfl_down(s, off);
    s = __shfl(s, 0);
    float inv = 1.0f / s;

    float acc = 0.f;
    for (int e = beg; e < end; e++) {
        int src = col[e];
        float v = alsrc[src * heads + h] + ad;
        v = (v >= 0.f) ? v : NEG_SLOPE * v;
        float alpha = expf(v - m) * inv;
        if (lane < co) acc += alpha * bf2f(hlin[(size_t)src * K + h * co + lane]);
    }
    if (lane < co) {
        if (isfinal) {
            float v = acc + bias[lane];
            outf[node * 3 + lane] = v + resid[node * 3 + lane];
        } else {
            float v = acc + bias[h * co + lane];
            float ge = 0.5f * v * (1.0f + erff(v * 0.70710678118654752f));
            size_t idx = (size_t)node * K + h * co + lane;
            if (dores) ge += bf2f(hio[idx]);
            hio[idx] = f2bf(ge);
        }
    }
}

// ============================ launch ============================
extern "C" void kernel_launch(void* const* d_in, const int* in_sizes, int n_in,
                              void* d_out, int out_size, void* d_ws, size_t ws_size,
                              hipStream_t stream) {
    const float* x    = (const float*)d_in[0];
    const int*   ei   = (const int*)d_in[1];
    const float* resW = (const float*)d_in[2];
    const float* resb = (const float*)d_in[3];
    const float *lng[4], *lnb[4], *Wm[4], *asr[4], *adt[4], *bias[4];
    int idx = 4;
    for (int i = 0; i < 4; i++) {
        lng[i]  = (const float*)d_in[idx++];
        lnb[i]  = (const float*)d_in[idx++];
        Wm[i]   = (const float*)d_in[idx++];
        asr[i]  = (const float*)d_in[idx++];
        adt[i]  = (const float*)d_in[idx++];
        bias[i] = (const float*)d_in[idx++];
    }

    char* base = (char*)d_ws;
    size_t off = 0;
    auto alloc = [&](size_t bytes) {
        void* p = base + off;
        off += (bytes + 255) & ~(size_t)255;
        return p;
    };
    bf16u* hbuf  = (bf16u*)alloc((size_t)NN * 512 * 2);   // 51.2 MB
    bf16u* hlin  = (bf16u*)alloc((size_t)NN * 512 * 2);   // 51.2 MB
    float* stats = (float*)alloc((size_t)NN * 2 * 4);
    float* alsrc = (float*)alloc((size_t)NN * 8 * 4);
    float* aldst = (float*)alloc((size_t)NN * 8 * 4);
    float* resid = (float*)alloc((size_t)NN * 3 * 4);
    int* rowptr  = (int*)alloc((size_t)(NN + 1) * 4);
    int* cursor  = (int*)alloc((size_t)NN * 4);
    int* deg     = (int*)alloc((size_t)NN * 4);
    int* colidx  = (int*)alloc((size_t)NE * 4);
    int* bsums   = (int*)alloc(256 * 4);
    if (off > ws_size) return;   // ~109 MB needed

    float* out = (float*)d_out;

    // ---- CSR build ----
    k_zero_i32<<<(NN + 255) / 256, 256, 0, stream>>>(deg, NN);
    k_deg<<<(NE + 255) / 256, 256, 0, stream>>>(ei, deg);
    int nb = (NN + 1023) / 1024;
    k_scan1<<<nb, 256, 0, stream>>>(deg, rowptr, bsums, NN);
    k_scan2<<<1, 64, 0, stream>>>(bsums, nb);
    k_scan3<<<(NN + 1 + 255) / 256, 256, 0, stream>>>(deg, rowptr, cursor, bsums, NN, NE);
    k_scatter<<<(NE + 255) / 256, 256, 0, stream>>>(ei, cursor, colidx);

    // ---- residual head + input cast ----
    k_residual<<<(NN * 64 + 255) / 256, 256, 0, stream>>>(x, resW, resb, resid);
    k_cast<<<(NN * IN_F + 255) / 256, 256, 0, stream>>>(x, hbuf, NN * IN_F);

    // ---- layers ----
    const int ci_a[4]    = {128, 512, 512, 512};
    const int heads_a[4] = {8, 8, 8, 1};
    const int co_a[4]    = {64, 64, 64, 3};

    int rowWaves = (NN * 64 + 255) / 256;
    for (int i = 0; i < 4; i++) {
        int ci = ci_a[i], heads = heads_a[i], co = co_a[i];
        int K = heads * co;
        int isfinal = (i == 3) ? 1 : 0;
        int dores = (i == 1 || i == 2) ? 1 : 0;

        k_lnstats<<<rowWaves, 256, 0, stream>>>(hbuf, stats, NN, ci);

        dim3 ggrid((NN + 63) / 64, (K + 63) / 64);
        k_gemm_ln<<<ggrid, 256, 0, stream>>>(hbuf, stats, lng[i], lnb[i], Wm[i], hlin, NN, ci, K);

        k_al<<<rowWaves, 256, 0, stream>>>(hlin, asr[i], adt[i], alsrc, aldst, NN, heads, co);

        int aggBlocks = (int)(((size_t)NN * heads * 64 + 255) / 256);
        k_agg<<<aggBlocks, 256, 0, stream>>>(hlin, alsrc, aldst, rowptr, colidx,
                                             bias[i], hbuf, out, resid,
                                             NN, heads, co, dores, isfinal);
    }
}

// Round 3
// 1976.980 us; speedup vs baseline: 1.5171x; 1.5171x over previous
//
#include <hip/hip_runtime.h>
#include <math.h>

#define NN 50000
#define MPAD 50048          // 391 * 128
#define EE 400000
#define NE 450000           // EE + NN self loops
#define IN_F 128
#define NEG_SLOPE 0.2f
#define EPSV 1e-6f

typedef unsigned short bf16u;
typedef short bf8_t __attribute__((ext_vector_type(8)));
typedef float f32x4 __attribute__((ext_vector_type(4)));

__device__ __forceinline__ float bf2f(unsigned int u) {
    return __uint_as_float(u << 16);
}
__device__ __forceinline__ bf16u f2bf(float f) {
    unsigned int u = __float_as_uint(f);
    unsigned int r = (u + 0x7FFFu + ((u >> 16) & 1u)) >> 16;
    return (bf16u)r;
}

__device__ __forceinline__ void gload_lds16(const void* g, void* l) {
    __builtin_amdgcn_global_load_lds(
        (__attribute__((address_space(1))) void*)(g),
        (__attribute__((address_space(3))) void*)(l), 16, 0, 0);
}

// ============================ CSR build ============================
__global__ void k_zero_i32(int* p, int n) {
    int i = blockIdx.x * 256 + threadIdx.x;
    if (i < n) p[i] = 0;
}

__global__ void k_deg(const int* __restrict__ ei, int* __restrict__ deg) {
    int i = blockIdx.x * 256 + threadIdx.x;
    if (i >= NE) return;
    int d = (i < EE) ? ei[EE + i] : (i - EE);
    atomicAdd(&deg[d], 1);
}

__global__ __launch_bounds__(256) void k_scan1(const int* __restrict__ deg,
                                               int* __restrict__ incl,
                                               int* __restrict__ bsums, int n) {
    __shared__ int sm[1024];
    int base = blockIdx.x * 1024;
    for (int i = threadIdx.x; i < 1024; i += 256)
        sm[i] = (base + i < n) ? deg[base + i] : 0;
    __syncthreads();
    for (int off = 1; off < 1024; off <<= 1) {
        int v[4];
#pragma unroll
        for (int j = 0; j < 4; j++) {
            int i = threadIdx.x + 256 * j;
            v[j] = (i >= off) ? sm[i - off] : 0;
        }
        __syncthreads();
#pragma unroll
        for (int j = 0; j < 4; j++) {
            int i = threadIdx.x + 256 * j;
            sm[i] += v[j];
        }
        __syncthreads();
    }
    for (int i = threadIdx.x; i < 1024; i += 256)
        if (base + i < n) incl[base + i] = sm[i];
    if (threadIdx.x == 0) bsums[blockIdx.x] = sm[1023];
}

__global__ void k_scan2(int* bsums, int nb) {
    if (threadIdx.x == 0 && blockIdx.x == 0) {
        int run = 0;
        for (int i = 0; i < nb; i++) { int v = bsums[i]; bsums[i] = run; run += v; }
    }
}

__global__ void k_scan3(const int* __restrict__ deg, int* __restrict__ rowptr,
                        int* __restrict__ cursor, const int* __restrict__ bsums,
                        int n, int ne) {
    int i = blockIdx.x * 256 + threadIdx.x;
    if (i < n) {
        int excl = rowptr[i] + bsums[i >> 10] - deg[i];
        rowptr[i] = excl;
        cursor[i] = excl;
    }
    if (i == n) rowptr[n] = ne;
}

__global__ void k_scatter(const int* __restrict__ ei, int* __restrict__ cursor,
                          int* __restrict__ col) {
    int i = blockIdx.x * 256 + threadIdx.x;
    if (i >= NE) return;
    int s, d;
    if (i < EE) { s = ei[i]; d = ei[EE + i]; }
    else        { s = i - EE; d = i - EE; }
    int p = atomicAdd(&cursor[d], 1);
    col[p] = s;
}

// ============================ f32 -> bf16 cast ============================
__global__ void k_cast(const float* __restrict__ x, bf16u* __restrict__ h, int total) {
    int i = blockIdx.x * 256 + threadIdx.x;
    if (i < total) h[i] = f2bf(x[i]);
}

// ============================ residual head ============================
__global__ __launch_bounds__(256) void k_residual(const float* __restrict__ x,
                                                  const float* __restrict__ rw,
                                                  const float* __restrict__ rb,
                                                  float* __restrict__ res) {
    int gw = (blockIdx.x * 256 + threadIdx.x) >> 6;
    int lane = threadIdx.x & 63;
    if (gw >= NN) return;
    float a0 = 0.f, a1 = 0.f, a2 = 0.f;
    for (int k = lane; k < IN_F; k += 64) {
        float xv = x[(size_t)gw * IN_F + k];
        a0 += xv * rw[0 * IN_F + k];
        a1 += xv * rw[1 * IN_F + k];
        a2 += xv * rw[2 * IN_F + k];
    }
#pragma unroll
    for (int off = 32; off; off >>= 1) {
        a0 += __shfl_down(a0, off);
        a1 += __shfl_down(a1, off);
        a2 += __shfl_down(a2, off);
    }
    if (lane == 0) {
        res[gw * 3 + 0] = a0 + rb[0];
        res[gw * 3 + 1] = a1 + rb[1];
        res[gw * 3 + 2] = a2 + rb[2];
    }
}

// ============================ LN row stats (vectorized) ============================
__global__ __launch_bounds__(256) void k_lnstats(const bf16u* __restrict__ in,
                                                 float* __restrict__ stats, int n, int ci) {
    int row = (blockIdx.x * 256 + threadIdx.x) >> 6;
    int lane = threadIdx.x & 63;
    if (row >= n) return;
    int nv = ci >> 3;
    float s = 0.f, s2 = 0.f;
    if (lane < nv) {
        uint4 r = *(const uint4*)(in + (size_t)row * ci + lane * 8);
        unsigned int u[4] = {r.x, r.y, r.z, r.w};
#pragma unroll
        for (int j = 0; j < 4; j++) {
            float a = bf2f(u[j] & 0xFFFFu), b = bf2f(u[j] >> 16);
            s += a + b; s2 += a * a + b * b;
        }
    }
#pragma unroll
    for (int off = 32; off; off >>= 1) {
        s  += __shfl_down(s, off);
        s2 += __shfl_down(s2, off);
    }
    if (lane == 0) {
        float mu = s / ci;
        float var = s2 / ci - mu * mu;
        stats[row * 2 + 0] = mu;
        stats[row * 2 + 1] = rsqrtf(var + EPSV);
    }
}

// ============================ MFMA GEMM with fused LN on A ============================
// C[M,K] = LN(A)[M,ci] @ Wb[K,ci]^T ; A bf16 raw h, Wb bf16, C bf16.
// 128x128 block tile, 4 waves, each wave 64x64 via 4x4 of 16x16x32 fragments.
#define BM 128
#define BN 128
#define BKK 32
__global__ __launch_bounds__(256) void k_gemm_mfma(const bf16u* __restrict__ H,
                                                   const float* __restrict__ stats,
                                                   const float* __restrict__ g,
                                                   const float* __restrict__ bbias,
                                                   const bf16u* __restrict__ Wb,
                                                   bf16u* __restrict__ C,
                                                   int Mreal, int ci, int K) {
    __shared__ __align__(16) bf16u As[BM * BKK];
    __shared__ __align__(16) bf16u Bs[BN * BKK];
    const int tid = threadIdx.x;
    const int w = tid >> 6, lane = tid & 63;
    const int row0 = blockIdx.x * BM, col0 = blockIdx.y * BN;
    const int wr = (w >> 1) * 64, wc = (w & 1) * 64;

    // staging geometry: wave w covers tile rows [w*32, w*32+32), 2 issues of 16 rows
    const int srow = w * 32 + (lane >> 2);       // first-issue tile row for this lane
    const int scol = (lane & 3) * 8;             // bf16 column offset (16 B)
    const bf16u* gA = H + (size_t)(row0 + srow) * ci + scol;
    const bf16u* gB = Wb + (size_t)(col0 + srow) * ci + scol;
    const float mu1 = stats[(row0 + srow) * 2 + 0];
    const float rs1 = stats[(row0 + srow) * 2 + 1];
    const float mu2 = stats[(row0 + srow + 16) * 2 + 0];
    const float rs2 = stats[(row0 + srow + 16) * 2 + 1];
    bf16u* lA1 = &As[(size_t)srow * BKK + scol];
    bf16u* lA2 = &As[(size_t)(srow + 16) * BKK + scol];
    void* lB1 = &Bs[(size_t)(w * 32) * BKK];
    void* lB2 = &Bs[(size_t)(w * 32 + 16) * BKK];

    f32x4 acc[4][4] = {};

    const int fr = lane & 15;            // fragment row (A) / col (B)
    const int fk = (lane >> 4) * 8;      // fragment k offset

    for (int k0 = 0; k0 < ci; k0 += BKK) {
        // ---- load raw A (2 chunks of 8 bf16) + LN in registers ----
        uint4 ra1 = *(const uint4*)(gA + k0);
        uint4 ra2 = *(const uint4*)(gA + (size_t)16 * ci + k0);
        float4 g0 = *(const float4*)(g + k0 + scol);
        float4 g1 = *(const float4*)(g + k0 + scol + 4);
        float4 b0 = *(const float4*)(bbias + k0 + scol);
        float4 b1 = *(const float4*)(bbias + k0 + scol + 4);
        float gg[8] = {g0.x, g0.y, g0.z, g0.w, g1.x, g1.y, g1.z, g1.w};
        float bb[8] = {b0.x, b0.y, b0.z, b0.w, b1.x, b1.y, b1.z, b1.w};
        unsigned int u1[4] = {ra1.x, ra1.y, ra1.z, ra1.w};
        unsigned int u2[4] = {ra2.x, ra2.y, ra2.z, ra2.w};
        uint4 p1, p2;
        {
            unsigned int po[4], qo[4];
#pragma unroll
            for (int j = 0; j < 4; j++) {
                float va = (bf2f(u1[j] & 0xFFFFu) - mu1) * rs1;
                float vb = (bf2f(u1[j] >> 16)     - mu1) * rs1;
                float oa = fmaf(va, gg[2 * j], bb[2 * j]);
                float ob = fmaf(vb, gg[2 * j + 1], bb[2 * j + 1]);
                po[j] = (unsigned int)f2bf(oa) | ((unsigned int)f2bf(ob) << 16);
                float vc = (bf2f(u2[j] & 0xFFFFu) - mu2) * rs2;
                float vd = (bf2f(u2[j] >> 16)     - mu2) * rs2;
                float oc = fmaf(vc, gg[2 * j], bb[2 * j]);
                float od = fmaf(vd, gg[2 * j + 1], bb[2 * j + 1]);
                qo[j] = (unsigned int)f2bf(oc) | ((unsigned int)f2bf(od) << 16);
            }
            p1 = make_uint4(po[0], po[1], po[2], po[3]);
            p2 = make_uint4(qo[0], qo[1], qo[2], qo[3]);
        }

        __syncthreads();          // all waves done reading previous tiles
        *(uint4*)lA1 = p1;
        *(uint4*)lA2 = p2;
        gload_lds16(gB + k0, lB1);
        gload_lds16(gB + (size_t)16 * ci + k0, lB2);
        __syncthreads();          // compiler drains vmcnt/lgkmcnt before barrier

        bf8_t af[4], bf[4];
#pragma unroll
        for (int m = 0; m < 4; m++)
            af[m] = *(const bf8_t*)&As[(size_t)(wr + m * 16 + fr) * BKK + fk];
#pragma unroll
        for (int n = 0; n < 4; n++)
            bf[n] = *(const bf8_t*)&Bs[(size_t)(wc + n * 16 + fr) * BKK + fk];
#pragma unroll
        for (int m = 0; m < 4; m++)
#pragma unroll
            for (int n = 0; n < 4; n++)
                acc[m][n] = __builtin_amdgcn_mfma_f32_16x16x32_bf16(af[m], bf[n], acc[m][n], 0, 0, 0);
    }

    // ---- epilogue: store bf16 C ----
    const int fc = lane & 15;
    const int fq = (lane >> 4) * 4;
#pragma unroll
    for (int m = 0; m < 4; m++) {
#pragma unroll
        for (int r = 0; r < 4; r++) {
            int row = row0 + wr + m * 16 + fq + r;
            if (row >= Mreal) continue;
#pragma unroll
            for (int n = 0; n < 4; n++) {
                int col = col0 + wc + n * 16 + fc;
                C[(size_t)row * K + col] = f2bf(acc[m][n][r]);
            }
        }
    }
}

// ============================ attention logits (heads=8, co=64) ============================
__global__ __launch_bounds__(256) void k_al(const bf16u* __restrict__ hlin,
                                            const float* __restrict__ asr,
                                            const float* __restrict__ adt,
                                            float* __restrict__ alsrc,
                                            float* __restrict__ aldst,
                                            int n, int heads, int co) {
    int row = (blockIdx.x * 256 + threadIdx.x) >> 6;
    int lane = threadIdx.x & 63;
    if (row >= n) return;
    int K = heads * co;
    for (int h = 0; h < heads; h++) {
        float s1 = 0.f, s2 = 0.f;
        for (int c = lane; c < co; c += 64) {
            float v = bf2f(hlin[(size_t)row * K + h * co + c]);
            s1 += v * asr[h * co + c];
            s2 += v * adt[h * co + c];
        }
#pragma unroll
        for (int off = 32; off; off >>= 1) {
            s1 += __shfl_down(s1, off);
            s2 += __shfl_down(s2, off);
        }
        if (lane == 0) {
            alsrc[row * heads + h] = s1;
            aldst[row * heads + h] = s2;
        }
    }
}

// ============================ layer-3 matvec + logits ============================
// one wave per node: ln = LN(h_row); hlin3 = ln @ W3^T (3 outputs); al_src/al_dst inline
__global__ __launch_bounds__(256) void k_lin3(const bf16u* __restrict__ h,
                                              const float* __restrict__ stats,
                                              const float* __restrict__ g,
                                              const float* __restrict__ bb,
                                              const float* __restrict__ W,
                                              const float* __restrict__ a_s,
                                              const float* __restrict__ a_d,
                                              bf16u* __restrict__ hlin3,
                                              float* __restrict__ alsrc,
                                              float* __restrict__ aldst, int n) {
    int row = (blockIdx.x * 256 + threadIdx.x) >> 6;
    int lane = threadIdx.x & 63;
    if (row >= n) return;
    float mu = stats[row * 2 + 0], rs = stats[row * 2 + 1];
    uint4 r = *(const uint4*)(h + (size_t)row * 512 + lane * 8);
    float4 g0 = *(const float4*)(g + lane * 8);
    float4 g1 = *(const float4*)(g + lane * 8 + 4);
    float4 b0 = *(const float4*)(bb + lane * 8);
    float4 b1 = *(const float4*)(bb + lane * 8 + 4);
    float gg[8] = {g0.x, g0.y, g0.z, g0.w, g1.x, g1.y, g1.z, g1.w};
    float bv[8] = {b0.x, b0.y, b0.z, b0.w, b1.x, b1.y, b1.z, b1.w};
    unsigned int u[4] = {r.x, r.y, r.z, r.w};
    float ln[8];
#pragma unroll
    for (int j = 0; j < 4; j++) {
        ln[2 * j]     = fmaf((bf2f(u[j] & 0xFFFFu) - mu) * rs, gg[2 * j], bv[2 * j]);
        ln[2 * j + 1] = fmaf((bf2f(u[j] >> 16)     - mu) * rs, gg[2 * j + 1], bv[2 * j + 1]);
    }
    float a0 = 0.f, a1 = 0.f, a2 = 0.f;
#pragma unroll
    for (int j = 0; j < 8; j++) {
        int k = lane * 8 + j;
        a0 += ln[j] * W[k];
        a1 += ln[j] * W[512 + k];
        a2 += ln[j] * W[1024 + k];
    }
#pragma unroll
    for (int off = 32; off; off >>= 1) {
        a0 += __shfl_down(a0, off);
        a1 += __shfl_down(a1, off);
        a2 += __shfl_down(a2, off);
    }
    if (lane == 0) {
        hlin3[row * 3 + 0] = f2bf(a0);
        hlin3[row * 3 + 1] = f2bf(a1);
        hlin3[row * 3 + 2] = f2bf(a2);
        alsrc[row] = a0 * a_s[0] + a1 * a_s[1] + a2 * a_s[2];
        aldst[row] = a0 * a_d[0] + a1 * a_d[1] + a2 * a_d[2];
    }
}

// ============================ softmax + aggregate + fused epilogue ============================
__global__ __launch_bounds__(256) void k_agg(const bf16u* __restrict__ hlin,
                                             const float* __restrict__ alsrc,
                                             const float* __restrict__ aldst,
                                             const int* __restrict__ rowptr,
                                             const int* __restrict__ col,
                                             const float* __restrict__ bias,
                                             bf16u* __restrict__ hio,
                                             float* __restrict__ outf,
                                             const float* __restrict__ resid,
                                             int n, int heads, int co,
                                             int dores, int isfinal) {
    int gw = (blockIdx.x * 256 + threadIdx.x) >> 6;
    int lane = threadIdx.x & 63;
    int node = gw / heads;
    int h = gw - node * heads;
    if (node >= n) return;
    int K = heads * co;
    int beg = rowptr[node], end = rowptr[node + 1];
    float ad = aldst[node * heads + h];

    float m = -INFINITY;
    for (int e = beg + lane; e < end; e += 64) {
        float v = alsrc[col[e] * heads + h] + ad;
        v = (v >= 0.f) ? v : NEG_SLOPE * v;
        m = fmaxf(m, v);
    }
#pragma unroll
    for (int off = 32; off; off >>= 1) m = fmaxf(m, __shfl_down(m, off));
    m = __shfl(m, 0);

    float s = 0.f;
    for (int e = beg + lane; e < end; e += 64) {
        float v = alsrc[col[e] * heads + h] + ad;
        v = (v >= 0.f) ? v : NEG_SLOPE * v;
        s += expf(v - m);
    }
#pragma unroll
    for (int off = 32; off; off >>= 1) s += __shfl_down(s, off);
    s = __shfl(s, 0);
    float inv = 1.0f / s;

    float acc = 0.f;
    for (int e = beg; e < end; e++) {
        int src = col[e];
        float v = alsrc[src * heads + h] + ad;
        v = (v >= 0.f) ? v : NEG_SLOPE * v;
        float alpha = expf(v - m) * inv;
        if (lane < co) acc += alpha * bf2f(hlin[(size_t)src * K + h * co + lane]);
    }
    if (lane < co) {
        if (isfinal) {
            float v = acc + bias[lane];
            outf[node * 3 + lane] = v + resid[node * 3 + lane];
        } else {
            float v = acc + bias[h * co + lane];
            float ge = 0.5f * v * (1.0f + erff(v * 0.70710678118654752f));
            size_t idx = (size_t)node * K + h * co + lane;
            if (dores) ge += bf2f(hio[idx]);
            hio[idx] = f2bf(ge);
        }
    }
}

// ============================ launch ============================
extern "C" void kernel_launch(void* const* d_in, const int* in_sizes, int n_in,
                              void* d_out, int out_size, void* d_ws, size_t ws_size,
                              hipStream_t stream) {
    const float* x    = (const float*)d_in[0];
    const int*   ei   = (const int*)d_in[1];
    const float* resW = (const float*)d_in[2];
    const float* resb = (const float*)d_in[3];
    const float *lng[4], *lnb[4], *Wm[4], *asr[4], *adt[4], *bias[4];
    int idx = 4;
    for (int i = 0; i < 4; i++) {
        lng[i]  = (const float*)d_in[idx++];
        lnb[i]  = (const float*)d_in[idx++];
        Wm[i]   = (const float*)d_in[idx++];
        asr[i]  = (const float*)d_in[idx++];
        adt[i]  = (const float*)d_in[idx++];
        bias[i] = (const float*)d_in[idx++];
    }

    char* base = (char*)d_ws;
    size_t off = 0;
    auto alloc = [&](size_t bytes) {
        void* p = base + off;
        off += (bytes + 255) & ~(size_t)255;
        return p;
    };
    bf16u* hbuf  = (bf16u*)alloc((size_t)MPAD * 512 * 2);   // 51.25 MB
    bf16u* lbuf  = (bf16u*)alloc((size_t)MPAD * 512 * 2);   // 51.25 MB
    bf16u* wb0   = (bf16u*)alloc((size_t)512 * 128 * 2);
    bf16u* wb1   = (bf16u*)alloc((size_t)512 * 512 * 2);
    bf16u* wb2   = (bf16u*)alloc((size_t)512 * 512 * 2);
    float* stats = (float*)alloc((size_t)MPAD * 2 * 4);
    float* alsrc = (float*)alloc((size_t)NN * 8 * 4);
    float* aldst = (float*)alloc((size_t)NN * 8 * 4);
    float* resid = (float*)alloc((size_t)NN * 3 * 4);
    int* rowptr  = (int*)alloc((size_t)(NN + 1) * 4);
    int* cursor  = (int*)alloc((size_t)NN * 4);
    int* deg     = (int*)alloc((size_t)NN * 4);
    int* colidx  = (int*)alloc((size_t)NE * 4);
    int* bsums   = (int*)alloc(256 * 4);
    if (off > ws_size) return;   // ~110 MB needed

    float* out = (float*)d_out;

    // ---- CSR build ----
    k_zero_i32<<<(NN + 255) / 256, 256, 0, stream>>>(deg, NN);
    k_deg<<<(NE + 255) / 256, 256, 0, stream>>>(ei, deg);
    int nb = (NN + 1023) / 1024;
    k_scan1<<<nb, 256, 0, stream>>>(deg, rowptr, bsums, NN);
    k_scan2<<<1, 64, 0, stream>>>(bsums, nb);
    k_scan3<<<(NN + 1 + 255) / 256, 256, 0, stream>>>(deg, rowptr, cursor, bsums, NN, NE);
    k_scatter<<<(NE + 255) / 256, 256, 0, stream>>>(ei, cursor, colidx);

    // ---- residual head + input cast + weight casts ----
    k_residual<<<(NN * 64 + 255) / 256, 256, 0, stream>>>(x, resW, resb, resid);
    k_cast<<<(NN * IN_F + 255) / 256, 256, 0, stream>>>(x, hbuf, NN * IN_F);
    k_cast<<<(512 * 128 + 255) / 256, 256, 0, stream>>>(Wm[0], wb0, 512 * 128);
    k_cast<<<(512 * 512 + 255) / 256, 256, 0, stream>>>(Wm[1], wb1, 512 * 512);
    k_cast<<<(512 * 512 + 255) / 256, 256, 0, stream>>>(Wm[2], wb2, 512 * 512);

    const bf16u* wb[3] = {wb0, wb1, wb2};
    const int ci_a[3] = {128, 512, 512};

    int rowWaves = (NN * 64 + 255) / 256;
    for (int i = 0; i < 3; i++) {
        int ci = ci_a[i];
        int dores = (i >= 1) ? 1 : 0;

        k_lnstats<<<rowWaves, 256, 0, stream>>>(hbuf, stats, NN, ci);

        dim3 ggrid(MPAD / BM, 512 / BN);
        k_gemm_mfma<<<ggrid, 256, 0, stream>>>(hbuf, stats, lng[i], lnb[i], wb[i],
                                               lbuf, NN, ci, 512);

        k_al<<<rowWaves, 256, 0, stream>>>(lbuf, asr[i], adt[i], alsrc, aldst, NN, 8, 64);

        int aggBlocks = (int)(((size_t)NN * 8 * 64 + 255) / 256);
        k_agg<<<aggBlocks, 256, 0, stream>>>(lbuf, alsrc, aldst, rowptr, colidx,
                                             bias[i], hbuf, out, resid,
                                             NN, 8, 64, dores, 0);
    }

    // ---- layer 3: matvec + logits, then final aggregate into d_out ----
    k_lnstats<<<rowWaves, 256, 0, stream>>>(hbuf, stats, NN, 512);
    k_lin3<<<rowWaves, 256, 0, stream>>>(hbuf, stats, lng[3], lnb[3], Wm[3],
                                         asr[3], adt[3], lbuf, alsrc, aldst, NN);
    int aggBlocks3 = (int)(((size_t)NN * 1 * 64 + 255) / 256);
    k_agg<<<aggBlocks3, 256, 0, stream>>>(lbuf, alsrc, aldst, rowptr, colidx,
                                          bias[3], hbuf, out, resid,
                                          NN, 1, 3, 0, 1);
}

// Round 4
// 1253.683 us; speedup vs baseline: 2.3923x; 1.5769x over previous
//
#include <hip/hip_runtime.h>
#include <math.h>

#define NN 50000
#define MPAD 50048          // 391 * 128
#define EE 400000
#define NE 450000           // EE + NN self loops
#define IN_F 128
#define NEG_SLOPE 0.2f
#define EPSV 1e-6f

typedef unsigned short bf16u;
typedef short bf8_t __attribute__((ext_vector_type(8)));
typedef float f32x4 __attribute__((ext_vector_type(4)));

__device__ __forceinline__ float bf2f(unsigned int u) {
    return __uint_as_float(u << 16);
}
__device__ __forceinline__ bf16u f2bf(float f) {
    unsigned int u = __float_as_uint(f);
    unsigned int r = (u + 0x7FFFu + ((u >> 16) & 1u)) >> 16;
    return (bf16u)r;
}

__device__ __forceinline__ void gload_lds16(const void* g, void* l) {
    __builtin_amdgcn_global_load_lds(
        (__attribute__((address_space(1))) void*)(g),
        (__attribute__((address_space(3))) void*)(l), 16, 0, 0);
}

// ============================ CSR build ============================
__global__ void k_zero_i32(int* p, int n) {
    int i = blockIdx.x * 256 + threadIdx.x;
    if (i < n) p[i] = 0;
}

__global__ void k_deg(const int* __restrict__ ei, int* __restrict__ deg) {
    int i = blockIdx.x * 256 + threadIdx.x;
    if (i >= NE) return;
    int d = (i < EE) ? ei[EE + i] : (i - EE);
    atomicAdd(&deg[d], 1);
}

__global__ __launch_bounds__(256) void k_scan1(const int* __restrict__ deg,
                                               int* __restrict__ incl,
                                               int* __restrict__ bsums, int n) {
    __shared__ int sm[1024];
    int base = blockIdx.x * 1024;
    for (int i = threadIdx.x; i < 1024; i += 256)
        sm[i] = (base + i < n) ? deg[base + i] : 0;
    __syncthreads();
    for (int off = 1; off < 1024; off <<= 1) {
        int v[4];
#pragma unroll
        for (int j = 0; j < 4; j++) {
            int i = threadIdx.x + 256 * j;
            v[j] = (i >= off) ? sm[i - off] : 0;
        }
        __syncthreads();
#pragma unroll
        for (int j = 0; j < 4; j++) {
            int i = threadIdx.x + 256 * j;
            sm[i] += v[j];
        }
        __syncthreads();
    }
    for (int i = threadIdx.x; i < 1024; i += 256)
        if (base + i < n) incl[base + i] = sm[i];
    if (threadIdx.x == 0) bsums[blockIdx.x] = sm[1023];
}

__global__ void k_scan2(int* bsums, int nb) {
    if (threadIdx.x == 0 && blockIdx.x == 0) {
        int run = 0;
        for (int i = 0; i < nb; i++) { int v = bsums[i]; bsums[i] = run; run += v; }
    }
}

__global__ void k_scan3(const int* __restrict__ deg, int* __restrict__ rowptr,
                        int* __restrict__ cursor, const int* __restrict__ bsums,
                        int n, int ne) {
    int i = blockIdx.x * 256 + threadIdx.x;
    if (i < n) {
        int excl = rowptr[i] + bsums[i >> 10] - deg[i];
        rowptr[i] = excl;
        cursor[i] = excl;
    }
    if (i == n) rowptr[n] = ne;
}

__global__ void k_scatter(const int* __restrict__ ei, int* __restrict__ cursor,
                          int* __restrict__ col) {
    int i = blockIdx.x * 256 + threadIdx.x;
    if (i >= NE) return;
    int s, d;
    if (i < EE) { s = ei[i]; d = ei[EE + i]; }
    else        { s = i - EE; d = i - EE; }
    int p = atomicAdd(&cursor[d], 1);
    col[p] = s;
}

// ============================ f32 -> bf16 cast ============================
__global__ void k_cast(const float* __restrict__ x, bf16u* __restrict__ h, int total) {
    int i = blockIdx.x * 256 + threadIdx.x;
    if (i < total) h[i] = f2bf(x[i]);
}

// ============================ residual head ============================
__global__ __launch_bounds__(256) void k_residual(const float* __restrict__ x,
                                                  const float* __restrict__ rw,
                                                  const float* __restrict__ rb,
                                                  float* __restrict__ res) {
    int gw = (blockIdx.x * 256 + threadIdx.x) >> 6;
    int lane = threadIdx.x & 63;
    if (gw >= NN) return;
    float a0 = 0.f, a1 = 0.f, a2 = 0.f;
    for (int k = lane; k < IN_F; k += 64) {
        float xv = x[(size_t)gw * IN_F + k];
        a0 += xv * rw[0 * IN_F + k];
        a1 += xv * rw[1 * IN_F + k];
        a2 += xv * rw[2 * IN_F + k];
    }
#pragma unroll
    for (int off = 32; off; off >>= 1) {
        a0 += __shfl_down(a0, off);
        a1 += __shfl_down(a1, off);
        a2 += __shfl_down(a2, off);
    }
    if (lane == 0) {
        res[gw * 3 + 0] = a0 + rb[0];
        res[gw * 3 + 1] = a1 + rb[1];
        res[gw * 3 + 2] = a2 + rb[2];
    }
}

// ============================ LN row stats (vectorized) ============================
__global__ __launch_bounds__(256) void k_lnstats(const bf16u* __restrict__ in,
                                                 float* __restrict__ stats, int n, int ci) {
    int row = (blockIdx.x * 256 + threadIdx.x) >> 6;
    int lane = threadIdx.x & 63;
    if (row >= n) return;
    int nv = ci >> 3;
    float s = 0.f, s2 = 0.f;
    if (lane < nv) {
        uint4 r = *(const uint4*)(in + (size_t)row * ci + lane * 8);
        unsigned int u[4] = {r.x, r.y, r.z, r.w};
#pragma unroll
        for (int j = 0; j < 4; j++) {
            float a = bf2f(u[j] & 0xFFFFu), b = bf2f(u[j] >> 16);
            s += a + b; s2 += a * a + b * b;
        }
    }
#pragma unroll
    for (int off = 32; off; off >>= 1) {
        s  += __shfl_down(s, off);
        s2 += __shfl_down(s2, off);
    }
    if (lane == 0) {
        float mu = s / ci;
        float var = s2 / ci - mu * mu;
        stats[row * 2 + 0] = mu;
        stats[row * 2 + 1] = rsqrtf(var + EPSV);
    }
}

// ============================ MFMA GEMM with fused LN on A ============================
#define BM 128
#define BN 128
#define BKK 32
__global__ __launch_bounds__(256) void k_gemm_mfma(const bf16u* __restrict__ H,
                                                   const float* __restrict__ stats,
                                                   const float* __restrict__ g,
                                                   const float* __restrict__ bbias,
                                                   const bf16u* __restrict__ Wb,
                                                   bf16u* __restrict__ C,
                                                   int Mreal, int ci, int K) {
    __shared__ __align__(16) bf16u As[BM * BKK];
    __shared__ __align__(16) bf16u Bs[BN * BKK];
    const int tid = threadIdx.x;
    const int w = tid >> 6, lane = tid & 63;
    const int row0 = blockIdx.x * BM, col0 = blockIdx.y * BN;
    const int wr = (w >> 1) * 64, wc = (w & 1) * 64;

    const int srow = w * 32 + (lane >> 2);
    const int scol = (lane & 3) * 8;
    const bf16u* gA = H + (size_t)(row0 + srow) * ci + scol;
    const bf16u* gB = Wb + (size_t)(col0 + srow) * ci + scol;
    const float mu1 = stats[(row0 + srow) * 2 + 0];
    const float rs1 = stats[(row0 + srow) * 2 + 1];
    const float mu2 = stats[(row0 + srow + 16) * 2 + 0];
    const float rs2 = stats[(row0 + srow + 16) * 2 + 1];
    bf16u* lA1 = &As[(size_t)srow * BKK + scol];
    bf16u* lA2 = &As[(size_t)(srow + 16) * BKK + scol];
    void* lB1 = &Bs[(size_t)(w * 32) * BKK];
    void* lB2 = &Bs[(size_t)(w * 32 + 16) * BKK];

    f32x4 acc[4][4] = {};

    const int fr = lane & 15;
    const int fk = (lane >> 4) * 8;

    for (int k0 = 0; k0 < ci; k0 += BKK) {
        uint4 ra1 = *(const uint4*)(gA + k0);
        uint4 ra2 = *(const uint4*)(gA + (size_t)16 * ci + k0);
        float4 g0 = *(const float4*)(g + k0 + scol);
        float4 g1 = *(const float4*)(g + k0 + scol + 4);
        float4 b0 = *(const float4*)(bbias + k0 + scol);
        float4 b1 = *(const float4*)(bbias + k0 + scol + 4);
        float gg[8] = {g0.x, g0.y, g0.z, g0.w, g1.x, g1.y, g1.z, g1.w};
        float bb[8] = {b0.x, b0.y, b0.z, b0.w, b1.x, b1.y, b1.z, b1.w};
        unsigned int u1[4] = {ra1.x, ra1.y, ra1.z, ra1.w};
        unsigned int u2[4] = {ra2.x, ra2.y, ra2.z, ra2.w};
        uint4 p1, p2;
        {
            unsigned int po[4], qo[4];
#pragma unroll
            for (int j = 0; j < 4; j++) {
                float va = (bf2f(u1[j] & 0xFFFFu) - mu1) * rs1;
                float vb = (bf2f(u1[j] >> 16)     - mu1) * rs1;
                float oa = fmaf(va, gg[2 * j], bb[2 * j]);
                float ob = fmaf(vb, gg[2 * j + 1], bb[2 * j + 1]);
                po[j] = (unsigned int)f2bf(oa) | ((unsigned int)f2bf(ob) << 16);
                float vc = (bf2f(u2[j] & 0xFFFFu) - mu2) * rs2;
                float vd = (bf2f(u2[j] >> 16)     - mu2) * rs2;
                float oc = fmaf(vc, gg[2 * j], bb[2 * j]);
                float od = fmaf(vd, gg[2 * j + 1], bb[2 * j + 1]);
                qo[j] = (unsigned int)f2bf(oc) | ((unsigned int)f2bf(od) << 16);
            }
            p1 = make_uint4(po[0], po[1], po[2], po[3]);
            p2 = make_uint4(qo[0], qo[1], qo[2], qo[3]);
        }

        __syncthreads();
        *(uint4*)lA1 = p1;
        *(uint4*)lA2 = p2;
        gload_lds16(gB + k0, lB1);
        gload_lds16(gB + (size_t)16 * ci + k0, lB2);
        __syncthreads();

        bf8_t af[4], bf[4];
#pragma unroll
        for (int m = 0; m < 4; m++)
            af[m] = *(const bf8_t*)&As[(size_t)(wr + m * 16 + fr) * BKK + fk];
#pragma unroll
        for (int n = 0; n < 4; n++)
            bf[n] = *(const bf8_t*)&Bs[(size_t)(wc + n * 16 + fr) * BKK + fk];
#pragma unroll
        for (int m = 0; m < 4; m++)
#pragma unroll
            for (int n = 0; n < 4; n++)
                acc[m][n] = __builtin_amdgcn_mfma_f32_16x16x32_bf16(af[m], bf[n], acc[m][n], 0, 0, 0);
    }

    const int fc = lane & 15;
    const int fq = (lane >> 4) * 4;
#pragma unroll
    for (int m = 0; m < 4; m++) {
#pragma unroll
        for (int r = 0; r < 4; r++) {
            int row = row0 + wr + m * 16 + fq + r;
            if (row >= Mreal) continue;
#pragma unroll
            for (int n = 0; n < 4; n++) {
                int col = col0 + wc + n * 16 + fc;
                C[(size_t)row * K + col] = f2bf(acc[m][n][r]);
            }
        }
    }
}

// ============================ attention logits (heads=8, co=64) ============================
__global__ __launch_bounds__(256) void k_al(const bf16u* __restrict__ hlin,
                                            const float* __restrict__ asr,
                                            const float* __restrict__ adt,
                                            float* __restrict__ alsrc,
                                            float* __restrict__ aldst,
                                            int n, int heads, int co) {
    int row = (blockIdx.x * 256 + threadIdx.x) >> 6;
    int lane = threadIdx.x & 63;
    if (row >= n) return;
    int K = heads * co;
    for (int h = 0; h < heads; h++) {
        float s1 = 0.f, s2 = 0.f;
        for (int c = lane; c < co; c += 64) {
            float v = bf2f(hlin[(size_t)row * K + h * co + c]);
            s1 += v * asr[h * co + c];
            s2 += v * adt[h * co + c];
        }
#pragma unroll
        for (int off = 32; off; off >>= 1) {
            s1 += __shfl_down(s1, off);
            s2 += __shfl_down(s2, off);
        }
        if (lane == 0) {
            alsrc[row * heads + h] = s1;
            aldst[row * heads + h] = s2;
        }
    }
}

// ============================ layer-3 matvec + logits ============================
__global__ __launch_bounds__(256) void k_lin3(const bf16u* __restrict__ h,
                                              const float* __restrict__ stats,
                                              const float* __restrict__ g,
                                              const float* __restrict__ bb,
                                              const float* __restrict__ W,
                                              const float* __restrict__ a_s,
                                              const float* __restrict__ a_d,
                                              bf16u* __restrict__ hlin3,
                                              float* __restrict__ alsrc,
                                              float* __restrict__ aldst, int n) {
    int row = (blockIdx.x * 256 + threadIdx.x) >> 6;
    int lane = threadIdx.x & 63;
    if (row >= n) return;
    float mu = stats[row * 2 + 0], rs = stats[row * 2 + 1];
    uint4 r = *(const uint4*)(h + (size_t)row * 512 + lane * 8);
    float4 g0 = *(const float4*)(g + lane * 8);
    float4 g1 = *(const float4*)(g + lane * 8 + 4);
    float4 b0 = *(const float4*)(bb + lane * 8);
    float4 b1 = *(const float4*)(bb + lane * 8 + 4);
    float gg[8] = {g0.x, g0.y, g0.z, g0.w, g1.x, g1.y, g1.z, g1.w};
    float bv[8] = {b0.x, b0.y, b0.z, b0.w, b1.x, b1.y, b1.z, b1.w};
    unsigned int u[4] = {r.x, r.y, r.z, r.w};
    float ln[8];
#pragma unroll
    for (int j = 0; j < 4; j++) {
        ln[2 * j]     = fmaf((bf2f(u[j] & 0xFFFFu) - mu) * rs, gg[2 * j], bv[2 * j]);
        ln[2 * j + 1] = fmaf((bf2f(u[j] >> 16)     - mu) * rs, gg[2 * j + 1], bv[2 * j + 1]);
    }
    float a0 = 0.f, a1 = 0.f, a2 = 0.f;
#pragma unroll
    for (int j = 0; j < 8; j++) {
        int k = lane * 8 + j;
        a0 += ln[j] * W[k];
        a1 += ln[j] * W[512 + k];
        a2 += ln[j] * W[1024 + k];
    }
#pragma unroll
    for (int off = 32; off; off >>= 1) {
        a0 += __shfl_down(a0, off);
        a1 += __shfl_down(a1, off);
        a2 += __shfl_down(a2, off);
    }
    if (lane == 0) {
        hlin3[row * 3 + 0] = f2bf(a0);
        hlin3[row * 3 + 1] = f2bf(a1);
        hlin3[row * 3 + 2] = f2bf(a2);
        alsrc[row] = a0 * a_s[0] + a1 * a_s[1] + a2 * a_s[2];
        aldst[row] = a0 * a_d[0] + a1 * a_d[1] + a2 * a_d[2];
    }
}

// ============================ fast softmax+aggregate (heads=8, co=64) ============================
// wave per (node, head). Softmax computed ONCE in registers (lane = edge slot),
// then 2 edges/iteration channel aggregation (lane>>5 = edge parity, lane&31 = channel pair).
__global__ __launch_bounds__(256) void k_agg2(const bf16u* __restrict__ hlin,
                                              const float* __restrict__ alsrc,
                                              const float* __restrict__ aldst,
                                              const int* __restrict__ rowptr,
                                              const int* __restrict__ col,
                                              const float* __restrict__ bias,
                                              bf16u* __restrict__ hio,
                                              int n, int dores) {
    int gw = (blockIdx.x * 256 + threadIdx.x) >> 6;
    int lane = threadIdx.x & 63;
    int node = gw >> 3;
    int h = gw & 7;
    if (node >= n) return;
    int beg = rowptr[node], end = rowptr[node + 1];
    int deg = end - beg;
    float ad = aldst[node * 8 + h];

    if (deg <= 64) {
        // ---- prologue: per-lane edge logit, butterfly max/sum, exp once ----
        int srcreg = 0;
        float val = -INFINITY;
        if (lane < deg) {
            srcreg = col[beg + lane];
            float v = alsrc[srcreg * 8 + h] + ad;
            val = (v >= 0.f) ? v : NEG_SLOPE * v;
        }
        float m = val;
#pragma unroll
        for (int off = 32; off; off >>= 1) m = fmaxf(m, __shfl_xor(m, off));
        float expv = (lane < deg) ? __expf(val - m) : 0.f;
        float s = expv;
#pragma unroll
        for (int off = 32; off; off >>= 1) s += __shfl_xor(s, off);
        float inv = 1.0f / s;

        // ---- aggregate: 2 edges per iteration ----
        int sub = lane >> 5;        // edge parity
        int cl = lane & 31;         // channel pair
        float acc0 = 0.f, acc1 = 0.f;
        for (int j0 = 0; j0 < deg; j0 += 2) {
            int j = j0 + sub;
            float alpha = __shfl(expv, j) * inv;      // 0 for j >= deg
            int src = __shfl(srcreg, j);              // 0 for j >= deg (safe addr)
            unsigned int u = *(const unsigned int*)(hlin + (size_t)src * 512 + h * 64 + cl * 2);
            acc0 = fmaf(alpha, bf2f(u & 0xFFFFu), acc0);
            acc1 = fmaf(alpha, bf2f(u >> 16), acc1);
        }
        acc0 += __shfl_xor(acc0, 32);
        acc1 += __shfl_xor(acc1, 32);
        if (lane < 32) {
            float2 bv = *(const float2*)(bias + h * 64 + cl * 2);
            float v0 = acc0 + bv.x, v1 = acc1 + bv.y;
            float ge0 = 0.5f * v0 * (1.0f + erff(v0 * 0.70710678118654752f));
            float ge1 = 0.5f * v1 * (1.0f + erff(v1 * 0.70710678118654752f));
            size_t idx = (size_t)node * 512 + h * 64 + cl * 2;
            if (dores) {
                unsigned int up = *(const unsigned int*)(hio + idx);
                ge0 += bf2f(up & 0xFFFFu);
                ge1 += bf2f(up >> 16);
            }
            *(unsigned int*)(hio + idx) =
                (unsigned int)f2bf(ge0) | ((unsigned int)f2bf(ge1) << 16);
        }
    } else {
        // ---- fallback (deg > 64): 3-pass, lane = channel ----
        float m = -INFINITY;
        for (int e = beg + lane; e < end; e += 64) {
            float v = alsrc[col[e] * 8 + h] + ad;
            v = (v >= 0.f) ? v : NEG_SLOPE * v;
            m = fmaxf(m, v);
        }
#pragma unroll
        for (int off = 32; off; off >>= 1) m = fmaxf(m, __shfl_xor(m, off));
        float s = 0.f;
        for (int e = beg + lane; e < end; e += 64) {
            float v = alsrc[col[e] * 8 + h] + ad;
            v = (v >= 0.f) ? v : NEG_SLOPE * v;
            s += __expf(v - m);
        }
#pragma unroll
        for (int off = 32; off; off >>= 1) s += __shfl_xor(s, off);
        float inv = 1.0f / s;
        float acc = 0.f;
        for (int e = beg; e < end; e++) {
            int src = col[e];
            float v = alsrc[src * 8 + h] + ad;
            v = (v >= 0.f) ? v : NEG_SLOPE * v;
            float alpha = __expf(v - m) * inv;
            acc = fmaf(alpha, bf2f(hlin[(size_t)src * 512 + h * 64 + lane]), acc);
        }
        float v = acc + bias[h * 64 + lane];
        float ge = 0.5f * v * (1.0f + erff(v * 0.70710678118654752f));
        size_t idx = (size_t)node * 512 + h * 64 + lane;
        if (dores) ge += bf2f(hio[idx]);
        hio[idx] = f2bf(ge);
    }
}

// ============================ general softmax+aggregate (final layer) ============================
__global__ __launch_bounds__(256) void k_agg(const bf16u* __restrict__ hlin,
                                             const float* __restrict__ alsrc,
                                             const float* __restrict__ aldst,
                                             const int* __restrict__ rowptr,
                                             const int* __restrict__ col,
                                             const float* __restrict__ bias,
                                             float* __restrict__ outf,
                                             const float* __restrict__ resid,
                                             int n, int heads, int co) {
    int gw = (blockIdx.x * 256 + threadIdx.x) >> 6;
    int lane = threadIdx.x & 63;
    int node = gw / heads;
    int h = gw - node * heads;
    if (node >= n) return;
    int K = heads * co;
    int beg = rowptr[node], end = rowptr[node + 1];
    float ad = aldst[node * heads + h];

    float m = -INFINITY;
    for (int e = beg + lane; e < end; e += 64) {
        float v = alsrc[col[e] * heads + h] + ad;
        v = (v >= 0.f) ? v : NEG_SLOPE * v;
        m = fmaxf(m, v);
    }
#pragma unroll
    for (int off = 32; off; off >>= 1) m = fmaxf(m, __shfl_xor(m, off));

    float s = 0.f;
    for (int e = beg + lane; e < end; e += 64) {
        float v = alsrc[col[e] * heads + h] + ad;
        v = (v >= 0.f) ? v : NEG_SLOPE * v;
        s += __expf(v - m);
    }
#pragma unroll
    for (int off = 32; off; off >>= 1) s += __shfl_xor(s, off);
    s = __shfl(s, 0);
    float inv = 1.0f / s;

    float acc = 0.f;
    for (int e = beg; e < end; e++) {
        int src = col[e];
        float v = alsrc[src * heads + h] + ad;
        v = (v >= 0.f) ? v : NEG_SLOPE * v;
        float alpha = __expf(v - m) * inv;
        if (lane < co) acc += alpha * bf2f(hlin[(size_t)src * K + h * co + lane]);
    }
    if (lane < co) {
        float v = acc + bias[lane];
        outf[node * 3 + lane] = v + resid[node * 3 + lane];
    }
}

// ============================ launch ============================
extern "C" void kernel_launch(void* const* d_in, const int* in_sizes, int n_in,
                              void* d_out, int out_size, void* d_ws, size_t ws_size,
                              hipStream_t stream) {
    const float* x    = (const float*)d_in[0];
    const int*   ei   = (const int*)d_in[1];
    const float* resW = (const float*)d_in[2];
    const float* resb = (const float*)d_in[3];
    const float *lng[4], *lnb[4], *Wm[4], *asr[4], *adt[4], *bias[4];
    int idx = 4;
    for (int i = 0; i < 4; i++) {
        lng[i]  = (const float*)d_in[idx++];
        lnb[i]  = (const float*)d_in[idx++];
        Wm[i]   = (const float*)d_in[idx++];
        asr[i]  = (const float*)d_in[idx++];
        adt[i]  = (const float*)d_in[idx++];
        bias[i] = (const float*)d_in[idx++];
    }

    char* base = (char*)d_ws;
    size_t off = 0;
    auto alloc = [&](size_t bytes) {
        void* p = base + off;
        off += (bytes + 255) & ~(size_t)255;
        return p;
    };
    bf16u* hbuf  = (bf16u*)alloc((size_t)MPAD * 512 * 2);
    bf16u* lbuf  = (bf16u*)alloc((size_t)MPAD * 512 * 2);
    bf16u* wb0   = (bf16u*)alloc((size_t)512 * 128 * 2);
    bf16u* wb1   = (bf16u*)alloc((size_t)512 * 512 * 2);
    bf16u* wb2   = (bf16u*)alloc((size_t)512 * 512 * 2);
    float* stats = (float*)alloc((size_t)MPAD * 2 * 4);
    float* alsrc = (float*)alloc((size_t)NN * 8 * 4);
    float* aldst = (float*)alloc((size_t)NN * 8 * 4);
    float* resid = (float*)alloc((size_t)NN * 3 * 4);
    int* rowptr  = (int*)alloc((size_t)(NN + 1) * 4);
    int* cursor  = (int*)alloc((size_t)NN * 4);
    int* deg     = (int*)alloc((size_t)NN * 4);
    int* colidx  = (int*)alloc((size_t)NE * 4);
    int* bsums   = (int*)alloc(256 * 4);
    if (off > ws_size) return;

    float* out = (float*)d_out;

    // ---- CSR build ----
    k_zero_i32<<<(NN + 255) / 256, 256, 0, stream>>>(deg, NN);
    k_deg<<<(NE + 255) / 256, 256, 0, stream>>>(ei, deg);
    int nb = (NN + 1023) / 1024;
    k_scan1<<<nb, 256, 0, stream>>>(deg, rowptr, bsums, NN);
    k_scan2<<<1, 64, 0, stream>>>(bsums, nb);
    k_scan3<<<(NN + 1 + 255) / 256, 256, 0, stream>>>(deg, rowptr, cursor, bsums, NN, NE);
    k_scatter<<<(NE + 255) / 256, 256, 0, stream>>>(ei, cursor, colidx);

    // ---- residual head + input cast + weight casts ----
    k_residual<<<(NN * 64 + 255) / 256, 256, 0, stream>>>(x, resW, resb, resid);
    k_cast<<<(NN * IN_F + 255) / 256, 256, 0, stream>>>(x, hbuf, NN * IN_F);
    k_cast<<<(512 * 128 + 255) / 256, 256, 0, stream>>>(Wm[0], wb0, 512 * 128);
    k_cast<<<(512 * 512 + 255) / 256, 256, 0, stream>>>(Wm[1], wb1, 512 * 512);
    k_cast<<<(512 * 512 + 255) / 256, 256, 0, stream>>>(Wm[2], wb2, 512 * 512);

    const bf16u* wb[3] = {wb0, wb1, wb2};
    const int ci_a[3] = {128, 512, 512};

    int rowWaves = (NN * 64 + 255) / 256;
    for (int i = 0; i < 3; i++) {
        int ci = ci_a[i];
        int dores = (i >= 1) ? 1 : 0;

        k_lnstats<<<rowWaves, 256, 0, stream>>>(hbuf, stats, NN, ci);

        dim3 ggrid(MPAD / BM, 512 / BN);
        k_gemm_mfma<<<ggrid, 256, 0, stream>>>(hbuf, stats, lng[i], lnb[i], wb[i],
                                               lbuf, NN, ci, 512);

        k_al<<<rowWaves, 256, 0, stream>>>(lbuf, asr[i], adt[i], alsrc, aldst, NN, 8, 64);

        int aggBlocks = (int)(((size_t)NN * 8 * 64 + 255) / 256);
        k_agg2<<<aggBlocks, 256, 0, stream>>>(lbuf, alsrc, aldst, rowptr, colidx,
                                              bias[i], hbuf, NN, dores);
    }

    // ---- layer 3: matvec + logits, then final aggregate into d_out ----
    k_lnstats<<<rowWaves, 256, 0, stream>>>(hbuf, stats, NN, 512);
    k_lin3<<<rowWaves, 256, 0, stream>>>(hbuf, stats, lng[3], lnb[3], Wm[3],
                                         asr[3], adt[3], lbuf, alsrc, aldst, NN);
    int aggBlocks3 = (int)(((size_t)NN * 1 * 64 + 255) / 256);
    k_agg<<<aggBlocks3, 256, 0, stream>>>(lbuf, alsrc, aldst, rowptr, colidx,
                                          bias[3], out, resid, NN, 1, 3);
}

// Round 5
// 704.458 us; speedup vs baseline: 4.2574x; 1.7796x over previous
//
#include <hip/hip_runtime.h>
#include <math.h>

#define NN 50000
#define MPAD 50048          // 391 * 128
#define EE 400000
#define NE 450000           // EE + NN self loops
#define IN_F 128
#define NEG_SLOPE 0.2f
#define EPSV 1e-6f

typedef unsigned short bf16u;
typedef short bf8_t __attribute__((ext_vector_type(8)));
typedef float f32x4 __attribute__((ext_vector_type(4)));

__device__ __forceinline__ float bf2f(unsigned int u) {
    return __uint_as_float(u << 16);
}
__device__ __forceinline__ bf16u f2bf(float f) {
    unsigned int u = __float_as_uint(f);
    unsigned int r = (u + 0x7FFFu + ((u >> 16) & 1u)) >> 16;
    return (bf16u)r;
}
__device__ __forceinline__ float gelu_f(float v) {
    return 0.5f * v * (1.0f + erff(v * 0.70710678118654752f));
}

__device__ __forceinline__ void gload_lds16(const void* g, void* l) {
    __builtin_amdgcn_global_load_lds(
        (__attribute__((address_space(1))) void*)(g),
        (__attribute__((address_space(3))) void*)(l), 16, 0, 0);
}

// ============================ CSR build ============================
__global__ void k_zero_i32(int* p, int n) {
    int i = blockIdx.x * 256 + threadIdx.x;
    if (i < n) p[i] = 0;
}

__global__ void k_deg(const int* __restrict__ ei, int* __restrict__ deg) {
    int i = blockIdx.x * 256 + threadIdx.x;
    if (i >= NE) return;
    int d = (i < EE) ? ei[EE + i] : (i - EE);
    atomicAdd(&deg[d], 1);
}

__global__ __launch_bounds__(256) void k_scan1(const int* __restrict__ deg,
                                               int* __restrict__ incl,
                                               int* __restrict__ bsums, int n) {
    __shared__ int sm[1024];
    int base = blockIdx.x * 1024;
    for (int i = threadIdx.x; i < 1024; i += 256)
        sm[i] = (base + i < n) ? deg[base + i] : 0;
    __syncthreads();
    for (int off = 1; off < 1024; off <<= 1) {
        int v[4];
#pragma unroll
        for (int j = 0; j < 4; j++) {
            int i = threadIdx.x + 256 * j;
            v[j] = (i >= off) ? sm[i - off] : 0;
        }
        __syncthreads();
#pragma unroll
        for (int j = 0; j < 4; j++) {
            int i = threadIdx.x + 256 * j;
            sm[i] += v[j];
        }
        __syncthreads();
    }
    for (int i = threadIdx.x; i < 1024; i += 256)
        if (base + i < n) incl[base + i] = sm[i];
    if (threadIdx.x == 0) bsums[blockIdx.x] = sm[1023];
}

__global__ void k_scan2(int* bsums, int nb) {
    if (threadIdx.x == 0 && blockIdx.x == 0) {
        int run = 0;
        for (int i = 0; i < nb; i++) { int v = bsums[i]; bsums[i] = run; run += v; }
    }
}

__global__ void k_scan3(const int* __restrict__ deg, int* __restrict__ rowptr,
                        int* __restrict__ cursor, const int* __restrict__ bsums,
                        int n, int ne) {
    int i = blockIdx.x * 256 + threadIdx.x;
    if (i < n) {
        int excl = rowptr[i] + bsums[i >> 10] - deg[i];
        rowptr[i] = excl;
        cursor[i] = excl;
    }
    if (i == n) rowptr[n] = ne;
}

__global__ void k_scatter(const int* __restrict__ ei, int* __restrict__ cursor,
                          int* __restrict__ col) {
    int i = blockIdx.x * 256 + threadIdx.x;
    if (i >= NE) return;
    int s, d;
    if (i < EE) { s = ei[i]; d = ei[EE + i]; }
    else        { s = i - EE; d = i - EE; }
    int p = atomicAdd(&cursor[d], 1);
    col[p] = s;
}

// ============================ f32 -> bf16 cast (weights) ============================
__global__ void k_cast(const float* __restrict__ x, bf16u* __restrict__ h, int total) {
    int i = blockIdx.x * 256 + threadIdx.x;
    if (i < total) h[i] = f2bf(x[i]);
}

// ============================ cast x -> bf16 + LN stats (ci=128) ============================
__global__ __launch_bounds__(256) void k_castln(const float* __restrict__ x,
                                                bf16u* __restrict__ h,
                                                float* __restrict__ stats, int n) {
    int row = (blockIdx.x * 256 + threadIdx.x) >> 6;
    int lane = threadIdx.x & 63;
    if (row >= n) return;
    float2 v = *(const float2*)(x + (size_t)row * 128 + lane * 2);
    unsigned int pk = (unsigned int)f2bf(v.x) | ((unsigned int)f2bf(v.y) << 16);
    *(unsigned int*)(h + (size_t)row * 128 + lane * 2) = pk;
    float s = v.x + v.y, s2 = v.x * v.x + v.y * v.y;
#pragma unroll
    for (int off = 32; off; off >>= 1) {
        s  += __shfl_xor(s, off);
        s2 += __shfl_xor(s2, off);
    }
    if (lane == 0) {
        float mu = s * (1.0f / 128.0f);
        float var = s2 * (1.0f / 128.0f) - mu * mu;
        stats[row * 2 + 0] = mu;
        stats[row * 2 + 1] = rsqrtf(var + EPSV);
    }
}

// ============================ residual head ============================
__global__ __launch_bounds__(256) void k_residual(const float* __restrict__ x,
                                                  const float* __restrict__ rw,
                                                  const float* __restrict__ rb,
                                                  float* __restrict__ res) {
    int gw = (blockIdx.x * 256 + threadIdx.x) >> 6;
    int lane = threadIdx.x & 63;
    if (gw >= NN) return;
    float a0 = 0.f, a1 = 0.f, a2 = 0.f;
    for (int k = lane; k < IN_F; k += 64) {
        float xv = x[(size_t)gw * IN_F + k];
        a0 += xv * rw[0 * IN_F + k];
        a1 += xv * rw[1 * IN_F + k];
        a2 += xv * rw[2 * IN_F + k];
    }
#pragma unroll
    for (int off = 32; off; off >>= 1) {
        a0 += __shfl_down(a0, off);
        a1 += __shfl_down(a1, off);
        a2 += __shfl_down(a2, off);
    }
    if (lane == 0) {
        res[gw * 3 + 0] = a0 + rb[0];
        res[gw * 3 + 1] = a1 + rb[1];
        res[gw * 3 + 2] = a2 + rb[2];
    }
}

// ============================ MFMA GEMM with fused LN on A ============================
#define BM 128
#define BN 128
#define BKK 32
__global__ __launch_bounds__(256) void k_gemm_mfma(const bf16u* __restrict__ H,
                                                   const float* __restrict__ stats,
                                                   const float* __restrict__ g,
                                                   const float* __restrict__ bbias,
                                                   const bf16u* __restrict__ Wb,
                                                   bf16u* __restrict__ C,
                                                   int Mreal, int ci, int K) {
    __shared__ __align__(16) bf16u As[BM * BKK];
    __shared__ __align__(16) bf16u Bs[BN * BKK];
    const int tid = threadIdx.x;
    const int w = tid >> 6, lane = tid & 63;
    const int row0 = blockIdx.x * BM, col0 = blockIdx.y * BN;
    const int wr = (w >> 1) * 64, wc = (w & 1) * 64;

    const int srow = w * 32 + (lane >> 2);
    const int scol = (lane & 3) * 8;
    const bf16u* gA = H + (size_t)(row0 + srow) * ci + scol;
    const bf16u* gB = Wb + (size_t)(col0 + srow) * ci + scol;
    const float mu1 = stats[(row0 + srow) * 2 + 0];
    const float rs1 = stats[(row0 + srow) * 2 + 1];
    const float mu2 = stats[(row0 + srow + 16) * 2 + 0];
    const float rs2 = stats[(row0 + srow + 16) * 2 + 1];
    bf16u* lA1 = &As[(size_t)srow * BKK + scol];
    bf16u* lA2 = &As[(size_t)(srow + 16) * BKK + scol];
    void* lB1 = &Bs[(size_t)(w * 32) * BKK];
    void* lB2 = &Bs[(size_t)(w * 32 + 16) * BKK];

    f32x4 acc[4][4] = {};

    const int fr = lane & 15;
    const int fk = (lane >> 4) * 8;

    for (int k0 = 0; k0 < ci; k0 += BKK) {
        uint4 ra1 = *(const uint4*)(gA + k0);
        uint4 ra2 = *(const uint4*)(gA + (size_t)16 * ci + k0);
        float4 g0 = *(const float4*)(g + k0 + scol);
        float4 g1 = *(const float4*)(g + k0 + scol + 4);
        float4 b0 = *(const float4*)(bbias + k0 + scol);
        float4 b1 = *(const float4*)(bbias + k0 + scol + 4);
        float gg[8] = {g0.x, g0.y, g0.z, g0.w, g1.x, g1.y, g1.z, g1.w};
        float bb[8] = {b0.x, b0.y, b0.z, b0.w, b1.x, b1.y, b1.z, b1.w};
        unsigned int u1[4] = {ra1.x, ra1.y, ra1.z, ra1.w};
        unsigned int u2[4] = {ra2.x, ra2.y, ra2.z, ra2.w};
        uint4 p1, p2;
        {
            unsigned int po[4], qo[4];
#pragma unroll
            for (int j = 0; j < 4; j++) {
                float va = (bf2f(u1[j] & 0xFFFFu) - mu1) * rs1;
                float vb = (bf2f(u1[j] >> 16)     - mu1) * rs1;
                float oa = fmaf(va, gg[2 * j], bb[2 * j]);
                float ob = fmaf(vb, gg[2 * j + 1], bb[2 * j + 1]);
                po[j] = (unsigned int)f2bf(oa) | ((unsigned int)f2bf(ob) << 16);
                float vc = (bf2f(u2[j] & 0xFFFFu) - mu2) * rs2;
                float vd = (bf2f(u2[j] >> 16)     - mu2) * rs2;
                float oc = fmaf(vc, gg[2 * j], bb[2 * j]);
                float od = fmaf(vd, gg[2 * j + 1], bb[2 * j + 1]);
                qo[j] = (unsigned int)f2bf(oc) | ((unsigned int)f2bf(od) << 16);
            }
            p1 = make_uint4(po[0], po[1], po[2], po[3]);
            p2 = make_uint4(qo[0], qo[1], qo[2], qo[3]);
        }

        __syncthreads();
        *(uint4*)lA1 = p1;
        *(uint4*)lA2 = p2;
        gload_lds16(gB + k0, lB1);
        gload_lds16(gB + (size_t)16 * ci + k0, lB2);
        __syncthreads();

        bf8_t af[4], bf[4];
#pragma unroll
        for (int m = 0; m < 4; m++)
            af[m] = *(const bf8_t*)&As[(size_t)(wr + m * 16 + fr) * BKK + fk];
#pragma unroll
        for (int n = 0; n < 4; n++)
            bf[n] = *(const bf8_t*)&Bs[(size_t)(wc + n * 16 + fr) * BKK + fk];
#pragma unroll
        for (int m = 0; m < 4; m++)
#pragma unroll
            for (int n = 0; n < 4; n++)
                acc[m][n] = __builtin_amdgcn_mfma_f32_16x16x32_bf16(af[m], bf[n], acc[m][n], 0, 0, 0);
    }

    const int fc = lane & 15;
    const int fq = (lane >> 4) * 4;
#pragma unroll
    for (int m = 0; m < 4; m++) {
#pragma unroll
        for (int r = 0; r < 4; r++) {
            int row = row0 + wr + m * 16 + fq + r;
            if (row >= Mreal) continue;
#pragma unroll
            for (int n = 0; n < 4; n++) {
                int col = col0 + wc + n * 16 + fc;
                C[(size_t)row * K + col] = f2bf(acc[m][n][r]);
            }
        }
    }
}

// ============================ attention logits, vectorized (heads=8, co=64) ============================
// wave per row: lane covers 8 channels; head = lane>>3; reduce within 8-lane groups.
__global__ __launch_bounds__(256) void k_al2(const bf16u* __restrict__ hlin,
                                             const float* __restrict__ asr,
                                             const float* __restrict__ adt,
                                             float* __restrict__ alsrc,
                                             float* __restrict__ aldst, int n) {
    int row = (blockIdx.x * 256 + threadIdx.x) >> 6;
    int lane = threadIdx.x & 63;
    if (row >= n) return;
    int h = lane >> 3, c0 = (lane & 7) * 8;
    uint4 u = *(const uint4*)(hlin + (size_t)row * 512 + lane * 8);
    const float* as = asr + h * 64 + c0;
    const float* ad = adt + h * 64 + c0;
    float4 s0 = *(const float4*)as, s1 = *(const float4*)(as + 4);
    float4 d0 = *(const float4*)ad, d1 = *(const float4*)(ad + 4);
    float v0 = bf2f(u.x & 0xFFFFu), v1 = bf2f(u.x >> 16);
    float v2 = bf2f(u.y & 0xFFFFu), v3 = bf2f(u.y >> 16);
    float v4 = bf2f(u.z & 0xFFFFu), v5 = bf2f(u.z >> 16);
    float v6 = bf2f(u.w & 0xFFFFu), v7 = bf2f(u.w >> 16);
    float ss = v0 * s0.x + v1 * s0.y + v2 * s0.z + v3 * s0.w
             + v4 * s1.x + v5 * s1.y + v6 * s1.z + v7 * s1.w;
    float dd = v0 * d0.x + v1 * d0.y + v2 * d0.z + v3 * d0.w
             + v4 * d1.x + v5 * d1.y + v6 * d1.z + v7 * d1.w;
#pragma unroll
    for (int off = 4; off; off >>= 1) {
        ss += __shfl_xor(ss, off);
        dd += __shfl_xor(dd, off);
    }
    if ((lane & 7) == 0) {
        alsrc[row * 8 + h] = ss;
        aldst[row * 8 + h] = dd;
    }
}

// ============================ layer-3 matvec + logits ============================
__global__ __launch_bounds__(256) void k_lin3(const bf16u* __restrict__ h,
                                              const float* __restrict__ stats,
                                              const float* __restrict__ g,
                                              const float* __restrict__ bb,
                                              const float* __restrict__ W,
                                              const float* __restrict__ a_s,
                                              const float* __restrict__ a_d,
                                              bf16u* __restrict__ hlin3,
                                              float* __restrict__ alsrc,
                                              float* __restrict__ aldst, int n) {
    int row = (blockIdx.x * 256 + threadIdx.x) >> 6;
    int lane = threadIdx.x & 63;
    if (row >= n) return;
    float mu = stats[row * 2 + 0], rs = stats[row * 2 + 1];
    uint4 r = *(const uint4*)(h + (size_t)row * 512 + lane * 8);
    float4 g0 = *(const float4*)(g + lane * 8);
    float4 g1 = *(const float4*)(g + lane * 8 + 4);
    float4 b0 = *(const float4*)(bb + lane * 8);
    float4 b1 = *(const float4*)(bb + lane * 8 + 4);
    float gg[8] = {g0.x, g0.y, g0.z, g0.w, g1.x, g1.y, g1.z, g1.w};
    float bv[8] = {b0.x, b0.y, b0.z, b0.w, b1.x, b1.y, b1.z, b1.w};
    unsigned int u[4] = {r.x, r.y, r.z, r.w};
    float ln[8];
#pragma unroll
    for (int j = 0; j < 4; j++) {
        ln[2 * j]     = fmaf((bf2f(u[j] & 0xFFFFu) - mu) * rs, gg[2 * j], bv[2 * j]);
        ln[2 * j + 1] = fmaf((bf2f(u[j] >> 16)     - mu) * rs, gg[2 * j + 1], bv[2 * j + 1]);
    }
    float a0 = 0.f, a1 = 0.f, a2 = 0.f;
#pragma unroll
    for (int j = 0; j < 8; j++) {
        int k = lane * 8 + j;
        a0 += ln[j] * W[k];
        a1 += ln[j] * W[512 + k];
        a2 += ln[j] * W[1024 + k];
    }
#pragma unroll
    for (int off = 32; off; off >>= 1) {
        a0 += __shfl_down(a0, off);
        a1 += __shfl_down(a1, off);
        a2 += __shfl_down(a2, off);
    }
    if (lane == 0) {
        hlin3[row * 3 + 0] = f2bf(a0);
        hlin3[row * 3 + 1] = f2bf(a1);
        hlin3[row * 3 + 2] = f2bf(a2);
        alsrc[row] = a0 * a_s[0] + a1 * a_s[1] + a2 * a_s[2];
        aldst[row] = a0 * a_d[0] + a1 * a_d[1] + a2 * a_d[2];
    }
}

// ============================ all-head softmax+aggregate, wave per NODE ============================
// Fuses: leaky-relu softmax (all 8 heads), aggregation (full 512-ch row per uint4/lane),
// bias + GELU + optional residual add (in-place), and next layer's LN stats.
__global__ __launch_bounds__(256) void k_aggN(const bf16u* __restrict__ hlin,
                                              const float* __restrict__ alsrc,
                                              const float* __restrict__ aldst,
                                              const int* __restrict__ rowptr,
                                              const int* __restrict__ col,
                                              const float* __restrict__ bias,
                                              bf16u* __restrict__ hio,
                                              float* __restrict__ stats,
                                              int n, int dores) {
    __shared__ float alds[4][8][66];
    int wv = threadIdx.x >> 6;
    int node = (blockIdx.x * 256 + threadIdx.x) >> 6;
    int lane = threadIdx.x & 63;
    if (node >= n) return;
    int beg = rowptr[node], end = rowptr[node + 1];
    int deg = end - beg;

    // per-node (wave-uniform) dst logits
    const float4* dv = (const float4*)(aldst + node * 8);
    float4 da = dv[0], db = dv[1];
    float ad[8] = {da.x, da.y, da.z, da.w, db.x, db.y, db.z, db.w};

    float s = 0.f, s2 = 0.f;      // LN stats accumulators (over final row)

    if (deg <= 64) {
        // ---- prologue: lane j owns edge j ----
        int srcreg = 0;
        float raw[8];
#pragma unroll
        for (int h = 0; h < 8; h++) raw[h] = -INFINITY;
        if (lane < deg) {
            srcreg = col[beg + lane];
            const float4* sv = (const float4*)(alsrc + srcreg * 8);
            float4 sa = sv[0], sb = sv[1];
            float sl[8] = {sa.x, sa.y, sa.z, sa.w, sb.x, sb.y, sb.z, sb.w};
#pragma unroll
            for (int h = 0; h < 8; h++) {
                float v = sl[h] + ad[h];
                raw[h] = (v >= 0.f) ? v : NEG_SLOPE * v;
            }
        }
        float m[8];
#pragma unroll
        for (int h = 0; h < 8; h++) m[h] = raw[h];
#pragma unroll
        for (int off = 32; off; off >>= 1)
#pragma unroll
            for (int h = 0; h < 8; h++) m[h] = fmaxf(m[h], __shfl_xor(m[h], off));
        float ex[8], sm[8];
#pragma unroll
        for (int h = 0; h < 8; h++) {
            ex[h] = (lane < deg) ? __expf(raw[h] - m[h]) : 0.f;
            sm[h] = ex[h];
        }
#pragma unroll
        for (int off = 32; off; off >>= 1)
#pragma unroll
            for (int h = 0; h < 8; h++) sm[h] += __shfl_xor(sm[h], off);
#pragma unroll
        for (int h = 0; h < 8; h++)
            alds[wv][h][lane] = ex[h] * (1.0f / sm[h]);
        asm volatile("s_waitcnt lgkmcnt(0)" ::: "memory");

        // ---- aggregate: one uint4 (8 ch) per lane per edge ----
        int hl = lane >> 3;
        const float* myal = &alds[wv][hl][0];
        float acc[8] = {};
        for (int e = 0; e < deg; e++) {
            float alpha = myal[e];
            int src = __shfl(srcreg, e);
            uint4 u = *(const uint4*)(hlin + ((size_t)src << 9) + (lane << 3));
            acc[0] = fmaf(alpha, bf2f(u.x & 0xFFFFu), acc[0]);
            acc[1] = fmaf(alpha, bf2f(u.x >> 16),     acc[1]);
            acc[2] = fmaf(alpha, bf2f(u.y & 0xFFFFu), acc[2]);
            acc[3] = fmaf(alpha, bf2f(u.y >> 16),     acc[3]);
            acc[4] = fmaf(alpha, bf2f(u.z & 0xFFFFu), acc[4]);
            acc[5] = fmaf(alpha, bf2f(u.z >> 16),     acc[5]);
            acc[6] = fmaf(alpha, bf2f(u.w & 0xFFFFu), acc[6]);
            acc[7] = fmaf(alpha, bf2f(u.w >> 16),     acc[7]);
        }

        // ---- epilogue: bias + gelu + residual, pack, LN stats ----
        size_t idx = (size_t)node * 512 + lane * 8;
        float4 b0 = *(const float4*)(bias + lane * 8);
        float4 b1 = *(const float4*)(bias + lane * 8 + 4);
        float bb[8] = {b0.x, b0.y, b0.z, b0.w, b1.x, b1.y, b1.z, b1.w};
        float fin[8];
#pragma unroll
        for (int j = 0; j < 8; j++) fin[j] = gelu_f(acc[j] + bb[j]);
        if (dores) {
            uint4 up = *(const uint4*)(hio + idx);
            fin[0] += bf2f(up.x & 0xFFFFu); fin[1] += bf2f(up.x >> 16);
            fin[2] += bf2f(up.y & 0xFFFFu); fin[3] += bf2f(up.y >> 16);
            fin[4] += bf2f(up.z & 0xFFFFu); fin[5] += bf2f(up.z >> 16);
            fin[6] += bf2f(up.w & 0xFFFFu); fin[7] += bf2f(up.w >> 16);
        }
        uint4 pk;
        pk.x = (unsigned int)f2bf(fin[0]) | ((unsigned int)f2bf(fin[1]) << 16);
        pk.y = (unsigned int)f2bf(fin[2]) | ((unsigned int)f2bf(fin[3]) << 16);
        pk.z = (unsigned int)f2bf(fin[4]) | ((unsigned int)f2bf(fin[5]) << 16);
        pk.w = (unsigned int)f2bf(fin[6]) | ((unsigned int)f2bf(fin[7]) << 16);
        *(uint4*)(hio + idx) = pk;
#pragma unroll
        for (int j = 0; j < 8; j++) { s += fin[j]; s2 += fin[j] * fin[j]; }
    } else {
        // ---- fallback (deg > 64): per-head 3-pass, lane = channel ----
        for (int h = 0; h < 8; h++) {
            float adh = ad[h];
            float m = -INFINITY;
            for (int e = beg + lane; e < end; e += 64) {
                float v = alsrc[col[e] * 8 + h] + adh;
                v = (v >= 0.f) ? v : NEG_SLOPE * v;
                m = fmaxf(m, v);
            }
#pragma unroll
            for (int off = 32; off; off >>= 1) m = fmaxf(m, __shfl_xor(m, off));
            float sum = 0.f;
            for (int e = beg + lane; e < end; e += 64) {
                float v = alsrc[col[e] * 8 + h] + adh;
                v = (v >= 0.f) ? v : NEG_SLOPE * v;
                sum += __expf(v - m);
            }
#pragma unroll
            for (int off = 32; off; off >>= 1) sum += __shfl_xor(sum, off);
            float inv = 1.0f / sum;
            float acc = 0.f;
            for (int e = beg; e < end; e++) {
                int src = col[e];
                float v = alsrc[src * 8 + h] + adh;
                v = (v >= 0.f) ? v : NEG_SLOPE * v;
                float alpha = __expf(v - m) * inv;
                acc = fmaf(alpha, bf2f(hlin[((size_t)src << 9) + h * 64 + lane]), acc);
            }
            float fin = gelu_f(acc + bias[h * 64 + lane]);
            size_t idx = (size_t)node * 512 + h * 64 + lane;
            if (dores) fin += bf2f(hio[idx]);
            hio[idx] = f2bf(fin);
            s += fin; s2 += fin * fin;
        }
    }

    // ---- LN stats for the next layer ----
#pragma unroll
    for (int off = 32; off; off >>= 1) {
        s  += __shfl_xor(s, off);
        s2 += __shfl_xor(s2, off);
    }
    if (lane == 0) {
        float mu = s * (1.0f / 512.0f);
        float var = s2 * (1.0f / 512.0f) - mu * mu;
        stats[node * 2 + 0] = mu;
        stats[node * 2 + 1] = rsqrtf(var + EPSV);
    }
}

// ============================ final softmax+aggregate (heads=1, co=3) ============================
__global__ __launch_bounds__(256) void k_aggF(const bf16u* __restrict__ hlin,
                                              const float* __restrict__ alsrc,
                                              const float* __restrict__ aldst,
                                              const int* __restrict__ rowptr,
                                              const int* __restrict__ col,
                                              const float* __restrict__ bias,
                                              float* __restrict__ outf,
                                              const float* __restrict__ resid, int n) {
    int node = (blockIdx.x * 256 + threadIdx.x) >> 6;
    int lane = threadIdx.x & 63;
    if (node >= n) return;
    int beg = rowptr[node], end = rowptr[node + 1];
    float adh = aldst[node];

    float m = -INFINITY;
    for (int e = beg + lane; e < end; e += 64) {
        float v = alsrc[col[e]] + adh;
        v = (v >= 0.f) ? v : NEG_SLOPE * v;
        m = fmaxf(m, v);
    }
#pragma unroll
    for (int off = 32; off; off >>= 1) m = fmaxf(m, __shfl_xor(m, off));

    float sum = 0.f;
    for (int e = beg + lane; e < end; e += 64) {
        float v = alsrc[col[e]] + adh;
        v = (v >= 0.f) ? v : NEG_SLOPE * v;
        sum += __expf(v - m);
    }
#pragma unroll
    for (int off = 32; off; off >>= 1) sum += __shfl_xor(sum, off);
    float inv = 1.0f / sum;

    float acc = 0.f;
    for (int e = beg; e < end; e++) {
        int src = col[e];
        float v = alsrc[src] + adh;
        v = (v >= 0.f) ? v : NEG_SLOPE * v;
        float alpha = __expf(v - m) * inv;
        if (lane < 3) acc += alpha * bf2f(hlin[(size_t)src * 3 + lane]);
    }
    if (lane < 3)
        outf[node * 3 + lane] = acc + bias[lane] + resid[node * 3 + lane];
}

// ============================ launch ============================
extern "C" void kernel_launch(void* const* d_in, const int* in_sizes, int n_in,
                              void* d_out, int out_size, void* d_ws, size_t ws_size,
                              hipStream_t stream) {
    const float* x    = (const float*)d_in[0];
    const int*   ei   = (const int*)d_in[1];
    const float* resW = (const float*)d_in[2];
    const float* resb = (const float*)d_in[3];
    const float *lng[4], *lnb[4], *Wm[4], *asr[4], *adt[4], *bias[4];
    int idx = 4;
    for (int i = 0; i < 4; i++) {
        lng[i]  = (const float*)d_in[idx++];
        lnb[i]  = (const float*)d_in[idx++];
        Wm[i]   = (const float*)d_in[idx++];
        asr[i]  = (const float*)d_in[idx++];
        adt[i]  = (const float*)d_in[idx++];
        bias[i] = (const float*)d_in[idx++];
    }

    char* base = (char*)d_ws;
    size_t off = 0;
    auto alloc = [&](size_t bytes) {
        void* p = base + off;
        off += (bytes + 255) & ~(size_t)255;
        return p;
    };
    bf16u* hbuf  = (bf16u*)alloc((size_t)MPAD * 512 * 2);
    bf16u* lbuf  = (bf16u*)alloc((size_t)MPAD * 512 * 2);
    bf16u* wb0   = (bf16u*)alloc((size_t)512 * 128 * 2);
    bf16u* wb1   = (bf16u*)alloc((size_t)512 * 512 * 2);
    bf16u* wb2   = (bf16u*)alloc((size_t)512 * 512 * 2);
    float* stats = (float*)alloc((size_t)MPAD * 2 * 4);
    float* alsrc = (float*)alloc((size_t)NN * 8 * 4);
    float* aldst = (float*)alloc((size_t)NN * 8 * 4);
    float* resid = (float*)alloc((size_t)NN * 3 * 4);
    int* rowptr  = (int*)alloc((size_t)(NN + 1) * 4);
    int* cursor  = (int*)alloc((size_t)NN * 4);
    int* deg     = (int*)alloc((size_t)NN * 4);
    int* colidx  = (int*)alloc((size_t)NE * 4);
    int* bsums   = (int*)alloc(256 * 4);
    if (off > ws_size) return;

    float* out = (float*)d_out;

    // ---- CSR build ----
    k_zero_i32<<<(NN + 255) / 256, 256, 0, stream>>>(deg, NN);
    k_deg<<<(NE + 255) / 256, 256, 0, stream>>>(ei, deg);
    int nb = (NN + 1023) / 1024;
    k_scan1<<<nb, 256, 0, stream>>>(deg, rowptr, bsums, NN);
    k_scan2<<<1, 64, 0, stream>>>(bsums, nb);
    k_scan3<<<(NN + 1 + 255) / 256, 256, 0, stream>>>(deg, rowptr, cursor, bsums, NN, NE);
    k_scatter<<<(NE + 255) / 256, 256, 0, stream>>>(ei, cursor, colidx);

    // ---- residual head + input cast (+layer-0 stats) + weight casts ----
    int rowBlocks = (NN * 64 + 255) / 256;       // 12500
    k_residual<<<rowBlocks, 256, 0, stream>>>(x, resW, resb, resid);
    k_castln<<<rowBlocks, 256, 0, stream>>>(x, hbuf, stats, NN);
    k_cast<<<(512 * 128 + 255) / 256, 256, 0, stream>>>(Wm[0], wb0, 512 * 128);
    k_cast<<<(512 * 512 + 255) / 256, 256, 0, stream>>>(Wm[1], wb1, 512 * 512);
    k_cast<<<(512 * 512 + 255) / 256, 256, 0, stream>>>(Wm[2], wb2, 512 * 512);

    const bf16u* wb[3] = {wb0, wb1, wb2};
    const int ci_a[3] = {128, 512, 512};

    for (int i = 0; i < 3; i++) {
        int ci = ci_a[i];
        int dores = (i >= 1) ? 1 : 0;

        dim3 ggrid(MPAD / BM, 512 / BN);
        k_gemm_mfma<<<ggrid, 256, 0, stream>>>(hbuf, stats, lng[i], lnb[i], wb[i],
                                               lbuf, NN, ci, 512);

        k_al2<<<rowBlocks, 256, 0, stream>>>(lbuf, asr[i], adt[i], alsrc, aldst, NN);

        k_aggN<<<rowBlocks, 256, 0, stream>>>(lbuf, alsrc, aldst, rowptr, colidx,
                                              bias[i], hbuf, stats, NN, dores);
    }

    // ---- layer 3: matvec + logits, then final aggregate into d_out ----
    k_lin3<<<rowBlocks, 256, 0, stream>>>(hbuf, stats, lng[3], lnb[3], Wm[3],
                                          asr[3], adt[3], lbuf, alsrc, aldst, NN);
    k_aggF<<<rowBlocks, 256, 0, stream>>>(lbuf, alsrc, aldst, rowptr, colidx,
                                          bias[3], out, resid, NN);
}

// Round 6
// 670.084 us; speedup vs baseline: 4.4758x; 1.0513x over previous
//
#include <hip/hip_runtime.h>
#include <math.h>

#define NN 50000
#define MPAD 50048          // 391 * 128
#define EE 400000
#define NE 450000           // EE + NN self loops
#define IN_F 128
#define NEG_SLOPE 0.2f
#define EPSV 1e-6f

typedef unsigned short bf16u;
typedef short bf8_t __attribute__((ext_vector_type(8)));
typedef float f32x4 __attribute__((ext_vector_type(4)));

__device__ __forceinline__ float bf2f(unsigned int u) {
    return __uint_as_float(u << 16);
}
__device__ __forceinline__ float bf2f_hi(unsigned int u) {
    return __uint_as_float(u & 0xFFFF0000u);
}
__device__ __forceinline__ bf16u f2bf(float f) {
    unsigned int u = __float_as_uint(f);
    unsigned int r = (u + 0x7FFFu + ((u >> 16) & 1u)) >> 16;
    return (bf16u)r;
}
__device__ __forceinline__ float gelu_f(float v) {
    return 0.5f * v * (1.0f + erff(v * 0.70710678118654752f));
}

__device__ __forceinline__ void gload_lds16(const void* g, void* l) {
    __builtin_amdgcn_global_load_lds(
        (__attribute__((address_space(1))) void*)(g),
        (__attribute__((address_space(3))) void*)(l), 16, 0, 0);
}

// ============================ CSR build ============================
__global__ void k_zero_i32(int* p, int n) {
    int i = blockIdx.x * 256 + threadIdx.x;
    if (i < n) p[i] = 0;
}

__global__ void k_deg(const int* __restrict__ ei, int* __restrict__ deg) {
    int i = blockIdx.x * 256 + threadIdx.x;
    if (i >= NE) return;
    int d = (i < EE) ? ei[EE + i] : (i - EE);
    atomicAdd(&deg[d], 1);
}

__global__ __launch_bounds__(256) void k_scan1(const int* __restrict__ deg,
                                               int* __restrict__ incl,
                                               int* __restrict__ bsums, int n) {
    __shared__ int sm[1024];
    int base = blockIdx.x * 1024;
    for (int i = threadIdx.x; i < 1024; i += 256)
        sm[i] = (base + i < n) ? deg[base + i] : 0;
    __syncthreads();
    for (int off = 1; off < 1024; off <<= 1) {
        int v[4];
#pragma unroll
        for (int j = 0; j < 4; j++) {
            int i = threadIdx.x + 256 * j;
            v[j] = (i >= off) ? sm[i - off] : 0;
        }
        __syncthreads();
#pragma unroll
        for (int j = 0; j < 4; j++) {
            int i = threadIdx.x + 256 * j;
            sm[i] += v[j];
        }
        __syncthreads();
    }
    for (int i = threadIdx.x; i < 1024; i += 256)
        if (base + i < n) incl[base + i] = sm[i];
    if (threadIdx.x == 0) bsums[blockIdx.x] = sm[1023];
}

__global__ void k_scan2(int* bsums, int nb) {
    if (threadIdx.x == 0 && blockIdx.x == 0) {
        int run = 0;
        for (int i = 0; i < nb; i++) { int v = bsums[i]; bsums[i] = run; run += v; }
    }
}

__global__ void k_scan3(const int* __restrict__ deg, int* __restrict__ rowptr,
                        int* __restrict__ cursor, const int* __restrict__ bsums,
                        int n, int ne) {
    int i = blockIdx.x * 256 + threadIdx.x;
    if (i < n) {
        int excl = rowptr[i] + bsums[i >> 10] - deg[i];
        rowptr[i] = excl;
        cursor[i] = excl;
    }
    if (i == n) rowptr[n] = ne;
}

__global__ void k_scatter(const int* __restrict__ ei, int* __restrict__ cursor,
                          int* __restrict__ col) {
    int i = blockIdx.x * 256 + threadIdx.x;
    if (i >= NE) return;
    int s, d;
    if (i < EE) { s = ei[i]; d = ei[EE + i]; }
    else        { s = i - EE; d = i - EE; }
    int p = atomicAdd(&cursor[d], 1);
    col[p] = s;
}

// ============================ f32 -> bf16 cast (weights) ============================
__global__ void k_cast(const float* __restrict__ x, bf16u* __restrict__ h, int total) {
    int i = blockIdx.x * 256 + threadIdx.x;
    if (i < total) h[i] = f2bf(x[i]);
}

// ============ fused: cast x -> bf16, LN stats (ci=128), residual head ============
__global__ __launch_bounds__(256) void k_castres(const float* __restrict__ x,
                                                 const float* __restrict__ rw,
                                                 const float* __restrict__ rb,
                                                 bf16u* __restrict__ h,
                                                 float* __restrict__ stats,
                                                 float* __restrict__ res, int n) {
    int row = (blockIdx.x * 256 + threadIdx.x) >> 6;
    int lane = threadIdx.x & 63;
    if (row >= n) return;
    float2 v = *(const float2*)(x + (size_t)row * 128 + lane * 2);
    unsigned int pk = (unsigned int)f2bf(v.x) | ((unsigned int)f2bf(v.y) << 16);
    *(unsigned int*)(h + (size_t)row * 128 + lane * 2) = pk;
    float2 w0 = *(const float2*)(rw + 0 * 128 + lane * 2);
    float2 w1 = *(const float2*)(rw + 1 * 128 + lane * 2);
    float2 w2 = *(const float2*)(rw + 2 * 128 + lane * 2);
    float s = v.x + v.y, s2 = v.x * v.x + v.y * v.y;
    float a0 = v.x * w0.x + v.y * w0.y;
    float a1 = v.x * w1.x + v.y * w1.y;
    float a2 = v.x * w2.x + v.y * w2.y;
#pragma unroll
    for (int off = 32; off; off >>= 1) {
        s  += __shfl_xor(s, off);
        s2 += __shfl_xor(s2, off);
        a0 += __shfl_xor(a0, off);
        a1 += __shfl_xor(a1, off);
        a2 += __shfl_xor(a2, off);
    }
    if (lane == 0) {
        float mu = s * (1.0f / 128.0f);
        float var = s2 * (1.0f / 128.0f) - mu * mu;
        stats[row * 2 + 0] = mu;
        stats[row * 2 + 1] = rsqrtf(var + EPSV);
        res[row * 3 + 0] = a0 + rb[0];
        res[row * 3 + 1] = a1 + rb[1];
        res[row * 3 + 2] = a2 + rb[2];
    }
}

// ============================ MFMA GEMM with fused LN on A + fused al epilogue ============
// C[M,K] = LN(A)[M,ci] @ Wb[K,ci]^T. BN=128 = 2 heads of 64 -> each wave's 64 cols
// are one full head; attention-logit dots computed from f32 accumulators in-register.
#define BM 128
#define BN 128
#define BKK 32
__global__ __launch_bounds__(256) void k_gemm_mfma(const bf16u* __restrict__ H,
                                                   const float* __restrict__ stats,
                                                   const float* __restrict__ g,
                                                   const float* __restrict__ bbias,
                                                   const bf16u* __restrict__ Wb,
                                                   bf16u* __restrict__ C,
                                                   const float* __restrict__ asr,
                                                   const float* __restrict__ adt,
                                                   float* __restrict__ alsrc,
                                                   float* __restrict__ aldst,
                                                   int Mreal, int ci, int K) {
    __shared__ __align__(16) bf16u As[BM * BKK];
    __shared__ __align__(16) bf16u Bs[BN * BKK];
    const int tid = threadIdx.x;
    const int w = tid >> 6, lane = tid & 63;
    const int row0 = blockIdx.x * BM, col0 = blockIdx.y * BN;
    const int wr = (w >> 1) * 64, wc = (w & 1) * 64;

    const int srow = w * 32 + (lane >> 2);
    const int scol = (lane & 3) * 8;
    const bf16u* gA = H + (size_t)(row0 + srow) * ci + scol;
    const bf16u* gB = Wb + (size_t)(col0 + srow) * ci + scol;
    const float mu1 = stats[(row0 + srow) * 2 + 0];
    const float rs1 = stats[(row0 + srow) * 2 + 1];
    const float mu2 = stats[(row0 + srow + 16) * 2 + 0];
    const float rs2 = stats[(row0 + srow + 16) * 2 + 1];
    bf16u* lA1 = &As[(size_t)srow * BKK + scol];
    bf16u* lA2 = &As[(size_t)(srow + 16) * BKK + scol];
    void* lB1 = &Bs[(size_t)(w * 32) * BKK];
    void* lB2 = &Bs[(size_t)(w * 32 + 16) * BKK];

    f32x4 acc[4][4] = {};

    const int fr = lane & 15;
    const int fk = (lane >> 4) * 8;

    for (int k0 = 0; k0 < ci; k0 += BKK) {
        uint4 ra1 = *(const uint4*)(gA + k0);
        uint4 ra2 = *(const uint4*)(gA + (size_t)16 * ci + k0);
        float4 g0 = *(const float4*)(g + k0 + scol);
        float4 g1 = *(const float4*)(g + k0 + scol + 4);
        float4 b0 = *(const float4*)(bbias + k0 + scol);
        float4 b1 = *(const float4*)(bbias + k0 + scol + 4);
        float gg[8] = {g0.x, g0.y, g0.z, g0.w, g1.x, g1.y, g1.z, g1.w};
        float bb[8] = {b0.x, b0.y, b0.z, b0.w, b1.x, b1.y, b1.z, b1.w};
        unsigned int u1[4] = {ra1.x, ra1.y, ra1.z, ra1.w};
        unsigned int u2[4] = {ra2.x, ra2.y, ra2.z, ra2.w};
        uint4 p1, p2;
        {
            unsigned int po[4], qo[4];
#pragma unroll
            for (int j = 0; j < 4; j++) {
                float va = (bf2f(u1[j] & 0xFFFFu) - mu1) * rs1;
                float vb = (bf2f_hi(u1[j])         - mu1) * rs1;
                float oa = fmaf(va, gg[2 * j], bb[2 * j]);
                float ob = fmaf(vb, gg[2 * j + 1], bb[2 * j + 1]);
                po[j] = (unsigned int)f2bf(oa) | ((unsigned int)f2bf(ob) << 16);
                float vc = (bf2f(u2[j] & 0xFFFFu) - mu2) * rs2;
                float vd = (bf2f_hi(u2[j])         - mu2) * rs2;
                float oc = fmaf(vc, gg[2 * j], bb[2 * j]);
                float od = fmaf(vd, gg[2 * j + 1], bb[2 * j + 1]);
                qo[j] = (unsigned int)f2bf(oc) | ((unsigned int)f2bf(od) << 16);
            }
            p1 = make_uint4(po[0], po[1], po[2], po[3]);
            p2 = make_uint4(qo[0], qo[1], qo[2], qo[3]);
        }

        __syncthreads();
        *(uint4*)lA1 = p1;
        *(uint4*)lA2 = p2;
        gload_lds16(gB + k0, lB1);
        gload_lds16(gB + (size_t)16 * ci + k0, lB2);
        __syncthreads();

        bf8_t af[4], bf[4];
#pragma unroll
        for (int m = 0; m < 4; m++)
            af[m] = *(const bf8_t*)&As[(size_t)(wr + m * 16 + fr) * BKK + fk];
#pragma unroll
        for (int n = 0; n < 4; n++)
            bf[n] = *(const bf8_t*)&Bs[(size_t)(wc + n * 16 + fr) * BKK + fk];
#pragma unroll
        for (int m = 0; m < 4; m++)
#pragma unroll
            for (int n = 0; n < 4; n++)
                acc[m][n] = __builtin_amdgcn_mfma_f32_16x16x32_bf16(af[m], bf[n], acc[m][n], 0, 0, 0);
    }

    const int fc = lane & 15;
    const int fq = (lane >> 4) * 4;

    // ---- C store ----
#pragma unroll
    for (int m = 0; m < 4; m++) {
#pragma unroll
        for (int r = 0; r < 4; r++) {
            int row = row0 + wr + m * 16 + fq + r;
            if (row >= Mreal) continue;
#pragma unroll
            for (int n = 0; n < 4; n++) {
                int col = col0 + wc + n * 16 + fc;
                C[(size_t)row * K + col] = f2bf(acc[m][n][r]);
            }
        }
    }

    // ---- fused attention-logit dots (head = this wave's 64 cols) ----
    const int head = blockIdx.y * 2 + (wc >> 6);
    float av[4], dv[4];
#pragma unroll
    for (int n = 0; n < 4; n++) {
        av[n] = asr[head * 64 + n * 16 + fc];
        dv[n] = adt[head * 64 + n * 16 + fc];
    }
#pragma unroll
    for (int m = 0; m < 4; m++) {
#pragma unroll
        for (int r = 0; r < 4; r++) {
            float s1 = acc[m][0][r] * av[0] + acc[m][1][r] * av[1]
                     + acc[m][2][r] * av[2] + acc[m][3][r] * av[3];
            float s2 = acc[m][0][r] * dv[0] + acc[m][1][r] * dv[1]
                     + acc[m][2][r] * dv[2] + acc[m][3][r] * dv[3];
#pragma unroll
            for (int o = 1; o < 16; o <<= 1) {
                s1 += __shfl_xor(s1, o);
                s2 += __shfl_xor(s2, o);
            }
            int row = row0 + wr + m * 16 + fq + r;
            if (fc == 0 && row < Mreal) {
                alsrc[row * 8 + head] = s1;
                aldst[row * 8 + head] = s2;
            }
        }
    }
}

// ============================ layer-3 matvec + logits ============================
// hlin3 stored with row stride 4 (padded) for aligned uint2 loads in k_aggF.
__global__ __launch_bounds__(256) void k_lin3(const bf16u* __restrict__ h,
                                              const float* __restrict__ stats,
                                              const float* __restrict__ g,
                                              const float* __restrict__ bb,
                                              const float* __restrict__ W,
                                              const float* __restrict__ a_s,
                                              const float* __restrict__ a_d,
                                              bf16u* __restrict__ hlin3,
                                              float* __restrict__ alsrc,
                                              float* __restrict__ aldst, int n) {
    int row = (blockIdx.x * 256 + threadIdx.x) >> 6;
    int lane = threadIdx.x & 63;
    if (row >= n) return;
    float mu = stats[row * 2 + 0], rs = stats[row * 2 + 1];
    uint4 r = *(const uint4*)(h + (size_t)row * 512 + lane * 8);
    float4 g0 = *(const float4*)(g + lane * 8);
    float4 g1 = *(const float4*)(g + lane * 8 + 4);
    float4 b0 = *(const float4*)(bb + lane * 8);
    float4 b1 = *(const float4*)(bb + lane * 8 + 4);
    float gg[8] = {g0.x, g0.y, g0.z, g0.w, g1.x, g1.y, g1.z, g1.w};
    float bv[8] = {b0.x, b0.y, b0.z, b0.w, b1.x, b1.y, b1.z, b1.w};
    unsigned int u[4] = {r.x, r.y, r.z, r.w};
    float ln[8];
#pragma unroll
    for (int j = 0; j < 4; j++) {
        ln[2 * j]     = fmaf((bf2f(u[j] & 0xFFFFu) - mu) * rs, gg[2 * j], bv[2 * j]);
        ln[2 * j + 1] = fmaf((bf2f_hi(u[j])         - mu) * rs, gg[2 * j + 1], bv[2 * j + 1]);
    }
    float a0 = 0.f, a1 = 0.f, a2 = 0.f;
#pragma unroll
    for (int j = 0; j < 8; j++) {
        int k = lane * 8 + j;
        a0 += ln[j] * W[k];
        a1 += ln[j] * W[512 + k];
        a2 += ln[j] * W[1024 + k];
    }
#pragma unroll
    for (int off = 32; off; off >>= 1) {
        a0 += __shfl_down(a0, off);
        a1 += __shfl_down(a1, off);
        a2 += __shfl_down(a2, off);
    }
    if (lane == 0) {
        *(unsigned int*)(hlin3 + (size_t)row * 4) =
            (unsigned int)f2bf(a0) | ((unsigned int)f2bf(a1) << 16);
        *(unsigned int*)(hlin3 + (size_t)row * 4 + 2) = (unsigned int)f2bf(a2);
        alsrc[row] = a0 * a_s[0] + a1 * a_s[1] + a2 * a_s[2];
        aldst[row] = a0 * a_d[0] + a1 * a_d[1] + a2 * a_d[2];
    }
}

// ============================ all-head softmax+aggregate, wave per NODE ============================
__global__ __launch_bounds__(256) void k_aggN(const bf16u* __restrict__ hlin,
                                              const float* __restrict__ alsrc,
                                              const float* __restrict__ aldst,
                                              const int* __restrict__ rowptr,
                                              const int* __restrict__ col,
                                              const float* __restrict__ bias,
                                              bf16u* __restrict__ hio,
                                              float* __restrict__ stats,
                                              int n, int dores) {
    __shared__ uint2 aldsU[4][8][66];   // {alpha bits, row byte offset}
    int wv = threadIdx.x >> 6;
    int node = (blockIdx.x * 256 + threadIdx.x) >> 6;
    int lane = threadIdx.x & 63;
    if (node >= n) return;
    int beg = rowptr[node], end = rowptr[node + 1];
    int deg = end - beg;

    const float4* dvv = (const float4*)(aldst + node * 8);
    float4 da = dvv[0], db = dvv[1];
    float ad[8] = {da.x, da.y, da.z, da.w, db.x, db.y, db.z, db.w};

    float s = 0.f, s2 = 0.f;

    if (deg <= 64) {
        // ---- prologue: lane j owns edge j ----
        unsigned int offb = 0;
        float raw[8];
#pragma unroll
        for (int h = 0; h < 8; h++) raw[h] = -INFINITY;
        if (lane < deg) {
            int srcreg = col[beg + lane];
            offb = (unsigned int)srcreg << 10;     // bytes: src * 512 ch * 2B
            const float4* sv = (const float4*)(alsrc + srcreg * 8);
            float4 sa = sv[0], sb = sv[1];
            float sl[8] = {sa.x, sa.y, sa.z, sa.w, sb.x, sb.y, sb.z, sb.w};
#pragma unroll
            for (int h = 0; h < 8; h++) {
                float v = sl[h] + ad[h];
                raw[h] = (v >= 0.f) ? v : NEG_SLOPE * v;
            }
        }
        float m[8];
#pragma unroll
        for (int h = 0; h < 8; h++) m[h] = raw[h];
#pragma unroll
        for (int off = 32; off; off >>= 1)
#pragma unroll
            for (int h = 0; h < 8; h++) m[h] = fmaxf(m[h], __shfl_xor(m[h], off));
        float ex[8], sm[8];
#pragma unroll
        for (int h = 0; h < 8; h++) {
            ex[h] = (lane < deg) ? __expf(raw[h] - m[h]) : 0.f;
            sm[h] = ex[h];
        }
#pragma unroll
        for (int off = 32; off; off >>= 1)
#pragma unroll
            for (int h = 0; h < 8; h++) sm[h] += __shfl_xor(sm[h], off);
#pragma unroll
        for (int h = 0; h < 8; h++) {
            uint2 t;
            t.x = __float_as_uint(ex[h] * (1.0f / sm[h]));
            t.y = offb;
            aldsU[wv][h][lane] = t;
        }
        asm volatile("s_waitcnt lgkmcnt(0)" ::: "memory");

        // ---- aggregate: one uint4 (8 ch) per lane per edge, 2-edge unroll ----
        int hl = lane >> 3;
        const uint2* myal = &aldsU[wv][hl][0];
        const char* base2 = (const char*)hlin + (lane << 4);
        float acc[8] = {};
        int e = 0;
        for (; e + 2 <= deg; e += 2) {
            uint2 t0 = myal[e];
            uint2 t1 = myal[e + 1];
            uint4 u0 = *(const uint4*)(base2 + t0.y);
            uint4 u1 = *(const uint4*)(base2 + t1.y);
            float a0 = __uint_as_float(t0.x), a1 = __uint_as_float(t1.x);
            acc[0] = fmaf(a0, bf2f(u0.x & 0xFFFFu), acc[0]);
            acc[1] = fmaf(a0, bf2f_hi(u0.x),        acc[1]);
            acc[2] = fmaf(a0, bf2f(u0.y & 0xFFFFu), acc[2]);
            acc[3] = fmaf(a0, bf2f_hi(u0.y),        acc[3]);
            acc[4] = fmaf(a0, bf2f(u0.z & 0xFFFFu), acc[4]);
            acc[5] = fmaf(a0, bf2f_hi(u0.z),        acc[5]);
            acc[6] = fmaf(a0, bf2f(u0.w & 0xFFFFu), acc[6]);
            acc[7] = fmaf(a0, bf2f_hi(u0.w),        acc[7]);
            acc[0] = fmaf(a1, bf2f(u1.x & 0xFFFFu), acc[0]);
            acc[1] = fmaf(a1, bf2f_hi(u1.x),        acc[1]);
            acc[2] = fmaf(a1, bf2f(u1.y & 0xFFFFu), acc[2]);
            acc[3] = fmaf(a1, bf2f_hi(u1.y),        acc[3]);
            acc[4] = fmaf(a1, bf2f(u1.z & 0xFFFFu), acc[4]);
            acc[5] = fmaf(a1, bf2f_hi(u1.z),        acc[5]);
            acc[6] = fmaf(a1, bf2f(u1.w & 0xFFFFu), acc[6]);
            acc[7] = fmaf(a1, bf2f_hi(u1.w),        acc[7]);
        }
        if (e < deg) {
            uint2 t0 = myal[e];
            uint4 u0 = *(const uint4*)(base2 + t0.y);
            float a0 = __uint_as_float(t0.x);
            acc[0] = fmaf(a0, bf2f(u0.x & 0xFFFFu), acc[0]);
            acc[1] = fmaf(a0, bf2f_hi(u0.x),        acc[1]);
            acc[2] = fmaf(a0, bf2f(u0.y & 0xFFFFu), acc[2]);
            acc[3] = fmaf(a0, bf2f_hi(u0.y),        acc[3]);
            acc[4] = fmaf(a0, bf2f(u0.z & 0xFFFFu), acc[4]);
            acc[5] = fmaf(a0, bf2f_hi(u0.z),        acc[5]);
            acc[6] = fmaf(a0, bf2f(u0.w & 0xFFFFu), acc[6]);
            acc[7] = fmaf(a0, bf2f_hi(u0.w),        acc[7]);
        }

        // ---- epilogue: bias + gelu + residual, pack, LN stats ----
        size_t idx = (size_t)node * 512 + lane * 8;
        float4 b0 = *(const float4*)(bias + lane * 8);
        float4 b1 = *(const float4*)(bias + lane * 8 + 4);
        float bb[8] = {b0.x, b0.y, b0.z, b0.w, b1.x, b1.y, b1.z, b1.w};
        float fin[8];
#pragma unroll
        for (int j = 0; j < 8; j++) fin[j] = gelu_f(acc[j] + bb[j]);
        if (dores) {
            uint4 up = *(const uint4*)(hio + idx);
            fin[0] += bf2f(up.x & 0xFFFFu); fin[1] += bf2f_hi(up.x);
            fin[2] += bf2f(up.y & 0xFFFFu); fin[3] += bf2f_hi(up.y);
            fin[4] += bf2f(up.z & 0xFFFFu); fin[5] += bf2f_hi(up.z);
            fin[6] += bf2f(up.w & 0xFFFFu); fin[7] += bf2f_hi(up.w);
        }
        uint4 pk;
        pk.x = (unsigned int)f2bf(fin[0]) | ((unsigned int)f2bf(fin[1]) << 16);
        pk.y = (unsigned int)f2bf(fin[2]) | ((unsigned int)f2bf(fin[3]) << 16);
        pk.z = (unsigned int)f2bf(fin[4]) | ((unsigned int)f2bf(fin[5]) << 16);
        pk.w = (unsigned int)f2bf(fin[6]) | ((unsigned int)f2bf(fin[7]) << 16);
        *(uint4*)(hio + idx) = pk;
#pragma unroll
        for (int j = 0; j < 8; j++) { s += fin[j]; s2 += fin[j] * fin[j]; }
    } else {
        // ---- fallback (deg > 64): per-head 3-pass, lane = channel ----
        for (int h = 0; h < 8; h++) {
            float adh = ad[h];
            float m = -INFINITY;
            for (int e = beg + lane; e < end; e += 64) {
                float v = alsrc[col[e] * 8 + h] + adh;
                v = (v >= 0.f) ? v : NEG_SLOPE * v;
                m = fmaxf(m, v);
            }
#pragma unroll
            for (int off = 32; off; off >>= 1) m = fmaxf(m, __shfl_xor(m, off));
            float sum = 0.f;
            for (int e = beg + lane; e < end; e += 64) {
                float v = alsrc[col[e] * 8 + h] + adh;
                v = (v >= 0.f) ? v : NEG_SLOPE * v;
                sum += __expf(v - m);
            }
#pragma unroll
            for (int off = 32; off; off >>= 1) sum += __shfl_xor(sum, off);
            float inv = 1.0f / sum;
            float acc = 0.f;
            for (int e = beg; e < end; e++) {
                int src = col[e];
                float v = alsrc[src * 8 + h] + adh;
                v = (v >= 0.f) ? v : NEG_SLOPE * v;
                float alpha = __expf(v - m) * inv;
                acc = fmaf(alpha, bf2f(hlin[((size_t)src << 9) + h * 64 + lane]), acc);
            }
            float fin = gelu_f(acc + bias[h * 64 + lane]);
            size_t idx = (size_t)node * 512 + h * 64 + lane;
            if (dores) fin += bf2f(hio[idx]);
            hio[idx] = f2bf(fin);
            s += fin; s2 += fin * fin;
        }
    }

    // ---- LN stats for the next layer ----
#pragma unroll
    for (int off = 32; off; off >>= 1) {
        s  += __shfl_xor(s, off);
        s2 += __shfl_xor(s2, off);
    }
    if (lane == 0) {
        float mu = s * (1.0f / 512.0f);
        float var = s2 * (1.0f / 512.0f) - mu * mu;
        stats[node * 2 + 0] = mu;
        stats[node * 2 + 1] = rsqrtf(var + EPSV);
    }
}

// ============================ final softmax+aggregate (heads=1, co=3) ============================
// lane j = edge j; hlin3 has row stride 4 (padded).
__global__ __launch_bounds__(256) void k_aggF(const bf16u* __restrict__ hlin3,
                                              const float* __restrict__ alsrc,
                                              const float* __restrict__ aldst,
                                              const int* __restrict__ rowptr,
                                              const int* __restrict__ col,
                                              const float* __restrict__ bias,
                                              float* __restrict__ outf,
                                              const float* __restrict__ resid, int n) {
    int node = (blockIdx.x * 256 + threadIdx.x) >> 6;
    int lane = threadIdx.x & 63;
    if (node >= n) return;
    int beg = rowptr[node], end = rowptr[node + 1];
    int deg = end - beg;
    float adh = aldst[node];

    if (deg <= 64) {
        int src = 0;
        float raw = -INFINITY;
        if (lane < deg) {
            src = col[beg + lane];
            float v = alsrc[src] + adh;
            raw = (v >= 0.f) ? v : NEG_SLOPE * v;
        }
        float m = raw;
#pragma unroll
        for (int off = 32; off; off >>= 1) m = fmaxf(m, __shfl_xor(m, off));
        float ex = (lane < deg) ? __expf(raw - m) : 0.f;
        float sum = ex;
#pragma unroll
        for (int off = 32; off; off >>= 1) sum += __shfl_xor(sum, off);
        float alpha = ex / sum;

        float c0 = 0.f, c1 = 0.f, c2 = 0.f;
        if (lane < deg) {
            uint2 u = *(const uint2*)(hlin3 + (size_t)src * 4);
            c0 = alpha * bf2f(u.x & 0xFFFFu);
            c1 = alpha * bf2f_hi(u.x);
            c2 = alpha * bf2f(u.y & 0xFFFFu);
        }
#pragma unroll
        for (int off = 32; off; off >>= 1) {
            c0 += __shfl_xor(c0, off);
            c1 += __shfl_xor(c1, off);
            c2 += __shfl_xor(c2, off);
        }
        if (lane == 0) {
            outf[node * 3 + 0] = c0 + bias[0] + resid[node * 3 + 0];
            outf[node * 3 + 1] = c1 + bias[1] + resid[node * 3 + 1];
            outf[node * 3 + 2] = c2 + bias[2] + resid[node * 3 + 2];
        }
    } else {
        float m = -INFINITY;
        for (int e = beg + lane; e < end; e += 64) {
            float v = alsrc[col[e]] + adh;
            v = (v >= 0.f) ? v : NEG_SLOPE * v;
            m = fmaxf(m, v);
        }
#pragma unroll
        for (int off = 32; off; off >>= 1) m = fmaxf(m, __shfl_xor(m, off));
        float sum = 0.f;
        for (int e = beg + lane; e < end; e += 64) {
            float v = alsrc[col[e]] + adh;
            v = (v >= 0.f) ? v : NEG_SLOPE * v;
            sum += __expf(v - m);
        }
#pragma unroll
        for (int off = 32; off; off >>= 1) sum += __shfl_xor(sum, off);
        float inv = 1.0f / sum;
        float acc = 0.f;
        for (int e = beg; e < end; e++) {
            int src = col[e];
            float v = alsrc[src] + adh;
            v = (v >= 0.f) ? v : NEG_SLOPE * v;
            float alpha = __expf(v - m) * inv;
            if (lane < 3) acc += alpha * bf2f(hlin3[(size_t)src * 4 + lane]);
        }
        if (lane < 3)
            outf[node * 3 + lane] = acc + bias[lane] + resid[node * 3 + lane];
    }
}

// ============================ launch ============================
extern "C" void kernel_launch(void* const* d_in, const int* in_sizes, int n_in,
                              void* d_out, int out_size, void* d_ws, size_t ws_size,
                              hipStream_t stream) {
    const float* x    = (const float*)d_in[0];
    const int*   ei   = (const int*)d_in[1];
    const float* resW = (const float*)d_in[2];
    const float* resb = (const float*)d_in[3];
    const float *lng[4], *lnb[4], *Wm[4], *asr[4], *adt[4], *bias[4];
    int idx = 4;
    for (int i = 0; i < 4; i++) {
        lng[i]  = (const float*)d_in[idx++];
        lnb[i]  = (const float*)d_in[idx++];
        Wm[i]   = (const float*)d_in[idx++];
        asr[i]  = (const float*)d_in[idx++];
        adt[i]  = (const float*)d_in[idx++];
        bias[i] = (const float*)d_in[idx++];
    }

    char* base = (char*)d_ws;
    size_t off = 0;
    auto alloc = [&](size_t bytes) {
        void* p = base + off;
        off += (bytes + 255) & ~(size_t)255;
        return p;
    };
    bf16u* hbuf  = (bf16u*)alloc((size_t)MPAD * 512 * 2);
    bf16u* lbuf  = (bf16u*)alloc((size_t)MPAD * 512 * 2);
    bf16u* wb0   = (bf16u*)alloc((size_t)512 * 128 * 2);
    bf16u* wb1   = (bf16u*)alloc((size_t)512 * 512 * 2);
    bf16u* wb2   = (bf16u*)alloc((size_t)512 * 512 * 2);
    float* stats = (float*)alloc((size_t)MPAD * 2 * 4);
    float* alsrc = (float*)alloc((size_t)NN * 8 * 4);
    float* aldst = (float*)alloc((size_t)NN * 8 * 4);
    float* resid = (float*)alloc((size_t)NN * 3 * 4);
    int* rowptr  = (int*)alloc((size_t)(NN + 1) * 4);
    int* cursor  = (int*)alloc((size_t)NN * 4);
    int* deg     = (int*)alloc((size_t)NN * 4);
    int* colidx  = (int*)alloc((size_t)NE * 4);
    int* bsums   = (int*)alloc(256 * 4);
    if (off > ws_size) return;

    float* out = (float*)d_out;

    // ---- CSR build ----
    k_zero_i32<<<(NN + 255) / 256, 256, 0, stream>>>(deg, NN);
    k_deg<<<(NE + 255) / 256, 256, 0, stream>>>(ei, deg);
    int nb = (NN + 1023) / 1024;
    k_scan1<<<nb, 256, 0, stream>>>(deg, rowptr, bsums, NN);
    k_scan2<<<1, 64, 0, stream>>>(bsums, nb);
    k_scan3<<<(NN + 1 + 255) / 256, 256, 0, stream>>>(deg, rowptr, cursor, bsums, NN, NE);
    k_scatter<<<(NE + 255) / 256, 256, 0, stream>>>(ei, cursor, colidx);

    // ---- fused cast+stats+residual, weight casts ----
    int rowBlocks = (NN * 64 + 255) / 256;       // 12500
    k_castres<<<rowBlocks, 256, 0, stream>>>(x, resW, resb, hbuf, stats, resid, NN);
    k_cast<<<(512 * 128 + 255) / 256, 256, 0, stream>>>(Wm[0], wb0, 512 * 128);
    k_cast<<<(512 * 512 + 255) / 256, 256, 0, stream>>>(Wm[1], wb1, 512 * 512);
    k_cast<<<(512 * 512 + 255) / 256, 256, 0, stream>>>(Wm[2], wb2, 512 * 512);

    const bf16u* wb[3] = {wb0, wb1, wb2};
    const int ci_a[3] = {128, 512, 512};

    for (int i = 0; i < 3; i++) {
        int ci = ci_a[i];
        int dores = (i >= 1) ? 1 : 0;

        dim3 ggrid(MPAD / BM, 512 / BN);
        k_gemm_mfma<<<ggrid, 256, 0, stream>>>(hbuf, stats, lng[i], lnb[i], wb[i],
                                               lbuf, asr[i], adt[i], alsrc, aldst,
                                               NN, ci, 512);

        k_aggN<<<rowBlocks, 256, 0, stream>>>(lbuf, alsrc, aldst, rowptr, colidx,
                                              bias[i], hbuf, stats, NN, dores);
    }

    // ---- layer 3: matvec + logits, then final aggregate into d_out ----
    k_lin3<<<rowBlocks, 256, 0, stream>>>(hbuf, stats, lng[3], lnb[3], Wm[3],
                                          asr[3], adt[3], lbuf, alsrc, aldst, NN);
    k_aggF<<<rowBlocks, 256, 0, stream>>>(lbuf, alsrc, aldst, rowptr, colidx,
                                          bias[3], out, resid, NN);
}

// Round 7
// 666.452 us; speedup vs baseline: 4.5002x; 1.0055x over previous
//
#include <hip/hip_runtime.h>
#include <math.h>

#define NN 50000
#define MPAD 50048          // 391 * 128
#define EE 400000
#define NE 450000           // EE + NN self loops
#define IN_F 128
#define NEG_SLOPE 0.2f
#define EPSV 1e-6f

typedef unsigned short bf16u;
typedef short bf8_t __attribute__((ext_vector_type(8)));
typedef float f32x4 __attribute__((ext_vector_type(4)));

__device__ __forceinline__ float bf2f(unsigned int u) {
    return __uint_as_float(u << 16);
}
__device__ __forceinline__ float bf2f_hi(unsigned int u) {
    return __uint_as_float(u & 0xFFFF0000u);
}
__device__ __forceinline__ bf16u f2bf(float f) {
    unsigned int u = __float_as_uint(f);
    unsigned int r = (u + 0x7FFFu + ((u >> 16) & 1u)) >> 16;
    return (bf16u)r;
}
__device__ __forceinline__ float gelu_f(float v) {
    return 0.5f * v * (1.0f + erff(v * 0.70710678118654752f));
}

__device__ __forceinline__ void gload_lds16(const void* g, void* l) {
    __builtin_amdgcn_global_load_lds(
        (__attribute__((address_space(1))) void*)(g),
        (__attribute__((address_space(3))) void*)(l), 16, 0, 0);
}

// ============================ CSR build ============================
__global__ void k_zero_i32(int* p, int n) {
    int i = blockIdx.x * 256 + threadIdx.x;
    if (i < n) p[i] = 0;
}

__global__ void k_deg(const int* __restrict__ ei, int* __restrict__ deg) {
    int i = blockIdx.x * 256 + threadIdx.x;
    if (i >= NE) return;
    int d = (i < EE) ? ei[EE + i] : (i - EE);
    atomicAdd(&deg[d], 1);
}

__global__ __launch_bounds__(256) void k_scan1(const int* __restrict__ deg,
                                               int* __restrict__ incl,
                                               int* __restrict__ bsums, int n) {
    __shared__ int sm[1024];
    int base = blockIdx.x * 1024;
    for (int i = threadIdx.x; i < 1024; i += 256)
        sm[i] = (base + i < n) ? deg[base + i] : 0;
    __syncthreads();
    for (int off = 1; off < 1024; off <<= 1) {
        int v[4];
#pragma unroll
        for (int j = 0; j < 4; j++) {
            int i = threadIdx.x + 256 * j;
            v[j] = (i >= off) ? sm[i - off] : 0;
        }
        __syncthreads();
#pragma unroll
        for (int j = 0; j < 4; j++) {
            int i = threadIdx.x + 256 * j;
            sm[i] += v[j];
        }
        __syncthreads();
    }
    for (int i = threadIdx.x; i < 1024; i += 256)
        if (base + i < n) incl[base + i] = sm[i];
    if (threadIdx.x == 0) bsums[blockIdx.x] = sm[1023];
}

__global__ void k_scan2(int* bsums, int nb) {
    if (threadIdx.x == 0 && blockIdx.x == 0) {
        int run = 0;
        for (int i = 0; i < nb; i++) { int v = bsums[i]; bsums[i] = run; run += v; }
    }
}

__global__ void k_scan3(const int* __restrict__ deg, int* __restrict__ rowptr,
                        int* __restrict__ cursor, const int* __restrict__ bsums,
                        int n, int ne) {
    int i = blockIdx.x * 256 + threadIdx.x;
    if (i < n) {
        int excl = rowptr[i] + bsums[i >> 10] - deg[i];
        rowptr[i] = excl;
        cursor[i] = excl;
    }
    if (i == n) rowptr[n] = ne;
}

__global__ void k_scatter(const int* __restrict__ ei, int* __restrict__ cursor,
                          int* __restrict__ col) {
    int i = blockIdx.x * 256 + threadIdx.x;
    if (i >= NE) return;
    int s, d;
    if (i < EE) { s = ei[i]; d = ei[EE + i]; }
    else        { s = i - EE; d = i - EE; }
    int p = atomicAdd(&cursor[d], 1);
    col[p] = s;
}

// ============================ f32 -> bf16 cast (weights) ============================
__global__ void k_cast(const float* __restrict__ x, bf16u* __restrict__ h, int total) {
    int i = blockIdx.x * 256 + threadIdx.x;
    if (i < total) h[i] = f2bf(x[i]);
}

// ======== OLD PATH: fused cast x -> bf16, LN stats (ci=128), residual head ========
__global__ __launch_bounds__(256) void k_castres(const float* __restrict__ x,
                                                 const float* __restrict__ rw,
                                                 const float* __restrict__ rb,
                                                 bf16u* __restrict__ h,
                                                 float* __restrict__ stats,
                                                 float* __restrict__ res, int n) {
    int row = (blockIdx.x * 256 + threadIdx.x) >> 6;
    int lane = threadIdx.x & 63;
    if (row >= n) return;
    float2 v = *(const float2*)(x + (size_t)row * 128 + lane * 2);
    unsigned int pk = (unsigned int)f2bf(v.x) | ((unsigned int)f2bf(v.y) << 16);
    *(unsigned int*)(h + (size_t)row * 128 + lane * 2) = pk;
    float2 w0 = *(const float2*)(rw + 0 * 128 + lane * 2);
    float2 w1 = *(const float2*)(rw + 1 * 128 + lane * 2);
    float2 w2 = *(const float2*)(rw + 2 * 128 + lane * 2);
    float s = v.x + v.y, s2 = v.x * v.x + v.y * v.y;
    float a0 = v.x * w0.x + v.y * w0.y;
    float a1 = v.x * w1.x + v.y * w1.y;
    float a2 = v.x * w2.x + v.y * w2.y;
#pragma unroll
    for (int off = 32; off; off >>= 1) {
        s  += __shfl_xor(s, off);
        s2 += __shfl_xor(s2, off);
        a0 += __shfl_xor(a0, off);
        a1 += __shfl_xor(a1, off);
        a2 += __shfl_xor(a2, off);
    }
    if (lane == 0) {
        float mu = s * (1.0f / 128.0f);
        float var = s2 * (1.0f / 128.0f) - mu * mu;
        stats[row * 2 + 0] = mu;
        stats[row * 2 + 1] = rsqrtf(var + EPSV);
        res[row * 3 + 0] = a0 + rb[0];
        res[row * 3 + 1] = a1 + rb[1];
        res[row * 3 + 2] = a2 + rb[2];
    }
}

// ======== NEW PATH: cast x -> LN'd bf16 (g0,b0 applied) + residual head ========
__global__ __launch_bounds__(256) void k_castres2(const float* __restrict__ x,
                                                  const float* __restrict__ rw,
                                                  const float* __restrict__ rb,
                                                  const float* __restrict__ g0,
                                                  const float* __restrict__ b0,
                                                  bf16u* __restrict__ abuf,
                                                  float* __restrict__ res, int n) {
    int row = (blockIdx.x * 256 + threadIdx.x) >> 6;
    int lane = threadIdx.x & 63;
    if (row >= n) return;
    float2 v = *(const float2*)(x + (size_t)row * 128 + lane * 2);
    float2 w0 = *(const float2*)(rw + 0 * 128 + lane * 2);
    float2 w1 = *(const float2*)(rw + 1 * 128 + lane * 2);
    float2 w2 = *(const float2*)(rw + 2 * 128 + lane * 2);
    float s = v.x + v.y, s2 = v.x * v.x + v.y * v.y;
    float a0 = v.x * w0.x + v.y * w0.y;
    float a1 = v.x * w1.x + v.y * w1.y;
    float a2 = v.x * w2.x + v.y * w2.y;
#pragma unroll
    for (int off = 32; off; off >>= 1) {
        s  += __shfl_xor(s, off);
        s2 += __shfl_xor(s2, off);
        a0 += __shfl_xor(a0, off);
        a1 += __shfl_xor(a1, off);
        a2 += __shfl_xor(a2, off);
    }
    float mu = s * (1.0f / 128.0f);
    float var = s2 * (1.0f / 128.0f) - mu * mu;
    float rs = rsqrtf(var + EPSV);
    float2 gg = *(const float2*)(g0 + lane * 2);
    float2 bb = *(const float2*)(b0 + lane * 2);
    float l0 = fmaf((v.x - mu) * rs, gg.x, bb.x);
    float l1 = fmaf((v.y - mu) * rs, gg.y, bb.y);
    *(unsigned int*)(abuf + (size_t)row * 128 + lane * 2) =
        (unsigned int)f2bf(l0) | ((unsigned int)f2bf(l1) << 16);
    if (lane == 0) {
        res[row * 3 + 0] = a0 + rb[0];
        res[row * 3 + 1] = a1 + rb[1];
        res[row * 3 + 2] = a2 + rb[2];
    }
}

// ============ OLD PATH: MFMA GEMM with fused LN on A + fused al epilogue ============
#define BM 128
#define BN 128
#define BKK 32
__global__ __launch_bounds__(256) void k_gemm_mfma(const bf16u* __restrict__ H,
                                                   const float* __restrict__ stats,
                                                   const float* __restrict__ g,
                                                   const float* __restrict__ bbias,
                                                   const bf16u* __restrict__ Wb,
                                                   bf16u* __restrict__ C,
                                                   const float* __restrict__ asr,
                                                   const float* __restrict__ adt,
                                                   float* __restrict__ alsrc,
                                                   float* __restrict__ aldst,
                                                   int Mreal, int ci, int K) {
    __shared__ __align__(16) bf16u As[BM * BKK];
    __shared__ __align__(16) bf16u Bs[BN * BKK];
    const int tid = threadIdx.x;
    const int w = tid >> 6, lane = tid & 63;
    const int row0 = blockIdx.x * BM, col0 = blockIdx.y * BN;
    const int wr = (w >> 1) * 64, wc = (w & 1) * 64;

    const int srow = w * 32 + (lane >> 2);
    const int scol = (lane & 3) * 8;
    const bf16u* gA = H + (size_t)(row0 + srow) * ci + scol;
    const bf16u* gB = Wb + (size_t)(col0 + srow) * ci + scol;
    const float mu1 = stats[(row0 + srow) * 2 + 0];
    const float rs1 = stats[(row0 + srow) * 2 + 1];
    const float mu2 = stats[(row0 + srow + 16) * 2 + 0];
    const float rs2 = stats[(row0 + srow + 16) * 2 + 1];
    bf16u* lA1 = &As[(size_t)srow * BKK + scol];
    bf16u* lA2 = &As[(size_t)(srow + 16) * BKK + scol];
    void* lB1 = &Bs[(size_t)(w * 32) * BKK];
    void* lB2 = &Bs[(size_t)(w * 32 + 16) * BKK];

    f32x4 acc[4][4] = {};

    const int fr = lane & 15;
    const int fk = (lane >> 4) * 8;

    for (int k0 = 0; k0 < ci; k0 += BKK) {
        uint4 ra1 = *(const uint4*)(gA + k0);
        uint4 ra2 = *(const uint4*)(gA + (size_t)16 * ci + k0);
        float4 g0 = *(const float4*)(g + k0 + scol);
        float4 g1 = *(const float4*)(g + k0 + scol + 4);
        float4 b0 = *(const float4*)(bbias + k0 + scol);
        float4 b1 = *(const float4*)(bbias + k0 + scol + 4);
        float gg[8] = {g0.x, g0.y, g0.z, g0.w, g1.x, g1.y, g1.z, g1.w};
        float bb[8] = {b0.x, b0.y, b0.z, b0.w, b1.x, b1.y, b1.z, b1.w};
        unsigned int u1[4] = {ra1.x, ra1.y, ra1.z, ra1.w};
        unsigned int u2[4] = {ra2.x, ra2.y, ra2.z, ra2.w};
        uint4 p1, p2;
        {
            unsigned int po[4], qo[4];
#pragma unroll
            for (int j = 0; j < 4; j++) {
                float va = (bf2f(u1[j] & 0xFFFFu) - mu1) * rs1;
                float vb = (bf2f_hi(u1[j])         - mu1) * rs1;
                float oa = fmaf(va, gg[2 * j], bb[2 * j]);
                float ob = fmaf(vb, gg[2 * j + 1], bb[2 * j + 1]);
                po[j] = (unsigned int)f2bf(oa) | ((unsigned int)f2bf(ob) << 16);
                float vc = (bf2f(u2[j] & 0xFFFFu) - mu2) * rs2;
                float vd = (bf2f_hi(u2[j])         - mu2) * rs2;
                float oc = fmaf(vc, gg[2 * j], bb[2 * j]);
                float od = fmaf(vd, gg[2 * j + 1], bb[2 * j + 1]);
                qo[j] = (unsigned int)f2bf(oc) | ((unsigned int)f2bf(od) << 16);
            }
            p1 = make_uint4(po[0], po[1], po[2], po[3]);
            p2 = make_uint4(qo[0], qo[1], qo[2], qo[3]);
        }

        __syncthreads();
        *(uint4*)lA1 = p1;
        *(uint4*)lA2 = p2;
        gload_lds16(gB + k0, lB1);
        gload_lds16(gB + (size_t)16 * ci + k0, lB2);
        __syncthreads();

        bf8_t af[4], bfv[4];
#pragma unroll
        for (int m = 0; m < 4; m++)
            af[m] = *(const bf8_t*)&As[(size_t)(wr + m * 16 + fr) * BKK + fk];
#pragma unroll
        for (int n = 0; n < 4; n++)
            bfv[n] = *(const bf8_t*)&Bs[(size_t)(wc + n * 16 + fr) * BKK + fk];
#pragma unroll
        for (int m = 0; m < 4; m++)
#pragma unroll
            for (int n = 0; n < 4; n++)
                acc[m][n] = __builtin_amdgcn_mfma_f32_16x16x32_bf16(af[m], bfv[n], acc[m][n], 0, 0, 0);
    }

    const int fc = lane & 15;
    const int fq = (lane >> 4) * 4;

#pragma unroll
    for (int m = 0; m < 4; m++) {
#pragma unroll
        for (int r = 0; r < 4; r++) {
            int row = row0 + wr + m * 16 + fq + r;
            if (row >= Mreal) continue;
#pragma unroll
            for (int n = 0; n < 4; n++) {
                int col = col0 + wc + n * 16 + fc;
                C[(size_t)row * K + col] = f2bf(acc[m][n][r]);
            }
        }
    }

    const int head = blockIdx.y * 2 + (wc >> 6);
    float av[4], dv[4];
#pragma unroll
    for (int n = 0; n < 4; n++) {
        av[n] = asr[head * 64 + n * 16 + fc];
        dv[n] = adt[head * 64 + n * 16 + fc];
    }
#pragma unroll
    for (int m = 0; m < 4; m++) {
#pragma unroll
        for (int r = 0; r < 4; r++) {
            float s1 = acc[m][0][r] * av[0] + acc[m][1][r] * av[1]
                     + acc[m][2][r] * av[2] + acc[m][3][r] * av[3];
            float s2 = acc[m][0][r] * dv[0] + acc[m][1][r] * dv[1]
                     + acc[m][2][r] * dv[2] + acc[m][3][r] * dv[3];
#pragma unroll
            for (int o = 1; o < 16; o <<= 1) {
                s1 += __shfl_xor(s1, o);
                s2 += __shfl_xor(s2, o);
            }
            int row = row0 + wr + m * 16 + fq + r;
            if (fc == 0 && row < Mreal) {
                alsrc[row * 8 + head] = s1;
                aldst[row * 8 + head] = s2;
            }
        }
    }
}

// ============ NEW PATH: pure bf16 MFMA GEMM (A pre-normalized) + al epilogue ============
// BK=64, both operands via global_load_lds; XOR swizzle (elem ^= (row&7)<<3) applied
// to the GLOBAL source column (LDS dest linear) and to the ds_read address.
#define BK2 64
__global__ __launch_bounds__(256) void k_gemm_pure(const bf16u* __restrict__ A,
                                                   const bf16u* __restrict__ Wb,
                                                   bf16u* __restrict__ C,
                                                   const float* __restrict__ asr,
                                                   const float* __restrict__ adt,
                                                   float* __restrict__ alsrc,
                                                   float* __restrict__ aldst,
                                                   int Mreal, int ci, int K) {
    __shared__ __align__(16) bf16u As[BM * BK2];
    __shared__ __align__(16) bf16u Bs[BN * BK2];
    const int tid = threadIdx.x;
    const int w = tid >> 6, lane = tid & 63;
    const int row0 = blockIdx.x * BM, col0 = blockIdx.y * BN;
    const int wr = (w >> 1) * 64, wc = (w & 1) * 64;

    // staging: wave w covers rows [w*32, w*32+32), 4 issues of 8 rows (128B/row)
    const int lrow = lane >> 3;                            // row within issue
    const int scolx = ((lane & 7) * 8) ^ (lrow << 3);      // pre-swizzled source col
    const bf16u* gA = A + (size_t)(row0 + w * 32 + lrow) * ci + scolx;
    const bf16u* gB = Wb + (size_t)(col0 + w * 32 + lrow) * ci + scolx;

    f32x4 acc[4][4] = {};
    const int fr = lane & 15;
    const int fk = (lane >> 4) * 8;
    const int fxor = (fr & 7) << 3;

    for (int k0 = 0; k0 < ci; k0 += BK2) {
        __syncthreads();
#pragma unroll
        for (int j = 0; j < 4; j++) {
            gload_lds16(gA + (size_t)(j * 8) * ci + k0, &As[(w * 32 + j * 8) * BK2]);
            gload_lds16(gB + (size_t)(j * 8) * ci + k0, &Bs[(w * 32 + j * 8) * BK2]);
        }
        __syncthreads();
#pragma unroll
        for (int ks = 0; ks < 2; ks++) {
            bf8_t af[4], bfv[4];
#pragma unroll
            for (int m = 0; m < 4; m++)
                af[m] = *(const bf8_t*)&As[(wr + m * 16 + fr) * BK2 + ((ks * 32 + fk) ^ fxor)];
#pragma unroll
            for (int n = 0; n < 4; n++)
                bfv[n] = *(const bf8_t*)&Bs[(wc + n * 16 + fr) * BK2 + ((ks * 32 + fk) ^ fxor)];
#pragma unroll
            for (int m = 0; m < 4; m++)
#pragma unroll
                for (int n = 0; n < 4; n++)
                    acc[m][n] = __builtin_amdgcn_mfma_f32_16x16x32_bf16(af[m], bfv[n], acc[m][n], 0, 0, 0);
        }
    }

    const int fc = lane & 15;
    const int fq = (lane >> 4) * 4;

#pragma unroll
    for (int m = 0; m < 4; m++) {
#pragma unroll
        for (int r = 0; r < 4; r++) {
            int row = row0 + wr + m * 16 + fq + r;
            if (row >= Mreal) continue;
#pragma unroll
            for (int n = 0; n < 4; n++) {
                int col = col0 + wc + n * 16 + fc;
                C[(size_t)row * K + col] = f2bf(acc[m][n][r]);
            }
        }
    }

    const int head = blockIdx.y * 2 + (wc >> 6);
    float av[4], dv[4];
#pragma unroll
    for (int n = 0; n < 4; n++) {
        av[n] = asr[head * 64 + n * 16 + fc];
        dv[n] = adt[head * 64 + n * 16 + fc];
    }
#pragma unroll
    for (int m = 0; m < 4; m++) {
#pragma unroll
        for (int r = 0; r < 4; r++) {
            float s1 = acc[m][0][r] * av[0] + acc[m][1][r] * av[1]
                     + acc[m][2][r] * av[2] + acc[m][3][r] * av[3];
            float s2 = acc[m][0][r] * dv[0] + acc[m][1][r] * dv[1]
                     + acc[m][2][r] * dv[2] + acc[m][3][r] * dv[3];
#pragma unroll
            for (int o = 1; o < 16; o <<= 1) {
                s1 += __shfl_xor(s1, o);
                s2 += __shfl_xor(s2, o);
            }
            int row = row0 + wr + m * 16 + fq + r;
            if (fc == 0 && row < Mreal) {
                alsrc[row * 8 + head] = s1;
                aldst[row * 8 + head] = s2;
            }
        }
    }
}

// ============ OLD PATH: layer-3 matvec + logits (LN applied here) ============
__global__ __launch_bounds__(256) void k_lin3(const bf16u* __restrict__ h,
                                              const float* __restrict__ stats,
                                              const float* __restrict__ g,
                                              const float* __restrict__ bb,
                                              const float* __restrict__ W,
                                              const float* __restrict__ a_s,
                                              const float* __restrict__ a_d,
                                              bf16u* __restrict__ hlin3,
                                              float* __restrict__ alsrc,
                                              float* __restrict__ aldst, int n) {
    int row = (blockIdx.x * 256 + threadIdx.x) >> 6;
    int lane = threadIdx.x & 63;
    if (row >= n) return;
    float mu = stats[row * 2 + 0], rs = stats[row * 2 + 1];
    uint4 r = *(const uint4*)(h + (size_t)row * 512 + lane * 8);
    float4 g0 = *(const float4*)(g + lane * 8);
    float4 g1 = *(const float4*)(g + lane * 8 + 4);
    float4 b0 = *(const float4*)(bb + lane * 8);
    float4 b1 = *(const float4*)(bb + lane * 8 + 4);
    float gg[8] = {g0.x, g0.y, g0.z, g0.w, g1.x, g1.y, g1.z, g1.w};
    float bv[8] = {b0.x, b0.y, b0.z, b0.w, b1.x, b1.y, b1.z, b1.w};
    unsigned int u[4] = {r.x, r.y, r.z, r.w};
    float ln[8];
#pragma unroll
    for (int j = 0; j < 4; j++) {
        ln[2 * j]     = fmaf((bf2f(u[j] & 0xFFFFu) - mu) * rs, gg[2 * j], bv[2 * j]);
        ln[2 * j + 1] = fmaf((bf2f_hi(u[j])         - mu) * rs, gg[2 * j + 1], bv[2 * j + 1]);
    }
    float a0 = 0.f, a1 = 0.f, a2 = 0.f;
#pragma unroll
    for (int j = 0; j < 8; j++) {
        int k = lane * 8 + j;
        a0 += ln[j] * W[k];
        a1 += ln[j] * W[512 + k];
        a2 += ln[j] * W[1024 + k];
    }
#pragma unroll
    for (int off = 32; off; off >>= 1) {
        a0 += __shfl_down(a0, off);
        a1 += __shfl_down(a1, off);
        a2 += __shfl_down(a2, off);
    }
    if (lane == 0) {
        *(unsigned int*)(hlin3 + (size_t)row * 4) =
            (unsigned int)f2bf(a0) | ((unsigned int)f2bf(a1) << 16);
        *(unsigned int*)(hlin3 + (size_t)row * 4 + 2) = (unsigned int)f2bf(a2);
        alsrc[row] = a0 * a_s[0] + a1 * a_s[1] + a2 * a_s[2];
        aldst[row] = a0 * a_d[0] + a1 * a_d[1] + a2 * a_d[2];
    }
}

// ============ NEW PATH: layer-3 matvec + logits (input already LN'd) ============
__global__ __launch_bounds__(256) void k_lin3b(const bf16u* __restrict__ an,
                                               const float* __restrict__ W,
                                               const float* __restrict__ a_s,
                                               const float* __restrict__ a_d,
                                               bf16u* __restrict__ hlin3,
                                               float* __restrict__ alsrc,
                                               float* __restrict__ aldst, int n) {
    int row = (blockIdx.x * 256 + threadIdx.x) >> 6;
    int lane = threadIdx.x & 63;
    if (row >= n) return;
    uint4 r = *(const uint4*)(an + (size_t)row * 512 + lane * 8);
    unsigned int u[4] = {r.x, r.y, r.z, r.w};
    float ln[8];
#pragma unroll
    for (int j = 0; j < 4; j++) {
        ln[2 * j]     = bf2f(u[j] & 0xFFFFu);
        ln[2 * j + 1] = bf2f_hi(u[j]);
    }
    float a0 = 0.f, a1 = 0.f, a2 = 0.f;
#pragma unroll
    for (int j = 0; j < 8; j++) {
        int k = lane * 8 + j;
        a0 += ln[j] * W[k];
        a1 += ln[j] * W[512 + k];
        a2 += ln[j] * W[1024 + k];
    }
#pragma unroll
    for (int off = 32; off; off >>= 1) {
        a0 += __shfl_down(a0, off);
        a1 += __shfl_down(a1, off);
        a2 += __shfl_down(a2, off);
    }
    if (lane == 0) {
        *(unsigned int*)(hlin3 + (size_t)row * 4) =
            (unsigned int)f2bf(a0) | ((unsigned int)f2bf(a1) << 16);
        *(unsigned int*)(hlin3 + (size_t)row * 4 + 2) = (unsigned int)f2bf(a2);
        alsrc[row] = a0 * a_s[0] + a1 * a_s[1] + a2 * a_s[2];
        aldst[row] = a0 * a_d[0] + a1 * a_d[1] + a2 * a_d[2];
    }
}

// ============ OLD PATH: all-head softmax+aggregate (writes stats) ============
__global__ __launch_bounds__(256) void k_aggN(const bf16u* __restrict__ hlin,
                                              const float* __restrict__ alsrc,
                                              const float* __restrict__ aldst,
                                              const int* __restrict__ rowptr,
                                              const int* __restrict__ col,
                                              const float* __restrict__ bias,
                                              bf16u* __restrict__ hio,
                                              float* __restrict__ stats,
                                              int n, int dores) {
    __shared__ uint2 aldsU[4][8][66];
    int wv = threadIdx.x >> 6;
    int node = (blockIdx.x * 256 + threadIdx.x) >> 6;
    int lane = threadIdx.x & 63;
    if (node >= n) return;
    int beg = rowptr[node], end = rowptr[node + 1];
    int deg = end - beg;

    const float4* dvv = (const float4*)(aldst + node * 8);
    float4 da = dvv[0], db = dvv[1];
    float ad[8] = {da.x, da.y, da.z, da.w, db.x, db.y, db.z, db.w};

    float s = 0.f, s2 = 0.f;

    if (deg <= 64) {
        unsigned int offb = 0;
        float raw[8];
#pragma unroll
        for (int h = 0; h < 8; h++) raw[h] = -INFINITY;
        if (lane < deg) {
            int srcreg = col[beg + lane];
            offb = (unsigned int)srcreg << 10;
            const float4* sv = (const float4*)(alsrc + srcreg * 8);
            float4 sa = sv[0], sb = sv[1];
            float sl[8] = {sa.x, sa.y, sa.z, sa.w, sb.x, sb.y, sb.z, sb.w};
#pragma unroll
            for (int h = 0; h < 8; h++) {
                float v = sl[h] + ad[h];
                raw[h] = (v >= 0.f) ? v : NEG_SLOPE * v;
            }
        }
        float m[8];
#pragma unroll
        for (int h = 0; h < 8; h++) m[h] = raw[h];
#pragma unroll
        for (int off = 32; off; off >>= 1)
#pragma unroll
            for (int h = 0; h < 8; h++) m[h] = fmaxf(m[h], __shfl_xor(m[h], off));
        float ex[8], sm[8];
#pragma unroll
        for (int h = 0; h < 8; h++) {
            ex[h] = (lane < deg) ? __expf(raw[h] - m[h]) : 0.f;
            sm[h] = ex[h];
        }
#pragma unroll
        for (int off = 32; off; off >>= 1)
#pragma unroll
            for (int h = 0; h < 8; h++) sm[h] += __shfl_xor(sm[h], off);
#pragma unroll
        for (int h = 0; h < 8; h++) {
            uint2 t;
            t.x = __float_as_uint(ex[h] * (1.0f / sm[h]));
            t.y = offb;
            aldsU[wv][h][lane] = t;
        }
        asm volatile("s_waitcnt lgkmcnt(0)" ::: "memory");

        int hl = lane >> 3;
        const uint2* myal = &aldsU[wv][hl][0];
        const char* base2 = (const char*)hlin + (lane << 4);
        float acc[8] = {};
        int e = 0;
        for (; e + 2 <= deg; e += 2) {
            uint2 t0 = myal[e];
            uint2 t1 = myal[e + 1];
            uint4 u0 = *(const uint4*)(base2 + t0.y);
            uint4 u1 = *(const uint4*)(base2 + t1.y);
            float a0 = __uint_as_float(t0.x), a1 = __uint_as_float(t1.x);
            acc[0] = fmaf(a0, bf2f(u0.x & 0xFFFFu), acc[0]);
            acc[1] = fmaf(a0, bf2f_hi(u0.x),        acc[1]);
            acc[2] = fmaf(a0, bf2f(u0.y & 0xFFFFu), acc[2]);
            acc[3] = fmaf(a0, bf2f_hi(u0.y),        acc[3]);
            acc[4] = fmaf(a0, bf2f(u0.z & 0xFFFFu), acc[4]);
            acc[5] = fmaf(a0, bf2f_hi(u0.z),        acc[5]);
            acc[6] = fmaf(a0, bf2f(u0.w & 0xFFFFu), acc[6]);
            acc[7] = fmaf(a0, bf2f_hi(u0.w),        acc[7]);
            acc[0] = fmaf(a1, bf2f(u1.x & 0xFFFFu), acc[0]);
            acc[1] = fmaf(a1, bf2f_hi(u1.x),        acc[1]);
            acc[2] = fmaf(a1, bf2f(u1.y & 0xFFFFu), acc[2]);
            acc[3] = fmaf(a1, bf2f_hi(u1.y),        acc[3]);
            acc[4] = fmaf(a1, bf2f(u1.z & 0xFFFFu), acc[4]);
            acc[5] = fmaf(a1, bf2f_hi(u1.z),        acc[5]);
            acc[6] = fmaf(a1, bf2f(u1.w & 0xFFFFu), acc[6]);
            acc[7] = fmaf(a1, bf2f_hi(u1.w),        acc[7]);
        }
        if (e < deg) {
            uint2 t0 = myal[e];
            uint4 u0 = *(const uint4*)(base2 + t0.y);
            float a0 = __uint_as_float(t0.x);
            acc[0] = fmaf(a0, bf2f(u0.x & 0xFFFFu), acc[0]);
            acc[1] = fmaf(a0, bf2f_hi(u0.x),        acc[1]);
            acc[2] = fmaf(a0, bf2f(u0.y & 0xFFFFu), acc[2]);
            acc[3] = fmaf(a0, bf2f_hi(u0.y),        acc[3]);
            acc[4] = fmaf(a0, bf2f(u0.z & 0xFFFFu), acc[4]);
            acc[5] = fmaf(a0, bf2f_hi(u0.z),        acc[5]);
            acc[6] = fmaf(a0, bf2f(u0.w & 0xFFFFu), acc[6]);
            acc[7] = fmaf(a0, bf2f_hi(u0.w),        acc[7]);
        }

        size_t idx = (size_t)node * 512 + lane * 8;
        float4 b0 = *(const float4*)(bias + lane * 8);
        float4 b1 = *(const float4*)(bias + lane * 8 + 4);
        float bb[8] = {b0.x, b0.y, b0.z, b0.w, b1.x, b1.y, b1.z, b1.w};
        float fin[8];
#pragma unroll
        for (int j = 0; j < 8; j++) fin[j] = gelu_f(acc[j] + bb[j]);
        if (dores) {
            uint4 up = *(const uint4*)(hio + idx);
            fin[0] += bf2f(up.x & 0xFFFFu); fin[1] += bf2f_hi(up.x);
            fin[2] += bf2f(up.y & 0xFFFFu); fin[3] += bf2f_hi(up.y);
            fin[4] += bf2f(up.z & 0xFFFFu); fin[5] += bf2f_hi(up.z);
            fin[6] += bf2f(up.w & 0xFFFFu); fin[7] += bf2f_hi(up.w);
        }
        uint4 pk;
        pk.x = (unsigned int)f2bf(fin[0]) | ((unsigned int)f2bf(fin[1]) << 16);
        pk.y = (unsigned int)f2bf(fin[2]) | ((unsigned int)f2bf(fin[3]) << 16);
        pk.z = (unsigned int)f2bf(fin[4]) | ((unsigned int)f2bf(fin[5]) << 16);
        pk.w = (unsigned int)f2bf(fin[6]) | ((unsigned int)f2bf(fin[7]) << 16);
        *(uint4*)(hio + idx) = pk;
#pragma unroll
        for (int j = 0; j < 8; j++) { s += fin[j]; s2 += fin[j] * fin[j]; }
    } else {
        for (int h = 0; h < 8; h++) {
            float adh = ad[h];
            float m = -INFINITY;
            for (int e = beg + lane; e < end; e += 64) {
                float v = alsrc[col[e] * 8 + h] + adh;
                v = (v >= 0.f) ? v : NEG_SLOPE * v;
                m = fmaxf(m, v);
            }
#pragma unroll
            for (int off = 32; off; off >>= 1) m = fmaxf(m, __shfl_xor(m, off));
            float sum = 0.f;
            for (int e = beg + lane; e < end; e += 64) {
                float v = alsrc[col[e] * 8 + h] + adh;
                v = (v >= 0.f) ? v : NEG_SLOPE * v;
                sum += __expf(v - m);
            }
#pragma unroll
            for (int off = 32; off; off >>= 1) sum += __shfl_xor(sum, off);
            float inv = 1.0f / sum;
            float acc = 0.f;
            for (int e = beg; e < end; e++) {
                int src = col[e];
                float v = alsrc[src * 8 + h] + adh;
                v = (v >= 0.f) ? v : NEG_SLOPE * v;
                float alpha = __expf(v - m) * inv;
                acc = fmaf(alpha, bf2f(hlin[((size_t)src << 9) + h * 64 + lane]), acc);
            }
            float fin = gelu_f(acc + bias[h * 64 + lane]);
            size_t idx = (size_t)node * 512 + h * 64 + lane;
            if (dores) fin += bf2f(hio[idx]);
            hio[idx] = f2bf(fin);
            s += fin; s2 += fin * fin;
        }
    }

#pragma unroll
    for (int off = 32; off; off >>= 1) {
        s  += __shfl_xor(s, off);
        s2 += __shfl_xor(s2, off);
    }
    if (lane == 0) {
        float mu = s * (1.0f / 512.0f);
        float var = s2 * (1.0f / 512.0f) - mu * mu;
        stats[node * 2 + 0] = mu;
        stats[node * 2 + 1] = rsqrtf(var + EPSV);
    }
}

// ============ NEW PATH: aggregate + epilogue ALSO writes LN'd row (next layer's A) ============
__global__ __launch_bounds__(256) void k_aggN2(const bf16u* __restrict__ hlin,
                                               const float* __restrict__ alsrc,
                                               const float* __restrict__ aldst,
                                               const int* __restrict__ rowptr,
                                               const int* __restrict__ col,
                                               const float* __restrict__ bias,
                                               bf16u* __restrict__ hio,
                                               const float* __restrict__ gn,
                                               const float* __restrict__ bn,
                                               bf16u* __restrict__ abuf,
                                               int n, int dores) {
    __shared__ uint2 aldsU[4][8][66];
    int wv = threadIdx.x >> 6;
    int node = (blockIdx.x * 256 + threadIdx.x) >> 6;
    int lane = threadIdx.x & 63;
    if (node >= n) return;
    int beg = rowptr[node], end = rowptr[node + 1];
    int deg = end - beg;

    const float4* dvv = (const float4*)(aldst + node * 8);
    float4 da = dvv[0], db = dvv[1];
    float ad[8] = {da.x, da.y, da.z, da.w, db.x, db.y, db.z, db.w};

    float s = 0.f, s2 = 0.f;
    float fin[8];

    if (deg <= 64) {
        unsigned int offb = 0;
        float raw[8];
#pragma unroll
        for (int h = 0; h < 8; h++) raw[h] = -INFINITY;
        if (lane < deg) {
            int srcreg = col[beg + lane];
            offb = (unsigned int)srcreg << 10;
            const float4* sv = (const float4*)(alsrc + srcreg * 8);
            float4 sa = sv[0], sb = sv[1];
            float sl[8] = {sa.x, sa.y, sa.z, sa.w, sb.x, sb.y, sb.z, sb.w};
#pragma unroll
            for (int h = 0; h < 8; h++) {
                float v = sl[h] + ad[h];
                raw[h] = (v >= 0.f) ? v : NEG_SLOPE * v;
            }
        }
        float m[8];
#pragma unroll
        for (int h = 0; h < 8; h++) m[h] = raw[h];
#pragma unroll
        for (int off = 32; off; off >>= 1)
#pragma unroll
            for (int h = 0; h < 8; h++) m[h] = fmaxf(m[h], __shfl_xor(m[h], off));
        float ex[8], sm[8];
#pragma unroll
        for (int h = 0; h < 8; h++) {
            ex[h] = (lane < deg) ? __expf(raw[h] - m[h]) : 0.f;
            sm[h] = ex[h];
        }
#pragma unroll
        for (int off = 32; off; off >>= 1)
#pragma unroll
            for (int h = 0; h < 8; h++) sm[h] += __shfl_xor(sm[h], off);
#pragma unroll
        for (int h = 0; h < 8; h++) {
            uint2 t;
            t.x = __float_as_uint(ex[h] * (1.0f / sm[h]));
            t.y = offb;
            aldsU[wv][h][lane] = t;
        }
        asm volatile("s_waitcnt lgkmcnt(0)" ::: "memory");

        int hl = lane >> 3;
        const uint2* myal = &aldsU[wv][hl][0];
        const char* base2 = (const char*)hlin + (lane << 4);
        float acc[8] = {};
        int e = 0;
        for (; e + 2 <= deg; e += 2) {
            uint2 t0 = myal[e];
            uint2 t1 = myal[e + 1];
            uint4 u0 = *(const uint4*)(base2 + t0.y);
            uint4 u1 = *(const uint4*)(base2 + t1.y);
            float a0 = __uint_as_float(t0.x), a1 = __uint_as_float(t1.x);
            acc[0] = fmaf(a0, bf2f(u0.x & 0xFFFFu), acc[0]);
            acc[1] = fmaf(a0, bf2f_hi(u0.x),        acc[1]);
            acc[2] = fmaf(a0, bf2f(u0.y & 0xFFFFu), acc[2]);
            acc[3] = fmaf(a0, bf2f_hi(u0.y),        acc[3]);
            acc[4] = fmaf(a0, bf2f(u0.z & 0xFFFFu), acc[4]);
            acc[5] = fmaf(a0, bf2f_hi(u0.z),        acc[5]);
            acc[6] = fmaf(a0, bf2f(u0.w & 0xFFFFu), acc[6]);
            acc[7] = fmaf(a0, bf2f_hi(u0.w),        acc[7]);
            acc[0] = fmaf(a1, bf2f(u1.x & 0xFFFFu), acc[0]);
            acc[1] = fmaf(a1, bf2f_hi(u1.x),        acc[1]);
            acc[2] = fmaf(a1, bf2f(u1.y & 0xFFFFu), acc[2]);
            acc[3] = fmaf(a1, bf2f_hi(u1.y),        acc[3]);
            acc[4] = fmaf(a1, bf2f(u1.z & 0xFFFFu), acc[4]);
            acc[5] = fmaf(a1, bf2f_hi(u1.z),        acc[5]);
            acc[6] = fmaf(a1, bf2f(u1.w & 0xFFFFu), acc[6]);
            acc[7] = fmaf(a1, bf2f_hi(u1.w),        acc[7]);
        }
        if (e < deg) {
            uint2 t0 = myal[e];
            uint4 u0 = *(const uint4*)(base2 + t0.y);
            float a0 = __uint_as_float(t0.x);
            acc[0] = fmaf(a0, bf2f(u0.x & 0xFFFFu), acc[0]);
            acc[1] = fmaf(a0, bf2f_hi(u0.x),        acc[1]);
            acc[2] = fmaf(a0, bf2f(u0.y & 0xFFFFu), acc[2]);
            acc[3] = fmaf(a0, bf2f_hi(u0.y),        acc[3]);
            acc[4] = fmaf(a0, bf2f(u0.z & 0xFFFFu), acc[4]);
            acc[5] = fmaf(a0, bf2f_hi(u0.z),        acc[5]);
            acc[6] = fmaf(a0, bf2f(u0.w & 0xFFFFu), acc[6]);
            acc[7] = fmaf(a0, bf2f_hi(u0.w),        acc[7]);
        }

        size_t idx = (size_t)node * 512 + lane * 8;
        float4 b0 = *(const float4*)(bias + lane * 8);
        float4 b1 = *(const float4*)(bias + lane * 8 + 4);
        float bb[8] = {b0.x, b0.y, b0.z, b0.w, b1.x, b1.y, b1.z, b1.w};
#pragma unroll
        for (int j = 0; j < 8; j++) fin[j] = gelu_f(acc[j] + bb[j]);
        if (dores) {
            uint4 up = *(const uint4*)(hio + idx);
            fin[0] += bf2f(up.x & 0xFFFFu); fin[1] += bf2f_hi(up.x);
            fin[2] += bf2f(up.y & 0xFFFFu); fin[3] += bf2f_hi(up.y);
            fin[4] += bf2f(up.z & 0xFFFFu); fin[5] += bf2f_hi(up.z);
            fin[6] += bf2f(up.w & 0xFFFFu); fin[7] += bf2f_hi(up.w);
        }
        uint4 pk;
        pk.x = (unsigned int)f2bf(fin[0]) | ((unsigned int)f2bf(fin[1]) << 16);
        pk.y = (unsigned int)f2bf(fin[2]) | ((unsigned int)f2bf(fin[3]) << 16);
        pk.z = (unsigned int)f2bf(fin[4]) | ((unsigned int)f2bf(fin[5]) << 16);
        pk.w = (unsigned int)f2bf(fin[6]) | ((unsigned int)f2bf(fin[7]) << 16);
        *(uint4*)(hio + idx) = pk;
#pragma unroll
        for (int j = 0; j < 8; j++) { s += fin[j]; s2 += fin[j] * fin[j]; }

        // full-wave LN stats, then write the pre-normalized row for the next GEMM
#pragma unroll
        for (int off = 32; off; off >>= 1) {
            s  += __shfl_xor(s, off);
            s2 += __shfl_xor(s2, off);
        }
        float mu = s * (1.0f / 512.0f);
        float rs = rsqrtf(s2 * (1.0f / 512.0f) - mu * mu + EPSV);
        float4 g0 = *(const float4*)(gn + lane * 8);
        float4 g1 = *(const float4*)(gn + lane * 8 + 4);
        float4 n0 = *(const float4*)(bn + lane * 8);
        float4 n1 = *(const float4*)(bn + lane * 8 + 4);
        float gg[8] = {g0.x, g0.y, g0.z, g0.w, g1.x, g1.y, g1.z, g1.w};
        float nb[8] = {n0.x, n0.y, n0.z, n0.w, n1.x, n1.y, n1.z, n1.w};
        float lnv[8];
#pragma unroll
        for (int j = 0; j < 8; j++) lnv[j] = fmaf((fin[j] - mu) * rs, gg[j], nb[j]);
        uint4 pl;
        pl.x = (unsigned int)f2bf(lnv[0]) | ((unsigned int)f2bf(lnv[1]) << 16);
        pl.y = (unsigned int)f2bf(lnv[2]) | ((unsigned int)f2bf(lnv[3]) << 16);
        pl.z = (unsigned int)f2bf(lnv[4]) | ((unsigned int)f2bf(lnv[5]) << 16);
        pl.w = (unsigned int)f2bf(lnv[6]) | ((unsigned int)f2bf(lnv[7]) << 16);
        *(uint4*)(abuf + idx) = pl;
    } else {
        // fallback (deg > 64): per-head 3-pass; lane owns channels h*64+lane
        float fins[8];
        for (int h = 0; h < 8; h++) {
            float adh = ad[h];
            float m = -INFINITY;
            for (int e = beg + lane; e < end; e += 64) {
                float v = alsrc[col[e] * 8 + h] + adh;
                v = (v >= 0.f) ? v : NEG_SLOPE * v;
                m = fmaxf(m, v);
            }
#pragma unroll
            for (int off = 32; off; off >>= 1) m = fmaxf(m, __shfl_xor(m, off));
            float sum = 0.f;
            for (int e = beg + lane; e < end; e += 64) {
                float v = alsrc[col[e] * 8 + h] + adh;
                v = (v >= 0.f) ? v : NEG_SLOPE * v;
                sum += __expf(v - m);
            }
#pragma unroll
            for (int off = 32; off; off >>= 1) sum += __shfl_xor(sum, off);
            float inv = 1.0f / sum;
            float acc = 0.f;
            for (int e = beg; e < end; e++) {
                int src = col[e];
                float v = alsrc[src * 8 + h] + adh;
                v = (v >= 0.f) ? v : NEG_SLOPE * v;
                float alpha = __expf(v - m) * inv;
                acc = fmaf(alpha, bf2f(hlin[((size_t)src << 9) + h * 64 + lane]), acc);
            }
            float fv = gelu_f(acc + bias[h * 64 + lane]);
            size_t idx = (size_t)node * 512 + h * 64 + lane;
            if (dores) fv += bf2f(hio[idx]);
            hio[idx] = f2bf(fv);
            fins[h] = fv;
            s += fv; s2 += fv * fv;
        }
#pragma unroll
        for (int off = 32; off; off >>= 1) {
            s  += __shfl_xor(s, off);
            s2 += __shfl_xor(s2, off);
        }
        float mu = s * (1.0f / 512.0f);
        float rs = rsqrtf(s2 * (1.0f / 512.0f) - mu * mu + EPSV);
        for (int h = 0; h < 8; h++) {
            int c = h * 64 + lane;
            abuf[(size_t)node * 512 + c] = f2bf(fmaf((fins[h] - mu) * rs, gn[c], bn[c]));
        }
    }
}

// ============================ final softmax+aggregate (heads=1, co=3) ============================
__global__ __launch_bounds__(256) void k_aggF(const bf16u* __restrict__ hlin3,
                                              const float* __restrict__ alsrc,
                                              const float* __restrict__ aldst,
                                              const int* __restrict__ rowptr,
                                              const int* __restrict__ col,
                                              const float* __restrict__ bias,
                                              float* __restrict__ outf,
                                              const float* __restrict__ resid, int n) {
    int node = (blockIdx.x * 256 + threadIdx.x) >> 6;
    int lane = threadIdx.x & 63;
    if (node >= n) return;
    int beg = rowptr[node], end = rowptr[node + 1];
    int deg = end - beg;
    float adh = aldst[node];

    if (deg <= 64) {
        int src = 0;
        float raw = -INFINITY;
        if (lane < deg) {
            src = col[beg + lane];
            float v = alsrc[src] + adh;
            raw = (v >= 0.f) ? v : NEG_SLOPE * v;
        }
        float m = raw;
#pragma unroll
        for (int off = 32; off; off >>= 1) m = fmaxf(m, __shfl_xor(m, off));
        float ex = (lane < deg) ? __expf(raw - m) : 0.f;
        float sum = ex;
#pragma unroll
        for (int off = 32; off; off >>= 1) sum += __shfl_xor(sum, off);
        float alpha = ex / sum;

        float c0 = 0.f, c1 = 0.f, c2 = 0.f;
        if (lane < deg) {
            uint2 u = *(const uint2*)(hlin3 + (size_t)src * 4);
            c0 = alpha * bf2f(u.x & 0xFFFFu);
            c1 = alpha * bf2f_hi(u.x);
            c2 = alpha * bf2f(u.y & 0xFFFFu);
        }
#pragma unroll
        for (int off = 32; off; off >>= 1) {
            c0 += __shfl_xor(c0, off);
            c1 += __shfl_xor(c1, off);
            c2 += __shfl_xor(c2, off);
        }
        if (lane == 0) {
            outf[node * 3 + 0] = c0 + bias[0] + resid[node * 3 + 0];
            outf[node * 3 + 1] = c1 + bias[1] + resid[node * 3 + 1];
            outf[node * 3 + 2] = c2 + bias[2] + resid[node * 3 + 2];
        }
    } else {
        float m = -INFINITY;
        for (int e = beg + lane; e < end; e += 64) {
            float v = alsrc[col[e]] + adh;
            v = (v >= 0.f) ? v : NEG_SLOPE * v;
            m = fmaxf(m, v);
        }
#pragma unroll
        for (int off = 32; off; off >>= 1) m = fmaxf(m, __shfl_xor(m, off));
        float sum = 0.f;
        for (int e = beg + lane; e < end; e += 64) {
            float v = alsrc[col[e]] + adh;
            v = (v >= 0.f) ? v : NEG_SLOPE * v;
            sum += __expf(v - m);
        }
#pragma unroll
        for (int off = 32; off; off >>= 1) sum += __shfl_xor(sum, off);
        float inv = 1.0f / sum;
        float acc = 0.f;
        for (int e = beg; e < end; e++) {
            int src = col[e];
            float v = alsrc[src] + adh;
            v = (v >= 0.f) ? v : NEG_SLOPE * v;
            float alpha = __expf(v - m) * inv;
            if (lane < 3) acc += alpha * bf2f(hlin3[(size_t)src * 4 + lane]);
        }
        if (lane < 3)
            outf[node * 3 + lane] = acc + bias[lane] + resid[node * 3 + lane];
    }
}

// ============================ launch ============================
extern "C" void kernel_launch(void* const* d_in, const int* in_sizes, int n_in,
                              void* d_out, int out_size, void* d_ws, size_t ws_size,
                              hipStream_t stream) {
    const float* x    = (const float*)d_in[0];
    const int*   ei   = (const int*)d_in[1];
    const float* resW = (const float*)d_in[2];
    const float* resb = (const float*)d_in[3];
    const float *lng[4], *lnb[4], *Wm[4], *asr[4], *adt[4], *bias[4];
    int idx = 4;
    for (int i = 0; i < 4; i++) {
        lng[i]  = (const float*)d_in[idx++];
        lnb[i]  = (const float*)d_in[idx++];
        Wm[i]   = (const float*)d_in[idx++];
        asr[i]  = (const float*)d_in[idx++];
        adt[i]  = (const float*)d_in[idx++];
        bias[i] = (const float*)d_in[idx++];
    }

    char* base = (char*)d_ws;
    size_t off = 0;
    auto alloc = [&](size_t bytes) {
        void* p = base + off;
        off += (bytes + 255) & ~(size_t)255;
        return p;
    };
    float* stats = (float*)alloc((size_t)MPAD * 2 * 4);
    float* alsrc = (float*)alloc((size_t)NN * 8 * 4);
    float* aldst = (float*)alloc((size_t)NN * 8 * 4);
    float* resid = (float*)alloc((size_t)NN * 3 * 4);
    int* rowptr  = (int*)alloc((size_t)(NN + 1) * 4);
    int* cursor  = (int*)alloc((size_t)NN * 4);
    int* deg     = (int*)alloc((size_t)NN * 4);
    int* colidx  = (int*)alloc((size_t)NE * 4);
    int* bsums   = (int*)alloc(256 * 4);
    bf16u* wb0   = (bf16u*)alloc((size_t)512 * 128 * 2);
    bf16u* wb1   = (bf16u*)alloc((size_t)512 * 512 * 2);
    bf16u* wb2   = (bf16u*)alloc((size_t)512 * 512 * 2);
    bf16u* hbuf  = (bf16u*)alloc((size_t)MPAD * 512 * 2);
    bf16u* lbuf  = (bf16u*)alloc((size_t)MPAD * 512 * 2);
    size_t base_need = off;
    bf16u* abuf  = (bf16u*)alloc((size_t)MPAD * 512 * 2);
    int useNew = (off <= ws_size) ? 1 : 0;
    if (base_need > ws_size) return;   // cannot run at all

    float* out = (float*)d_out;

    // ---- CSR build ----
    k_zero_i32<<<(NN + 255) / 256, 256, 0, stream>>>(deg, NN);
    k_deg<<<(NE + 255) / 256, 256, 0, stream>>>(ei, deg);
    int nb = (NN + 1023) / 1024;
    k_scan1<<<nb, 256, 0, stream>>>(deg, rowptr, bsums, NN);
    k_scan2<<<1, 64, 0, stream>>>(bsums, nb);
    k_scan3<<<(NN + 1 + 255) / 256, 256, 0, stream>>>(deg, rowptr, cursor, bsums, NN, NE);
    k_scatter<<<(NE + 255) / 256, 256, 0, stream>>>(ei, cursor, colidx);

    int rowBlocks = (NN * 64 + 255) / 256;       // 12500
    k_cast<<<(512 * 128 + 255) / 256, 256, 0, stream>>>(Wm[0], wb0, 512 * 128);
    k_cast<<<(512 * 512 + 255) / 256, 256, 0, stream>>>(Wm[1], wb1, 512 * 512);
    k_cast<<<(512 * 512 + 255) / 256, 256, 0, stream>>>(Wm[2], wb2, 512 * 512);

    const bf16u* wb[3] = {wb0, wb1, wb2};
    const int ci_a[3] = {128, 512, 512};
    dim3 ggrid(MPAD / BM, 512 / BN);

    if (useNew) {
        // ======== NEW PATH: pre-normalized A buffer ========
        k_castres2<<<rowBlocks, 256, 0, stream>>>(x, resW, resb, lng[0], lnb[0],
                                                  abuf, resid, NN);
        for (int i = 0; i < 3; i++) {
            int dores = (i >= 1) ? 1 : 0;
            k_gemm_pure<<<ggrid, 256, 0, stream>>>(abuf, wb[i], lbuf,
                                                   asr[i], adt[i], alsrc, aldst,
                                                   NN, ci_a[i], 512);
            k_aggN2<<<rowBlocks, 256, 0, stream>>>(lbuf, alsrc, aldst, rowptr, colidx,
                                                   bias[i], hbuf, lng[i + 1], lnb[i + 1],
                                                   abuf, NN, dores);
        }
        k_lin3b<<<rowBlocks, 256, 0, stream>>>(abuf, Wm[3], asr[3], adt[3],
                                               lbuf, alsrc, aldst, NN);
    } else {
        // ======== OLD PATH (round-6 structure) ========
        k_castres<<<rowBlocks, 256, 0, stream>>>(x, resW, resb, hbuf, stats, resid, NN);
        for (int i = 0; i < 3; i++) {
            int dores = (i >= 1) ? 1 : 0;
            k_gemm_mfma<<<ggrid, 256, 0, stream>>>(hbuf, stats, lng[i], lnb[i], wb[i],
                                                   lbuf, asr[i], adt[i], alsrc, aldst,
                                                   NN, ci_a[i], 512);
            k_aggN<<<rowBlocks, 256, 0, stream>>>(lbuf, alsrc, aldst, rowptr, colidx,
                                                  bias[i], hbuf, stats, NN, dores);
        }
        k_lin3<<<rowBlocks, 256, 0, stream>>>(hbuf, stats, lng[3], lnb[3], Wm[3],
                                              asr[3], adt[3], lbuf, alsrc, aldst, NN);
    }

    k_aggF<<<rowBlocks, 256, 0, stream>>>(lbuf, alsrc, aldst, rowptr, colidx,
                                          bias[3], out, resid, NN);
}

// Round 8
// 664.893 us; speedup vs baseline: 4.5108x; 1.0023x over previous
//
#include <hip/hip_runtime.h>
#include <math.h>

#define NN 50000
#define MPAD 50048          // 391 * 128
#define EE 400000
#define NE 450000           // EE + NN self loops
#define IN_F 128
#define NEG_SLOPE 0.2f
#define EPSV 1e-6f

typedef unsigned short bf16u;
typedef short bf8_t __attribute__((ext_vector_type(8)));
typedef float f32x4 __attribute__((ext_vector_type(4)));

__device__ __forceinline__ float bf2f(unsigned int u) {
    return __uint_as_float(u << 16);
}
__device__ __forceinline__ float bf2f_hi(unsigned int u) {
    return __uint_as_float(u & 0xFFFF0000u);
}
__device__ __forceinline__ bf16u f2bf(float f) {
    unsigned int u = __float_as_uint(f);
    unsigned int r = (u + 0x7FFFu + ((u >> 16) & 1u)) >> 16;
    return (bf16u)r;
}
__device__ __forceinline__ float gelu_f(float v) {
    return 0.5f * v * (1.0f + erff(v * 0.70710678118654752f));
}
__device__ __forceinline__ float lrelu(float v) {
    return fmaxf(v, NEG_SLOPE * v);
}

__device__ __forceinline__ void gload_lds16(const void* g, void* l) {
    __builtin_amdgcn_global_load_lds(
        (__attribute__((address_space(1))) void*)(g),
        (__attribute__((address_space(3))) void*)(l), 16, 0, 0);
}

// ============================ CSR build ============================
__global__ void k_zero_i32(int* p, int n) {
    int i = blockIdx.x * 256 + threadIdx.x;
    if (i < n) p[i] = 0;
}

__global__ void k_deg(const int* __restrict__ ei, int* __restrict__ deg) {
    int i = blockIdx.x * 256 + threadIdx.x;
    if (i >= NE) return;
    int d = (i < EE) ? ei[EE + i] : (i - EE);
    atomicAdd(&deg[d], 1);
}

__global__ __launch_bounds__(256) void k_scan1(const int* __restrict__ deg,
                                               int* __restrict__ incl,
                                               int* __restrict__ bsums, int n) {
    __shared__ int sm[1024];
    int base = blockIdx.x * 1024;
    for (int i = threadIdx.x; i < 1024; i += 256)
        sm[i] = (base + i < n) ? deg[base + i] : 0;
    __syncthreads();
    for (int off = 1; off < 1024; off <<= 1) {
        int v[4];
#pragma unroll
        for (int j = 0; j < 4; j++) {
            int i = threadIdx.x + 256 * j;
            v[j] = (i >= off) ? sm[i - off] : 0;
        }
        __syncthreads();
#pragma unroll
        for (int j = 0; j < 4; j++) {
            int i = threadIdx.x + 256 * j;
            sm[i] += v[j];
        }
        __syncthreads();
    }
    for (int i = threadIdx.x; i < 1024; i += 256)
        if (base + i < n) incl[base + i] = sm[i];
    if (threadIdx.x == 0) bsums[blockIdx.x] = sm[1023];
}

__global__ void k_scan2(int* bsums, int nb) {
    if (threadIdx.x == 0 && blockIdx.x == 0) {
        int run = 0;
        for (int i = 0; i < nb; i++) { int v = bsums[i]; bsums[i] = run; run += v; }
    }
}

__global__ void k_scan3(const int* __restrict__ deg, int* __restrict__ rowptr,
                        int* __restrict__ cursor, const int* __restrict__ bsums,
                        int n, int ne) {
    int i = blockIdx.x * 256 + threadIdx.x;
    if (i < n) {
        int excl = rowptr[i] + bsums[i >> 10] - deg[i];
        rowptr[i] = excl;
        cursor[i] = excl;
    }
    if (i == n) rowptr[n] = ne;
}

__global__ void k_scatter(const int* __restrict__ ei, int* __restrict__ cursor,
                          int* __restrict__ col) {
    int i = blockIdx.x * 256 + threadIdx.x;
    if (i >= NE) return;
    int s, d;
    if (i < EE) { s = ei[i]; d = ei[EE + i]; }
    else        { s = i - EE; d = i - EE; }
    int p = atomicAdd(&cursor[d], 1);
    col[p] = s;
}

// ============================ f32 -> bf16 cast (weights) ============================
__global__ void k_cast(const float* __restrict__ x, bf16u* __restrict__ h, int total) {
    int i = blockIdx.x * 256 + threadIdx.x;
    if (i < total) h[i] = f2bf(x[i]);
}

// ======== cast x -> LN'd bf16 (g0,b0 applied) + residual head ========
__global__ __launch_bounds__(256) void k_castres2(const float* __restrict__ x,
                                                  const float* __restrict__ rw,
                                                  const float* __restrict__ rb,
                                                  const float* __restrict__ g0,
                                                  const float* __restrict__ b0,
                                                  bf16u* __restrict__ abuf,
                                                  float* __restrict__ res, int n) {
    int row = (blockIdx.x * 256 + threadIdx.x) >> 6;
    int lane = threadIdx.x & 63;
    if (row >= n) return;
    float2 v = *(const float2*)(x + (size_t)row * 128 + lane * 2);
    float2 w0 = *(const float2*)(rw + 0 * 128 + lane * 2);
    float2 w1 = *(const float2*)(rw + 1 * 128 + lane * 2);
    float2 w2 = *(const float2*)(rw + 2 * 128 + lane * 2);
    float s = v.x + v.y, s2 = v.x * v.x + v.y * v.y;
    float a0 = v.x * w0.x + v.y * w0.y;
    float a1 = v.x * w1.x + v.y * w1.y;
    float a2 = v.x * w2.x + v.y * w2.y;
#pragma unroll
    for (int off = 32; off; off >>= 1) {
        s  += __shfl_xor(s, off);
        s2 += __shfl_xor(s2, off);
        a0 += __shfl_xor(a0, off);
        a1 += __shfl_xor(a1, off);
        a2 += __shfl_xor(a2, off);
    }
    float mu = s * (1.0f / 128.0f);
    float var = s2 * (1.0f / 128.0f) - mu * mu;
    float rs = rsqrtf(var + EPSV);
    float2 gg = *(const float2*)(g0 + lane * 2);
    float2 bb = *(const float2*)(b0 + lane * 2);
    float l0 = fmaf((v.x - mu) * rs, gg.x, bb.x);
    float l1 = fmaf((v.y - mu) * rs, gg.y, bb.y);
    *(unsigned int*)(abuf + (size_t)row * 128 + lane * 2) =
        (unsigned int)f2bf(l0) | ((unsigned int)f2bf(l1) << 16);
    if (lane == 0) {
        res[row * 3 + 0] = a0 + rb[0];
        res[row * 3 + 1] = a1 + rb[1];
        res[row * 3 + 2] = a2 + rb[2];
    }
}

// ============ Double-buffered pure bf16 MFMA GEMM + fused al epilogue ============
// BK=64, both operands via global_load_lds; XOR swizzle (elem ^= (row&7)<<3) applied
// to the GLOBAL source column (LDS dest linear) and to the ds_read address.
// 2-phase: issue next tile's loads BEFORE computing the current tile; one barrier/step.
#define BM 128
#define BN 128
#define BK2 64
__global__ __launch_bounds__(256) void k_gemm_db(const bf16u* __restrict__ A,
                                                 const bf16u* __restrict__ Wb,
                                                 bf16u* __restrict__ C,
                                                 const float* __restrict__ asr,
                                                 const float* __restrict__ adt,
                                                 float* __restrict__ alsrc,
                                                 float* __restrict__ aldst,
                                                 int Mreal, int ci, int K) {
    __shared__ __align__(16) bf16u As[2][BM * BK2];
    __shared__ __align__(16) bf16u Bs[2][BN * BK2];
    const int tid = threadIdx.x;
    const int w = tid >> 6, lane = tid & 63;
    const int row0 = blockIdx.x * BM, col0 = blockIdx.y * BN;
    const int wr = (w >> 1) * 64, wc = (w & 1) * 64;

    // staging: wave w covers rows [w*32, w*32+32), 4 issues of 8 rows (128B/row)
    const int lrow = lane >> 3;                            // row within issue
    const int scolx = ((lane & 7) * 8) ^ (lrow << 3);      // pre-swizzled source col
    const bf16u* gA = A + (size_t)(row0 + w * 32 + lrow) * ci + scolx;
    const bf16u* gB = Wb + (size_t)(col0 + w * 32 + lrow) * ci + scolx;

    const int nk = ci / BK2;

    // prologue: stage tile 0 into buf 0
#pragma unroll
    for (int j = 0; j < 4; j++) {
        gload_lds16(gA + (size_t)(j * 8) * ci, &As[0][(w * 32 + j * 8) * BK2]);
        gload_lds16(gB + (size_t)(j * 8) * ci, &Bs[0][(w * 32 + j * 8) * BK2]);
    }
    __syncthreads();     // compiler drains vmcnt(0) before barrier

    f32x4 acc[4][4] = {};
    const int fr = lane & 15;
    const int fk = (lane >> 4) * 8;
    const int fxor = (fr & 7) << 3;

    for (int t = 0; t < nk; t++) {
        const int cur = t & 1;
        if (t + 1 < nk) {
            const int k0 = (t + 1) * BK2;
#pragma unroll
            for (int j = 0; j < 4; j++) {
                gload_lds16(gA + (size_t)(j * 8) * ci + k0, &As[cur ^ 1][(w * 32 + j * 8) * BK2]);
                gload_lds16(gB + (size_t)(j * 8) * ci + k0, &Bs[cur ^ 1][(w * 32 + j * 8) * BK2]);
            }
        }
#pragma unroll
        for (int ks = 0; ks < 2; ks++) {
            bf8_t af[4], bfv[4];
#pragma unroll
            for (int m = 0; m < 4; m++)
                af[m] = *(const bf8_t*)&As[cur][(wr + m * 16 + fr) * BK2 + ((ks * 32 + fk) ^ fxor)];
#pragma unroll
            for (int n = 0; n < 4; n++)
                bfv[n] = *(const bf8_t*)&Bs[cur][(wc + n * 16 + fr) * BK2 + ((ks * 32 + fk) ^ fxor)];
#pragma unroll
            for (int m = 0; m < 4; m++)
#pragma unroll
                for (int n = 0; n < 4; n++)
                    acc[m][n] = __builtin_amdgcn_mfma_f32_16x16x32_bf16(af[m], bfv[n], acc[m][n], 0, 0, 0);
        }
        if (t + 1 < nk) __syncthreads();   // drains next tile's loads; syncs readers
    }

    const int fc = lane & 15;
    const int fq = (lane >> 4) * 4;

    // ---- C store ----
#pragma unroll
    for (int m = 0; m < 4; m++) {
#pragma unroll
        for (int r = 0; r < 4; r++) {
            int row = row0 + wr + m * 16 + fq + r;
            if (row >= Mreal) continue;
#pragma unroll
            for (int n = 0; n < 4; n++) {
                int col = col0 + wc + n * 16 + fc;
                C[(size_t)row * K + col] = f2bf(acc[m][n][r]);
            }
        }
    }

    // ---- fused attention-logit dots (head = this wave's 64 cols) ----
    const int head = blockIdx.y * 2 + (wc >> 6);
    float av[4], dv[4];
#pragma unroll
    for (int n = 0; n < 4; n++) {
        av[n] = asr[head * 64 + n * 16 + fc];
        dv[n] = adt[head * 64 + n * 16 + fc];
    }
#pragma unroll
    for (int m = 0; m < 4; m++) {
#pragma unroll
        for (int r = 0; r < 4; r++) {
            float s1 = acc[m][0][r] * av[0] + acc[m][1][r] * av[1]
                     + acc[m][2][r] * av[2] + acc[m][3][r] * av[3];
            float s2 = acc[m][0][r] * dv[0] + acc[m][1][r] * dv[1]
                     + acc[m][2][r] * dv[2] + acc[m][3][r] * dv[3];
#pragma unroll
            for (int o = 1; o < 16; o <<= 1) {
                s1 += __shfl_xor(s1, o);
                s2 += __shfl_xor(s2, o);
            }
            int row = row0 + wr + m * 16 + fq + r;
            if (fc == 0 && row < Mreal) {
                alsrc[row * 8 + head] = s1;
                aldst[row * 8 + head] = s2;
            }
        }
    }
}

// ============ layer-3 matvec + logits (input already LN'd) ============
__global__ __launch_bounds__(256) void k_lin3b(const bf16u* __restrict__ an,
                                               const float* __restrict__ W,
                                               const float* __restrict__ a_s,
                                               const float* __restrict__ a_d,
                                               bf16u* __restrict__ hlin3,
                                               float* __restrict__ alsrc,
                                               float* __restrict__ aldst, int n) {
    int row = (blockIdx.x * 256 + threadIdx.x) >> 6;
    int lane = threadIdx.x & 63;
    if (row >= n) return;
    uint4 r = *(const uint4*)(an + (size_t)row * 512 + lane * 8);
    unsigned int u[4] = {r.x, r.y, r.z, r.w};
    float ln[8];
#pragma unroll
    for (int j = 0; j < 4; j++) {
        ln[2 * j]     = bf2f(u[j] & 0xFFFFu);
        ln[2 * j + 1] = bf2f_hi(u[j]);
    }
    float a0 = 0.f, a1 = 0.f, a2 = 0.f;
#pragma unroll
    for (int j = 0; j < 8; j++) {
        int k = lane * 8 + j;
        a0 += ln[j] * W[k];
        a1 += ln[j] * W[512 + k];
        a2 += ln[j] * W[1024 + k];
    }
#pragma unroll
    for (int off = 32; off; off >>= 1) {
        a0 += __shfl_down(a0, off);
        a1 += __shfl_down(a1, off);
        a2 += __shfl_down(a2, off);
    }
    if (lane == 0) {
        *(unsigned int*)(hlin3 + (size_t)row * 4) =
            (unsigned int)f2bf(a0) | ((unsigned int)f2bf(a1) << 16);
        *(unsigned int*)(hlin3 + (size_t)row * 4 + 2) = (unsigned int)f2bf(a2);
        alsrc[row] = a0 * a_s[0] + a1 * a_s[1] + a2 * a_s[2];
        aldst[row] = a0 * a_d[0] + a1 * a_d[1] + a2 * a_d[2];
    }
}

// ============ aggregate + epilogue (gelu/residual) + writes LN'd row (next layer's A) ============
__global__ __launch_bounds__(256) void k_aggN2(const bf16u* __restrict__ hlin,
                                               const float* __restrict__ alsrc,
                                               const float* __restrict__ aldst,
                                               const int* __restrict__ rowptr,
                                               const int* __restrict__ col,
                                               const float* __restrict__ bias,
                                               bf16u* __restrict__ hio,
                                               const float* __restrict__ gn,
                                               const float* __restrict__ bn,
                                               bf16u* __restrict__ abuf,
                                               int n, int dores) {
    __shared__ uint2 aldsU[4][8][66];
    int wv = threadIdx.x >> 6;
    int node = (blockIdx.x * 256 + threadIdx.x) >> 6;
    int lane = threadIdx.x & 63;
    if (node >= n) return;
    int beg = rowptr[node], end = rowptr[node + 1];
    int deg = end - beg;

    const float4* dvv = (const float4*)(aldst + node * 8);
    float4 da = dvv[0], db = dvv[1];
    float ad[8] = {da.x, da.y, da.z, da.w, db.x, db.y, db.z, db.w};

    float s = 0.f, s2 = 0.f;
    float fin[8];

    if (deg <= 64) {
        unsigned int offb = 0;
        float raw[8];
#pragma unroll
        for (int h = 0; h < 8; h++) raw[h] = -INFINITY;
        if (lane < deg) {
            int srcreg = col[beg + lane];
            offb = (unsigned int)srcreg << 10;
            const float4* sv = (const float4*)(alsrc + srcreg * 8);
            float4 sa = sv[0], sb = sv[1];
            float sl[8] = {sa.x, sa.y, sa.z, sa.w, sb.x, sb.y, sb.z, sb.w};
#pragma unroll
            for (int h = 0; h < 8; h++) raw[h] = lrelu(sl[h] + ad[h]);
        }
        float m[8];
#pragma unroll
        for (int h = 0; h < 8; h++) m[h] = raw[h];
#pragma unroll
        for (int off = 32; off; off >>= 1)
#pragma unroll
            for (int h = 0; h < 8; h++) m[h] = fmaxf(m[h], __shfl_xor(m[h], off));
        float ex[8], sm[8];
#pragma unroll
        for (int h = 0; h < 8; h++) {
            ex[h] = (lane < deg) ? __expf(raw[h] - m[h]) : 0.f;
            sm[h] = ex[h];
        }
#pragma unroll
        for (int off = 32; off; off >>= 1)
#pragma unroll
            for (int h = 0; h < 8; h++) sm[h] += __shfl_xor(sm[h], off);
#pragma unroll
        for (int h = 0; h < 8; h++) {
            uint2 t;
            t.x = __float_as_uint(ex[h] * (1.0f / sm[h]));
            t.y = offb;
            aldsU[wv][h][lane] = t;
        }
        asm volatile("s_waitcnt lgkmcnt(0)" ::: "memory");

        int hl = lane >> 3;
        const uint2* myal = &aldsU[wv][hl][0];
        const char* base2 = (const char*)hlin + (lane << 4);
        float acc[8] = {};
        int e = 0;
        for (; e + 2 <= deg; e += 2) {
            uint2 t0 = myal[e];
            uint2 t1 = myal[e + 1];
            uint4 u0 = *(const uint4*)(base2 + t0.y);
            uint4 u1 = *(const uint4*)(base2 + t1.y);
            float a0 = __uint_as_float(t0.x), a1 = __uint_as_float(t1.x);
            acc[0] = fmaf(a0, bf2f(u0.x & 0xFFFFu), acc[0]);
            acc[1] = fmaf(a0, bf2f_hi(u0.x),        acc[1]);
            acc[2] = fmaf(a0, bf2f(u0.y & 0xFFFFu), acc[2]);
            acc[3] = fmaf(a0, bf2f_hi(u0.y),        acc[3]);
            acc[4] = fmaf(a0, bf2f(u0.z & 0xFFFFu), acc[4]);
            acc[5] = fmaf(a0, bf2f_hi(u0.z),        acc[5]);
            acc[6] = fmaf(a0, bf2f(u0.w & 0xFFFFu), acc[6]);
            acc[7] = fmaf(a0, bf2f_hi(u0.w),        acc[7]);
            acc[0] = fmaf(a1, bf2f(u1.x & 0xFFFFu), acc[0]);
            acc[1] = fmaf(a1, bf2f_hi(u1.x),        acc[1]);
            acc[2] = fmaf(a1, bf2f(u1.y & 0xFFFFu), acc[2]);
            acc[3] = fmaf(a1, bf2f_hi(u1.y),        acc[3]);
            acc[4] = fmaf(a1, bf2f(u1.z & 0xFFFFu), acc[4]);
            acc[5] = fmaf(a1, bf2f_hi(u1.z),        acc[5]);
            acc[6] = fmaf(a1, bf2f(u1.w & 0xFFFFu), acc[6]);
            acc[7] = fmaf(a1, bf2f_hi(u1.w),        acc[7]);
        }
        if (e < deg) {
            uint2 t0 = myal[e];
            uint4 u0 = *(const uint4*)(base2 + t0.y);
            float a0 = __uint_as_float(t0.x);
            acc[0] = fmaf(a0, bf2f(u0.x & 0xFFFFu), acc[0]);
            acc[1] = fmaf(a0, bf2f_hi(u0.x),        acc[1]);
            acc[2] = fmaf(a0, bf2f(u0.y & 0xFFFFu), acc[2]);
            acc[3] = fmaf(a0, bf2f_hi(u0.y),        acc[3]);
            acc[4] = fmaf(a0, bf2f(u0.z & 0xFFFFu), acc[4]);
            acc[5] = fmaf(a0, bf2f_hi(u0.z),        acc[5]);
            acc[6] = fmaf(a0, bf2f(u0.w & 0xFFFFu), acc[6]);
            acc[7] = fmaf(a0, bf2f_hi(u0.w),        acc[7]);
        }

        size_t idx = (size_t)node * 512 + lane * 8;
        float4 b0 = *(const float4*)(bias + lane * 8);
        float4 b1 = *(const float4*)(bias + lane * 8 + 4);
        float bb[8] = {b0.x, b0.y, b0.z, b0.w, b1.x, b1.y, b1.z, b1.w};
#pragma unroll
        for (int j = 0; j < 8; j++) fin[j] = gelu_f(acc[j] + bb[j]);
        if (dores) {
            uint4 up = *(const uint4*)(hio + idx);
            fin[0] += bf2f(up.x & 0xFFFFu); fin[1] += bf2f_hi(up.x);
            fin[2] += bf2f(up.y & 0xFFFFu); fin[3] += bf2f_hi(up.y);
            fin[4] += bf2f(up.z & 0xFFFFu); fin[5] += bf2f_hi(up.z);
            fin[6] += bf2f(up.w & 0xFFFFu); fin[7] += bf2f_hi(up.w);
        }
        uint4 pk;
        pk.x = (unsigned int)f2bf(fin[0]) | ((unsigned int)f2bf(fin[1]) << 16);
        pk.y = (unsigned int)f2bf(fin[2]) | ((unsigned int)f2bf(fin[3]) << 16);
        pk.z = (unsigned int)f2bf(fin[4]) | ((unsigned int)f2bf(fin[5]) << 16);
        pk.w = (unsigned int)f2bf(fin[6]) | ((unsigned int)f2bf(fin[7]) << 16);
        *(uint4*)(hio + idx) = pk;
#pragma unroll
        for (int j = 0; j < 8; j++) { s += fin[j]; s2 += fin[j] * fin[j]; }

        // full-wave LN stats, then write the pre-normalized row for the next GEMM
#pragma unroll
        for (int off = 32; off; off >>= 1) {
            s  += __shfl_xor(s, off);
            s2 += __shfl_xor(s2, off);
        }
        float mu = s * (1.0f / 512.0f);
        float rs = rsqrtf(s2 * (1.0f / 512.0f) - mu * mu + EPSV);
        float4 g0 = *(const float4*)(gn + lane * 8);
        float4 g1 = *(const float4*)(gn + lane * 8 + 4);
        float4 n0 = *(const float4*)(bn + lane * 8);
        float4 n1 = *(const float4*)(bn + lane * 8 + 4);
        float gg[8] = {g0.x, g0.y, g0.z, g0.w, g1.x, g1.y, g1.z, g1.w};
        float nb[8] = {n0.x, n0.y, n0.z, n0.w, n1.x, n1.y, n1.z, n1.w};
        float lnv[8];
#pragma unroll
        for (int j = 0; j < 8; j++) lnv[j] = fmaf((fin[j] - mu) * rs, gg[j], nb[j]);
        uint4 pl;
        pl.x = (unsigned int)f2bf(lnv[0]) | ((unsigned int)f2bf(lnv[1]) << 16);
        pl.y = (unsigned int)f2bf(lnv[2]) | ((unsigned int)f2bf(lnv[3]) << 16);
        pl.z = (unsigned int)f2bf(lnv[4]) | ((unsigned int)f2bf(lnv[5]) << 16);
        pl.w = (unsigned int)f2bf(lnv[6]) | ((unsigned int)f2bf(lnv[7]) << 16);
        *(uint4*)(abuf + idx) = pl;
    } else {
        // fallback (deg > 64): per-head 3-pass; lane owns channels h*64+lane
        float fins[8];
        for (int h = 0; h < 8; h++) {
            float adh = ad[h];
            float m = -INFINITY;
            for (int e = beg + lane; e < end; e += 64)
                m = fmaxf(m, lrelu(alsrc[col[e] * 8 + h] + adh));
#pragma unroll
            for (int off = 32; off; off >>= 1) m = fmaxf(m, __shfl_xor(m, off));
            float sum = 0.f;
            for (int e = beg + lane; e < end; e += 64)
                sum += __expf(lrelu(alsrc[col[e] * 8 + h] + adh) - m);
#pragma unroll
            for (int off = 32; off; off >>= 1) sum += __shfl_xor(sum, off);
            float inv = 1.0f / sum;
            float acc = 0.f;
            for (int e = beg; e < end; e++) {
                int src = col[e];
                float alpha = __expf(lrelu(alsrc[src * 8 + h] + adh) - m) * inv;
                acc = fmaf(alpha, bf2f(hlin[((size_t)src << 9) + h * 64 + lane]), acc);
            }
            float fv = gelu_f(acc + bias[h * 64 + lane]);
            size_t idx = (size_t)node * 512 + h * 64 + lane;
            if (dores) fv += bf2f(hio[idx]);
            hio[idx] = f2bf(fv);
            fins[h] = fv;
            s += fv; s2 += fv * fv;
        }
#pragma unroll
        for (int off = 32; off; off >>= 1) {
            s  += __shfl_xor(s, off);
            s2 += __shfl_xor(s2, off);
        }
        float mu = s * (1.0f / 512.0f);
        float rs = rsqrtf(s2 * (1.0f / 512.0f) - mu * mu + EPSV);
        for (int h = 0; h < 8; h++) {
            int c = h * 64 + lane;
            abuf[(size_t)node * 512 + c] = f2bf(fmaf((fins[h] - mu) * rs, gn[c], bn[c]));
        }
    }
}

// ============================ final softmax+aggregate (heads=1, co=3) ============================
__global__ __launch_bounds__(256) void k_aggF(const bf16u* __restrict__ hlin3,
                                              const float* __restrict__ alsrc,
                                              const float* __restrict__ aldst,
                                              const int* __restrict__ rowptr,
                                              const int* __restrict__ col,
                                              const float* __restrict__ bias,
                                              float* __restrict__ outf,
                                              const float* __restrict__ resid, int n) {
    int node = (blockIdx.x * 256 + threadIdx.x) >> 6;
    int lane = threadIdx.x & 63;
    if (node >= n) return;
    int beg = rowptr[node], end = rowptr[node + 1];
    int deg = end - beg;
    float adh = aldst[node];

    if (deg <= 64) {
        int src = 0;
        float raw = -INFINITY;
        if (lane < deg) {
            src = col[beg + lane];
            raw = lrelu(alsrc[src] + adh);
        }
        float m = raw;
#pragma unroll
        for (int off = 32; off; off >>= 1) m = fmaxf(m, __shfl_xor(m, off));
        float ex = (lane < deg) ? __expf(raw - m) : 0.f;
        float sum = ex;
#pragma unroll
        for (int off = 32; off; off >>= 1) sum += __shfl_xor(sum, off);
        float alpha = ex / sum;

        float c0 = 0.f, c1 = 0.f, c2 = 0.f;
        if (lane < deg) {
            uint2 u = *(const uint2*)(hlin3 + (size_t)src * 4);
            c0 = alpha * bf2f(u.x & 0xFFFFu);
            c1 = alpha * bf2f_hi(u.x);
            c2 = alpha * bf2f(u.y & 0xFFFFu);
        }
#pragma unroll
        for (int off = 32; off; off >>= 1) {
            c0 += __shfl_xor(c0, off);
            c1 += __shfl_xor(c1, off);
            c2 += __shfl_xor(c2, off);
        }
        if (lane == 0) {
            outf[node * 3 + 0] = c0 + bias[0] + resid[node * 3 + 0];
            outf[node * 3 + 1] = c1 + bias[1] + resid[node * 3 + 1];
            outf[node * 3 + 2] = c2 + bias[2] + resid[node * 3 + 2];
        }
    } else {
        float m = -INFINITY;
        for (int e = beg + lane; e < end; e += 64)
            m = fmaxf(m, lrelu(alsrc[col[e]] + adh));
#pragma unroll
        for (int off = 32; off; off >>= 1) m = fmaxf(m, __shfl_xor(m, off));
        float sum = 0.f;
        for (int e = beg + lane; e < end; e += 64)
            sum += __expf(lrelu(alsrc[col[e]] + adh) - m);
#pragma unroll
        for (int off = 32; off; off >>= 1) sum += __shfl_xor(sum, off);
        float inv = 1.0f / sum;
        float acc = 0.f;
        for (int e = beg; e < end; e++) {
            int src = col[e];
            float alpha = __expf(lrelu(alsrc[src] + adh) - m) * inv;
            if (lane < 3) acc += alpha * bf2f(hlin3[(size_t)src * 4 + lane]);
        }
        if (lane < 3)
            outf[node * 3 + lane] = acc + bias[lane] + resid[node * 3 + lane];
    }
}

// ============================ launch ============================
extern "C" void kernel_launch(void* const* d_in, const int* in_sizes, int n_in,
                              void* d_out, int out_size, void* d_ws, size_t ws_size,
                              hipStream_t stream) {
    const float* x    = (const float*)d_in[0];
    const int*   ei   = (const int*)d_in[1];
    const float* resW = (const float*)d_in[2];
    const float* resb = (const float*)d_in[3];
    const float *lng[4], *lnb[4], *Wm[4], *asr[4], *adt[4], *bias[4];
    int idx = 4;
    for (int i = 0; i < 4; i++) {
        lng[i]  = (const float*)d_in[idx++];
        lnb[i]  = (const float*)d_in[idx++];
        Wm[i]   = (const float*)d_in[idx++];
        asr[i]  = (const float*)d_in[idx++];
        adt[i]  = (const float*)d_in[idx++];
        bias[i] = (const float*)d_in[idx++];
    }

    char* base = (char*)d_ws;
    size_t off = 0;
    auto alloc = [&](size_t bytes) {
        void* p = base + off;
        off += (bytes + 255) & ~(size_t)255;
        return p;
    };
    float* alsrc = (float*)alloc((size_t)NN * 8 * 4);
    float* aldst = (float*)alloc((size_t)NN * 8 * 4);
    float* resid = (float*)alloc((size_t)NN * 3 * 4);
    int* rowptr  = (int*)alloc((size_t)(NN + 1) * 4);
    int* cursor  = (int*)alloc((size_t)NN * 4);
    int* deg     = (int*)alloc((size_t)NN * 4);
    int* colidx  = (int*)alloc((size_t)NE * 4);
    int* bsums   = (int*)alloc(256 * 4);
    bf16u* wb0   = (bf16u*)alloc((size_t)512 * 128 * 2);
    bf16u* wb1   = (bf16u*)alloc((size_t)512 * 512 * 2);
    bf16u* wb2   = (bf16u*)alloc((size_t)512 * 512 * 2);
    bf16u* hbuf  = (bf16u*)alloc((size_t)MPAD * 512 * 2);
    bf16u* lbuf  = (bf16u*)alloc((size_t)MPAD * 512 * 2);
    bf16u* abuf  = (bf16u*)alloc((size_t)MPAD * 512 * 2);
    if (off > ws_size) return;   // proven to fit in round 7

    float* out = (float*)d_out;

    // ---- CSR build ----
    k_zero_i32<<<(NN + 255) / 256, 256, 0, stream>>>(deg, NN);
    k_deg<<<(NE + 255) / 256, 256, 0, stream>>>(ei, deg);
    int nb = (NN + 1023) / 1024;
    k_scan1<<<nb, 256, 0, stream>>>(deg, rowptr, bsums, NN);
    k_scan2<<<1, 64, 0, stream>>>(bsums, nb);
    k_scan3<<<(NN + 1 + 255) / 256, 256, 0, stream>>>(deg, rowptr, cursor, bsums, NN, NE);
    k_scatter<<<(NE + 255) / 256, 256, 0, stream>>>(ei, cursor, colidx);

    int rowBlocks = (NN * 64 + 255) / 256;       // 12500
    k_cast<<<(512 * 128 + 255) / 256, 256, 0, stream>>>(Wm[0], wb0, 512 * 128);
    k_cast<<<(512 * 512 + 255) / 256, 256, 0, stream>>>(Wm[1], wb1, 512 * 512);
    k_cast<<<(512 * 512 + 255) / 256, 256, 0, stream>>>(Wm[2], wb2, 512 * 512);

    const bf16u* wb[3] = {wb0, wb1, wb2};
    const int ci_a[3] = {128, 512, 512};
    dim3 ggrid(MPAD / BM, 512 / BN);

    k_castres2<<<rowBlocks, 256, 0, stream>>>(x, resW, resb, lng[0], lnb[0],
                                              abuf, resid, NN);
    for (int i = 0; i < 3; i++) {
        int dores = (i >= 1) ? 1 : 0;
        k_gemm_db<<<ggrid, 256, 0, stream>>>(abuf, wb[i], lbuf,
                                             asr[i], adt[i], alsrc, aldst,
                                             NN, ci_a[i], 512);
        k_aggN2<<<rowBlocks, 256, 0, stream>>>(lbuf, alsrc, aldst, rowptr, colidx,
                                               bias[i], hbuf, lng[i + 1], lnb[i + 1],
                                               abuf, NN, dores);
    }
    k_lin3b<<<rowBlocks, 256, 0, stream>>>(abuf, Wm[3], asr[3], adt[3],
                                           lbuf, alsrc, aldst, NN);
    k_aggF<<<rowBlocks, 256, 0, stream>>>(lbuf, alsrc, aldst, rowptr, colidx,
                                          bias[3], out, resid, NN);
}

// Round 9
// 647.415 us; speedup vs baseline: 4.6326x; 1.0270x over previous
//
#include <hip/hip_runtime.h>
#include <math.h>

#define NN 50000
#define MPAD 50048          // 391 * 128
#define EE 400000
#define NE 450000           // EE + NN self loops
#define IN_F 128
#define NEG_SLOPE 0.2f
#define EPSV 1e-6f

typedef unsigned short bf16u;
typedef short bf8_t __attribute__((ext_vector_type(8)));
typedef float f32x4 __attribute__((ext_vector_type(4)));

__device__ __forceinline__ float bf2f(unsigned int u) {
    return __uint_as_float(u << 16);
}
__device__ __forceinline__ float bf2f_hi(unsigned int u) {
    return __uint_as_float(u & 0xFFFF0000u);
}
__device__ __forceinline__ bf16u f2bf(float f) {
    unsigned int u = __float_as_uint(f);
    unsigned int r = (u + 0x7FFFu + ((u >> 16) & 1u)) >> 16;
    return (bf16u)r;
}
__device__ __forceinline__ float gelu_f(float v) {
    return 0.5f * v * (1.0f + erff(v * 0.70710678118654752f));
}
__device__ __forceinline__ float lrelu(float v) {
    return fmaxf(v, NEG_SLOPE * v);
}

__device__ __forceinline__ void gload_lds16(const void* g, void* l) {
    __builtin_amdgcn_global_load_lds(
        (__attribute__((address_space(1))) void*)(g),
        (__attribute__((address_space(3))) void*)(l), 16, 0, 0);
}

// ============================ CSR build ============================
__global__ void k_zero_i32(int* p, int n) {
    int i = blockIdx.x * 256 + threadIdx.x;
    if (i < n) p[i] = 0;
}

__global__ void k_deg(const int* __restrict__ ei, int* __restrict__ deg) {
    int i = blockIdx.x * 256 + threadIdx.x;
    if (i >= NE) return;
    int d = (i < EE) ? ei[EE + i] : (i - EE);
    atomicAdd(&deg[d], 1);
}

__global__ __launch_bounds__(256) void k_scan1(const int* __restrict__ deg,
                                               int* __restrict__ incl,
                                               int* __restrict__ bsums, int n) {
    __shared__ int sm[1024];
    int base = blockIdx.x * 1024;
    for (int i = threadIdx.x; i < 1024; i += 256)
        sm[i] = (base + i < n) ? deg[base + i] : 0;
    __syncthreads();
    for (int off = 1; off < 1024; off <<= 1) {
        int v[4];
#pragma unroll
        for (int j = 0; j < 4; j++) {
            int i = threadIdx.x + 256 * j;
            v[j] = (i >= off) ? sm[i - off] : 0;
        }
        __syncthreads();
#pragma unroll
        for (int j = 0; j < 4; j++) {
            int i = threadIdx.x + 256 * j;
            sm[i] += v[j];
        }
        __syncthreads();
    }
    for (int i = threadIdx.x; i < 1024; i += 256)
        if (base + i < n) incl[base + i] = sm[i];
    if (threadIdx.x == 0) bsums[blockIdx.x] = sm[1023];
}

__global__ void k_scan2(int* bsums, int nb) {
    if (threadIdx.x == 0 && blockIdx.x == 0) {
        int run = 0;
        for (int i = 0; i < nb; i++) { int v = bsums[i]; bsums[i] = run; run += v; }
    }
}

__global__ void k_scan3(const int* __restrict__ deg, int* __restrict__ rowptr,
                        int* __restrict__ cursor, const int* __restrict__ bsums,
                        int n, int ne) {
    int i = blockIdx.x * 256 + threadIdx.x;
    if (i < n) {
        int excl = rowptr[i] + bsums[i >> 10] - deg[i];
        rowptr[i] = excl;
        cursor[i] = excl;
    }
    if (i == n) rowptr[n] = ne;
}

__global__ void k_scatter(const int* __restrict__ ei, int* __restrict__ cursor,
                          int* __restrict__ col) {
    int i = blockIdx.x * 256 + threadIdx.x;
    if (i >= NE) return;
    int s, d;
    if (i < EE) { s = ei[i]; d = ei[EE + i]; }
    else        { s = i - EE; d = i - EE; }
    int p = atomicAdd(&cursor[d], 1);
    col[p] = s;
}

// ================= one-shot f32 -> bf16 cast for all three weight mats =================
__global__ void k_cast3(const float* __restrict__ w0, bf16u* __restrict__ o0,
                        const float* __restrict__ w1, bf16u* __restrict__ o1,
                        const float* __restrict__ w2, bf16u* __restrict__ o2) {
    int i = blockIdx.x * 256 + threadIdx.x;
    if (i < 65536) { o0[i] = f2bf(w0[i]); return; }
    i -= 65536;
    if (i < 262144) { o1[i] = f2bf(w1[i]); return; }
    i -= 262144;
    if (i < 262144) o2[i] = f2bf(w2[i]);
}

// ======== cast x -> LN'd bf16 (g0,b0 applied) + residual head ========
__global__ __launch_bounds__(256) void k_castres2(const float* __restrict__ x,
                                                  const float* __restrict__ rw,
                                                  const float* __restrict__ rb,
                                                  const float* __restrict__ g0,
                                                  const float* __restrict__ b0,
                                                  bf16u* __restrict__ abuf,
                                                  float* __restrict__ res, int n) {
    int row = (blockIdx.x * 256 + threadIdx.x) >> 6;
    int lane = threadIdx.x & 63;
    if (row >= n) return;
    float2 v = *(const float2*)(x + (size_t)row * 128 + lane * 2);
    float2 w0 = *(const float2*)(rw + 0 * 128 + lane * 2);
    float2 w1 = *(const float2*)(rw + 1 * 128 + lane * 2);
    float2 w2 = *(const float2*)(rw + 2 * 128 + lane * 2);
    float s = v.x + v.y, s2 = v.x * v.x + v.y * v.y;
    float a0 = v.x * w0.x + v.y * w0.y;
    float a1 = v.x * w1.x + v.y * w1.y;
    float a2 = v.x * w2.x + v.y * w2.y;
#pragma unroll
    for (int off = 32; off; off >>= 1) {
        s  += __shfl_xor(s, off);
        s2 += __shfl_xor(s2, off);
        a0 += __shfl_xor(a0, off);
        a1 += __shfl_xor(a1, off);
        a2 += __shfl_xor(a2, off);
    }
    float mu = s * (1.0f / 128.0f);
    float var = s2 * (1.0f / 128.0f) - mu * mu;
    float rs = rsqrtf(var + EPSV);
    float2 gg = *(const float2*)(g0 + lane * 2);
    float2 bb = *(const float2*)(b0 + lane * 2);
    float l0 = fmaf((v.x - mu) * rs, gg.x, bb.x);
    float l1 = fmaf((v.y - mu) * rs, gg.y, bb.y);
    *(unsigned int*)(abuf + (size_t)row * 128 + lane * 2) =
        (unsigned int)f2bf(l0) | ((unsigned int)f2bf(l1) << 16);
    if (lane == 0) {
        res[row * 3 + 0] = a0 + rb[0];
        res[row * 3 + 1] = a1 + rb[1];
        res[row * 3 + 2] = a2 + rb[2];
    }
}

// ============ Double-buffered pure bf16 MFMA GEMM + fused al epilogue ============
// grid = (cols=4, rows=391): column-blocks sharing an A tile dispatch consecutively
// so A is fetched ~once from HBM (B panel 512KB is L2-resident anyway).
#define BM 128
#define BN 128
#define BK2 64
__global__ __launch_bounds__(256) void k_gemm_db(const bf16u* __restrict__ A,
                                                 const bf16u* __restrict__ Wb,
                                                 bf16u* __restrict__ C,
                                                 const float* __restrict__ asr,
                                                 const float* __restrict__ adt,
                                                 float* __restrict__ alsrc,
                                                 float* __restrict__ aldst,
                                                 int Mreal, int ci, int K) {
    __shared__ __align__(16) bf16u As[2][BM * BK2];
    __shared__ __align__(16) bf16u Bs[2][BN * BK2];
    const int tid = threadIdx.x;
    const int w = tid >> 6, lane = tid & 63;
    const int row0 = blockIdx.y * BM, col0 = blockIdx.x * BN;
    const int wr = (w >> 1) * 64, wc = (w & 1) * 64;

    // staging: wave w covers rows [w*32, w*32+32), 4 issues of 8 rows (128B/row)
    const int lrow = lane >> 3;                            // row within issue
    const int scolx = ((lane & 7) * 8) ^ (lrow << 3);      // pre-swizzled source col
    const bf16u* gA = A + (size_t)(row0 + w * 32 + lrow) * ci + scolx;
    const bf16u* gB = Wb + (size_t)(col0 + w * 32 + lrow) * ci + scolx;

    const int nk = ci / BK2;

    // prologue: stage tile 0 into buf 0
#pragma unroll
    for (int j = 0; j < 4; j++) {
        gload_lds16(gA + (size_t)(j * 8) * ci, &As[0][(w * 32 + j * 8) * BK2]);
        gload_lds16(gB + (size_t)(j * 8) * ci, &Bs[0][(w * 32 + j * 8) * BK2]);
    }
    __syncthreads();     // compiler drains vmcnt(0) before barrier

    f32x4 acc[4][4] = {};
    const int fr = lane & 15;
    const int fk = (lane >> 4) * 8;
    const int fxor = (fr & 7) << 3;

    for (int t = 0; t < nk; t++) {
        const int cur = t & 1;
        if (t + 1 < nk) {
            const int k0 = (t + 1) * BK2;
#pragma unroll
            for (int j = 0; j < 4; j++) {
                gload_lds16(gA + (size_t)(j * 8) * ci + k0, &As[cur ^ 1][(w * 32 + j * 8) * BK2]);
                gload_lds16(gB + (size_t)(j * 8) * ci + k0, &Bs[cur ^ 1][(w * 32 + j * 8) * BK2]);
            }
        }
#pragma unroll
        for (int ks = 0; ks < 2; ks++) {
            bf8_t af[4], bfv[4];
#pragma unroll
            for (int m = 0; m < 4; m++)
                af[m] = *(const bf8_t*)&As[cur][(wr + m * 16 + fr) * BK2 + ((ks * 32 + fk) ^ fxor)];
#pragma unroll
            for (int n = 0; n < 4; n++)
                bfv[n] = *(const bf8_t*)&Bs[cur][(wc + n * 16 + fr) * BK2 + ((ks * 32 + fk) ^ fxor)];
#pragma unroll
            for (int m = 0; m < 4; m++)
#pragma unroll
                for (int n = 0; n < 4; n++)
                    acc[m][n] = __builtin_amdgcn_mfma_f32_16x16x32_bf16(af[m], bfv[n], acc[m][n], 0, 0, 0);
        }
        if (t + 1 < nk) __syncthreads();   // drains next tile's loads; syncs readers
    }

    const int fc = lane & 15;
    const int fq = (lane >> 4) * 4;

    // ---- C store ----
#pragma unroll
    for (int m = 0; m < 4; m++) {
#pragma unroll
        for (int r = 0; r < 4; r++) {
            int row = row0 + wr + m * 16 + fq + r;
            if (row >= Mreal) continue;
#pragma unroll
            for (int n = 0; n < 4; n++) {
                int col = col0 + wc + n * 16 + fc;
                C[(size_t)row * K + col] = f2bf(acc[m][n][r]);
            }
        }
    }

    // ---- fused attention-logit dots (head = this wave's 64 cols) ----
    const int head = blockIdx.x * 2 + (wc >> 6);
    float av[4], dv[4];
#pragma unroll
    for (int n = 0; n < 4; n++) {
        av[n] = asr[head * 64 + n * 16 + fc];
        dv[n] = adt[head * 64 + n * 16 + fc];
    }
#pragma unroll
    for (int m = 0; m < 4; m++) {
#pragma unroll
        for (int r = 0; r < 4; r++) {
            float s1 = acc[m][0][r] * av[0] + acc[m][1][r] * av[1]
                     + acc[m][2][r] * av[2] + acc[m][3][r] * av[3];
            float s2 = acc[m][0][r] * dv[0] + acc[m][1][r] * dv[1]
                     + acc[m][2][r] * dv[2] + acc[m][3][r] * dv[3];
#pragma unroll
            for (int o = 1; o < 16; o <<= 1) {
                s1 += __shfl_xor(s1, o);
                s2 += __shfl_xor(s2, o);
            }
            int row = row0 + wr + m * 16 + fq + r;
            if (fc == 0 && row < Mreal) {
                alsrc[row * 8 + head] = s1;
                aldst[row * 8 + head] = s2;
            }
        }
    }
}

// ============ layer-3 matvec + logits (input already LN'd) ============
__global__ __launch_bounds__(256) void k_lin3b(const bf16u* __restrict__ an,
                                               const float* __restrict__ W,
                                               const float* __restrict__ a_s,
                                               const float* __restrict__ a_d,
                                               bf16u* __restrict__ hlin3,
                                               float* __restrict__ alsrc,
                                               float* __restrict__ aldst, int n) {
    int row = (blockIdx.x * 256 + threadIdx.x) >> 6;
    int lane = threadIdx.x & 63;
    if (row >= n) return;
    uint4 r = *(const uint4*)(an + (size_t)row * 512 + lane * 8);
    unsigned int u[4] = {r.x, r.y, r.z, r.w};
    float ln[8];
#pragma unroll
    for (int j = 0; j < 4; j++) {
        ln[2 * j]     = bf2f(u[j] & 0xFFFFu);
        ln[2 * j + 1] = bf2f_hi(u[j]);
    }
    float a0 = 0.f, a1 = 0.f, a2 = 0.f;
#pragma unroll
    for (int j = 0; j < 8; j++) {
        int k = lane * 8 + j;
        a0 += ln[j] * W[k];
        a1 += ln[j] * W[512 + k];
        a2 += ln[j] * W[1024 + k];
    }
#pragma unroll
    for (int off = 32; off; off >>= 1) {
        a0 += __shfl_down(a0, off);
        a1 += __shfl_down(a1, off);
        a2 += __shfl_down(a2, off);
    }
    if (lane == 0) {
        *(unsigned int*)(hlin3 + (size_t)row * 4) =
            (unsigned int)f2bf(a0) | ((unsigned int)f2bf(a1) << 16);
        *(unsigned int*)(hlin3 + (size_t)row * 4 + 2) = (unsigned int)f2bf(a2);
        alsrc[row] = a0 * a_s[0] + a1 * a_s[1] + a2 * a_s[2];
        aldst[row] = a0 * a_d[0] + a1 * a_d[1] + a2 * a_d[2];
    }
}

// ============ aggregate + epilogue (gelu/residual) + writes LN'd row (next layer's A) ============
// Softmax without max pass (logits O(1), f32 exp safe); sum via LDS group-sum
// (each lane sums 8 entries of its head) instead of 8x 6-round butterflies.
__global__ __launch_bounds__(256) void k_aggN2(const bf16u* __restrict__ hlin,
                                               const float* __restrict__ alsrc,
                                               const float* __restrict__ aldst,
                                               const int* __restrict__ rowptr,
                                               const int* __restrict__ col,
                                               const float* __restrict__ bias,
                                               bf16u* __restrict__ hio,
                                               const float* __restrict__ gn,
                                               const float* __restrict__ bn,
                                               bf16u* __restrict__ abuf,
                                               int n, int dores) {
    __shared__ uint2 aldsU[4][8][66];   // {exp bits (unnormalized), row byte offset}
    int wv = threadIdx.x >> 6;
    int node = (blockIdx.x * 256 + threadIdx.x) >> 6;
    int lane = threadIdx.x & 63;
    if (node >= n) return;
    int beg = rowptr[node], end = rowptr[node + 1];
    int deg = end - beg;

    const float4* dvv = (const float4*)(aldst + node * 8);
    float4 da = dvv[0], db = dvv[1];
    float ad[8] = {da.x, da.y, da.z, da.w, db.x, db.y, db.z, db.w};

    float s = 0.f, s2 = 0.f;
    float fin[8];

    if (deg <= 64) {
        // ---- prologue: lane j owns edge j; exp (no max shift) ----
        unsigned int offb = 0;
        float ex[8];
        if (lane < deg) {
            int srcreg = col[beg + lane];
            offb = (unsigned int)srcreg << 10;
            const float4* sv = (const float4*)(alsrc + srcreg * 8);
            float4 sa = sv[0], sb = sv[1];
            float sl[8] = {sa.x, sa.y, sa.z, sa.w, sb.x, sb.y, sb.z, sb.w};
#pragma unroll
            for (int h = 0; h < 8; h++) ex[h] = __expf(lrelu(sl[h] + ad[h]));
        } else {
#pragma unroll
            for (int h = 0; h < 8; h++) ex[h] = 0.f;
        }
#pragma unroll
        for (int h = 0; h < 8; h++) {
            uint2 t;
            t.x = __float_as_uint(ex[h]);
            t.y = offb;
            aldsU[wv][h][lane] = t;
        }
        asm volatile("s_waitcnt lgkmcnt(0)" ::: "memory");

        // ---- group-sum: lane sums 8 entries of its head, 3-round shfl in 8-lane group ----
        int hl = lane >> 3, s8 = lane & 7;
        const uint2* hrow = &aldsU[wv][hl][0];
        float ps = 0.f;
#pragma unroll
        for (int k2 = 0; k2 < 4; k2++) {
            uint4 q = *(const uint4*)(hrow + s8 * 8 + k2 * 2);
            ps += __uint_as_float(q.x) + __uint_as_float(q.z);
        }
#pragma unroll
        for (int o = 1; o < 8; o <<= 1) ps += __shfl_xor(ps, o);
        float invs = 1.0f / ps;

        // ---- aggregate: one uint4 (8 ch) per lane per edge, 2-edge unroll ----
        const uint2* myal = hrow;
        const char* base2 = (const char*)hlin + (lane << 4);
        float acc[8] = {};
        int e = 0;
        for (; e + 2 <= deg; e += 2) {
            uint2 t0 = myal[e];
            uint2 t1 = myal[e + 1];
            uint4 u0 = *(const uint4*)(base2 + t0.y);
            uint4 u1 = *(const uint4*)(base2 + t1.y);
            float a0 = __uint_as_float(t0.x) * invs;
            float a1 = __uint_as_float(t1.x) * invs;
            acc[0] = fmaf(a0, bf2f(u0.x & 0xFFFFu), acc[0]);
            acc[1] = fmaf(a0, bf2f_hi(u0.x),        acc[1]);
            acc[2] = fmaf(a0, bf2f(u0.y & 0xFFFFu), acc[2]);
            acc[3] = fmaf(a0, bf2f_hi(u0.y),        acc[3]);
            acc[4] = fmaf(a0, bf2f(u0.z & 0xFFFFu), acc[4]);
            acc[5] = fmaf(a0, bf2f_hi(u0.z),        acc[5]);
            acc[6] = fmaf(a0, bf2f(u0.w & 0xFFFFu), acc[6]);
            acc[7] = fmaf(a0, bf2f_hi(u0.w),        acc[7]);
            acc[0] = fmaf(a1, bf2f(u1.x & 0xFFFFu), acc[0]);
            acc[1] = fmaf(a1, bf2f_hi(u1.x),        acc[1]);
            acc[2] = fmaf(a1, bf2f(u1.y & 0xFFFFu), acc[2]);
            acc[3] = fmaf(a1, bf2f_hi(u1.y),        acc[3]);
            acc[4] = fmaf(a1, bf2f(u1.z & 0xFFFFu), acc[4]);
            acc[5] = fmaf(a1, bf2f_hi(u1.z),        acc[5]);
            acc[6] = fmaf(a1, bf2f(u1.w & 0xFFFFu), acc[6]);
            acc[7] = fmaf(a1, bf2f_hi(u1.w),        acc[7]);
        }
        if (e < deg) {
            uint2 t0 = myal[e];
            uint4 u0 = *(const uint4*)(base2 + t0.y);
            float a0 = __uint_as_float(t0.x) * invs;
            acc[0] = fmaf(a0, bf2f(u0.x & 0xFFFFu), acc[0]);
            acc[1] = fmaf(a0, bf2f_hi(u0.x),        acc[1]);
            acc[2] = fmaf(a0, bf2f(u0.y & 0xFFFFu), acc[2]);
            acc[3] = fmaf(a0, bf2f_hi(u0.y),        acc[3]);
            acc[4] = fmaf(a0, bf2f(u0.z & 0xFFFFu), acc[4]);
            acc[5] = fmaf(a0, bf2f_hi(u0.z),        acc[5]);
            acc[6] = fmaf(a0, bf2f(u0.w & 0xFFFFu), acc[6]);
            acc[7] = fmaf(a0, bf2f_hi(u0.w),        acc[7]);
        }

        size_t idx = (size_t)node * 512 + lane * 8;
        float4 b0 = *(const float4*)(bias + lane * 8);
        float4 b1 = *(const float4*)(bias + lane * 8 + 4);
        float bb[8] = {b0.x, b0.y, b0.z, b0.w, b1.x, b1.y, b1.z, b1.w};
#pragma unroll
        for (int j = 0; j < 8; j++) fin[j] = gelu_f(acc[j] + bb[j]);
        if (dores) {
            uint4 up = *(const uint4*)(hio + idx);
            fin[0] += bf2f(up.x & 0xFFFFu); fin[1] += bf2f_hi(up.x);
            fin[2] += bf2f(up.y & 0xFFFFu); fin[3] += bf2f_hi(up.y);
            fin[4] += bf2f(up.z & 0xFFFFu); fin[5] += bf2f_hi(up.z);
            fin[6] += bf2f(up.w & 0xFFFFu); fin[7] += bf2f_hi(up.w);
        }
        uint4 pk;
        pk.x = (unsigned int)f2bf(fin[0]) | ((unsigned int)f2bf(fin[1]) << 16);
        pk.y = (unsigned int)f2bf(fin[2]) | ((unsigned int)f2bf(fin[3]) << 16);
        pk.z = (unsigned int)f2bf(fin[4]) | ((unsigned int)f2bf(fin[5]) << 16);
        pk.w = (unsigned int)f2bf(fin[6]) | ((unsigned int)f2bf(fin[7]) << 16);
        *(uint4*)(hio + idx) = pk;
#pragma unroll
        for (int j = 0; j < 8; j++) { s += fin[j]; s2 += fin[j] * fin[j]; }

        // full-wave LN stats, then write the pre-normalized row for the next GEMM
#pragma unroll
        for (int off = 32; off; off >>= 1) {
            s  += __shfl_xor(s, off);
            s2 += __shfl_xor(s2, off);
        }
        float mu = s * (1.0f / 512.0f);
        float rs = rsqrtf(s2 * (1.0f / 512.0f) - mu * mu + EPSV);
        float4 g0 = *(const float4*)(gn + lane * 8);
        float4 g1 = *(const float4*)(gn + lane * 8 + 4);
        float4 n0 = *(const float4*)(bn + lane * 8);
        float4 n1 = *(const float4*)(bn + lane * 8 + 4);
        float gg[8] = {g0.x, g0.y, g0.z, g0.w, g1.x, g1.y, g1.z, g1.w};
        float nb[8] = {n0.x, n0.y, n0.z, n0.w, n1.x, n1.y, n1.z, n1.w};
        float lnv[8];
#pragma unroll
        for (int j = 0; j < 8; j++) lnv[j] = fmaf((fin[j] - mu) * rs, gg[j], nb[j]);
        uint4 pl;
        pl.x = (unsigned int)f2bf(lnv[0]) | ((unsigned int)f2bf(lnv[1]) << 16);
        pl.y = (unsigned int)f2bf(lnv[2]) | ((unsigned int)f2bf(lnv[3]) << 16);
        pl.z = (unsigned int)f2bf(lnv[4]) | ((unsigned int)f2bf(lnv[5]) << 16);
        pl.w = (unsigned int)f2bf(lnv[6]) | ((unsigned int)f2bf(lnv[7]) << 16);
        *(uint4*)(abuf + idx) = pl;
    } else {
        // fallback (deg > 64): per-head 3-pass with max; lane owns channels h*64+lane
        float fins[8];
        for (int h = 0; h < 8; h++) {
            float adh = ad[h];
            float m = -INFINITY;
            for (int e = beg + lane; e < end; e += 64)
                m = fmaxf(m, lrelu(alsrc[col[e] * 8 + h] + adh));
#pragma unroll
            for (int off = 32; off; off >>= 1) m = fmaxf(m, __shfl_xor(m, off));
            float sum = 0.f;
            for (int e = beg + lane; e < end; e += 64)
                sum += __expf(lrelu(alsrc[col[e] * 8 + h] + adh) - m);
#pragma unroll
            for (int off = 32; off; off >>= 1) sum += __shfl_xor(sum, off);
            float inv = 1.0f / sum;
            float acc = 0.f;
            for (int e = beg; e < end; e++) {
                int src = col[e];
                float alpha = __expf(lrelu(alsrc[src * 8 + h] + adh) - m) * inv;
                acc = fmaf(alpha, bf2f(hlin[((size_t)src << 9) + h * 64 + lane]), acc);
            }
            float fv = gelu_f(acc + bias[h * 64 + lane]);
            size_t idx = (size_t)node * 512 + h * 64 + lane;
            if (dores) fv += bf2f(hio[idx]);
            hio[idx] = f2bf(fv);
            fins[h] = fv;
            s += fv; s2 += fv * fv;
        }
#pragma unroll
        for (int off = 32; off; off >>= 1) {
            s  += __shfl_xor(s, off);
            s2 += __shfl_xor(s2, off);
        }
        float mu = s * (1.0f / 512.0f);
        float rs = rsqrtf(s2 * (1.0f / 512.0f) - mu * mu + EPSV);
        for (int h = 0; h < 8; h++) {
            int c = h * 64 + lane;
            abuf[(size_t)node * 512 + c] = f2bf(fmaf((fins[h] - mu) * rs, gn[c], bn[c]));
        }
    }
}

// ============================ final softmax+aggregate (heads=1, co=3) ============================
__global__ __launch_bounds__(256) void k_aggF(const bf16u* __restrict__ hlin3,
                                              const float* __restrict__ alsrc,
                                              const float* __restrict__ aldst,
                                              const int* __restrict__ rowptr,
                                              const int* __restrict__ col,
                                              const float* __restrict__ bias,
                                              float* __restrict__ outf,
                                              const float* __restrict__ resid, int n) {
    int node = (blockIdx.x * 256 + threadIdx.x) >> 6;
    int lane = threadIdx.x & 63;
    if (node >= n) return;
    int beg = rowptr[node], end = rowptr[node + 1];
    int deg = end - beg;
    float adh = aldst[node];

    if (deg <= 64) {
        int src = 0;
        float raw = -INFINITY;
        if (lane < deg) {
            src = col[beg + lane];
            raw = lrelu(alsrc[src] + adh);
        }
        float m = raw;
#pragma unroll
        for (int off = 32; off; off >>= 1) m = fmaxf(m, __shfl_xor(m, off));
        float ex = (lane < deg) ? __expf(raw - m) : 0.f;
        float sum = ex;
#pragma unroll
        for (int off = 32; off; off >>= 1) sum += __shfl_xor(sum, off);
        float alpha = ex / sum;

        float c0 = 0.f, c1 = 0.f, c2 = 0.f;
        if (lane < deg) {
            uint2 u = *(const uint2*)(hlin3 + (size_t)src * 4);
            c0 = alpha * bf2f(u.x & 0xFFFFu);
            c1 = alpha * bf2f_hi(u.x);
            c2 = alpha * bf2f(u.y & 0xFFFFu);
        }
#pragma unroll
        for (int off = 32; off; off >>= 1) {
            c0 += __shfl_xor(c0, off);
            c1 += __shfl_xor(c1, off);
            c2 += __shfl_xor(c2, off);
        }
        if (lane == 0) {
            outf[node * 3 + 0] = c0 + bias[0] + resid[node * 3 + 0];
            outf[node * 3 + 1] = c1 + bias[1] + resid[node * 3 + 1];
            outf[node * 3 + 2] = c2 + bias[2] + resid[node * 3 + 2];
        }
    } else {
        float m = -INFINITY;
        for (int e = beg + lane; e < end; e += 64)
            m = fmaxf(m, lrelu(alsrc[col[e]] + adh));
#pragma unroll
        for (int off = 32; off; off >>= 1) m = fmaxf(m, __shfl_xor(m, off));
        float sum = 0.f;
        for (int e = beg + lane; e < end; e += 64)
            sum += __expf(lrelu(alsrc[col[e]] + adh) - m);
#pragma unroll
        for (int off = 32; off; off >>= 1) sum += __shfl_xor(sum, off);
        float inv = 1.0f / sum;
        float acc = 0.f;
        for (int e = beg; e < end; e++) {
            int src = col[e];
            float alpha = __expf(lrelu(alsrc[src] + adh) - m) * inv;
            if (lane < 3) acc += alpha * bf2f(hlin3[(size_t)src * 4 + lane]);
        }
        if (lane < 3)
            outf[node * 3 + lane] = acc + bias[lane] + resid[node * 3 + lane];
    }
}

// ============================ launch ============================
extern "C" void kernel_launch(void* const* d_in, const int* in_sizes, int n_in,
                              void* d_out, int out_size, void* d_ws, size_t ws_size,
                              hipStream_t stream) {
    const float* x    = (const float*)d_in[0];
    const int*   ei   = (const int*)d_in[1];
    const float* resW = (const float*)d_in[2];
    const float* resb = (const float*)d_in[3];
    const float *lng[4], *lnb[4], *Wm[4], *asr[4], *adt[4], *bias[4];
    int idx = 4;
    for (int i = 0; i < 4; i++) {
        lng[i]  = (const float*)d_in[idx++];
        lnb[i]  = (const float*)d_in[idx++];
        Wm[i]   = (const float*)d_in[idx++];
        asr[i]  = (const float*)d_in[idx++];
        adt[i]  = (const float*)d_in[idx++];
        bias[i] = (const float*)d_in[idx++];
    }

    char* base = (char*)d_ws;
    size_t off = 0;
    auto alloc = [&](size_t bytes) {
        void* p = base + off;
        off += (bytes + 255) & ~(size_t)255;
        return p;
    };
    float* alsrc = (float*)alloc((size_t)NN * 8 * 4);
    float* aldst = (float*)alloc((size_t)NN * 8 * 4);
    float* resid = (float*)alloc((size_t)NN * 3 * 4);
    int* rowptr  = (int*)alloc((size_t)(NN + 1) * 4);
    int* cursor  = (int*)alloc((size_t)NN * 4);
    int* deg     = (int*)alloc((size_t)NN * 4);
    int* colidx  = (int*)alloc((size_t)NE * 4);
    int* bsums   = (int*)alloc(256 * 4);
    bf16u* wb0   = (bf16u*)alloc((size_t)512 * 128 * 2);
    bf16u* wb1   = (bf16u*)alloc((size_t)512 * 512 * 2);
    bf16u* wb2   = (bf16u*)alloc((size_t)512 * 512 * 2);
    bf16u* hbuf  = (bf16u*)alloc((size_t)MPAD * 512 * 2);
    bf16u* lbuf  = (bf16u*)alloc((size_t)MPAD * 512 * 2);
    bf16u* abuf  = (bf16u*)alloc((size_t)MPAD * 512 * 2);
    if (off > ws_size) return;   // proven to fit in round 7

    float* out = (float*)d_out;

    // ---- CSR build ----
    k_zero_i32<<<(NN + 255) / 256, 256, 0, stream>>>(deg, NN);
    k_deg<<<(NE + 255) / 256, 256, 0, stream>>>(ei, deg);
    int nb = (NN + 1023) / 1024;
    k_scan1<<<nb, 256, 0, stream>>>(deg, rowptr, bsums, NN);
    k_scan2<<<1, 64, 0, stream>>>(bsums, nb);
    k_scan3<<<(NN + 1 + 255) / 256, 256, 0, stream>>>(deg, rowptr, cursor, bsums, NN, NE);
    k_scatter<<<(NE + 255) / 256, 256, 0, stream>>>(ei, cursor, colidx);

    int rowBlocks = (NN * 64 + 255) / 256;       // 12500
    k_cast3<<<(589824 + 255) / 256, 256, 0, stream>>>(Wm[0], wb0, Wm[1], wb1, Wm[2], wb2);

    const bf16u* wb[3] = {wb0, wb1, wb2};
    const int ci_a[3] = {128, 512, 512};
    dim3 ggrid(512 / BN, MPAD / BM);    // x = column blocks (4), y = row blocks (391)

    k_castres2<<<rowBlocks, 256, 0, stream>>>(x, resW, resb, lng[0], lnb[0],
                                              abuf, resid, NN);
    for (int i = 0; i < 3; i++) {
        int dores = (i >= 1) ? 1 : 0;
        k_gemm_db<<<ggrid, 256, 0, stream>>>(abuf, wb[i], lbuf,
                                             asr[i], adt[i], alsrc, aldst,
                                             NN, ci_a[i], 512);
        k_aggN2<<<rowBlocks, 256, 0, stream>>>(lbuf, alsrc, aldst, rowptr, colidx,
                                               bias[i], hbuf, lng[i + 1], lnb[i + 1],
                                               abuf, NN, dores);
    }
    k_lin3b<<<rowBlocks, 256, 0, stream>>>(abuf, Wm[3], asr[3], adt[3],
                                           lbuf, alsrc, aldst, NN);
    k_aggF<<<rowBlocks, 256, 0, stream>>>(lbuf, alsrc, aldst, rowptr, colidx,
                                          bias[3], out, resid, NN);
}

// Round 10
// 640.167 us; speedup vs baseline: 4.6850x; 1.0113x over previous
//
#include <hip/hip_runtime.h>
#include <math.h>

#define NN 50000
#define MPAD 50048          // 391 * 128
#define EE 400000
#define NE 450000           // EE + NN self loops
#define IN_F 128
#define NEG_SLOPE 0.2f
#define EPSV 1e-6f

typedef unsigned short bf16u;
typedef short bf8_t __attribute__((ext_vector_type(8)));
typedef float f32x4 __attribute__((ext_vector_type(4)));

__device__ __forceinline__ float bf2f(unsigned int u) {
    return __uint_as_float(u << 16);
}
__device__ __forceinline__ float bf2f_hi(unsigned int u) {
    return __uint_as_float(u & 0xFFFF0000u);
}
__device__ __forceinline__ bf16u f2bf(float f) {
    unsigned int u = __float_as_uint(f);
    unsigned int r = (u + 0x7FFFu + ((u >> 16) & 1u)) >> 16;
    return (bf16u)r;
}
__device__ __forceinline__ float gelu_f(float v) {
    return 0.5f * v * (1.0f + erff(v * 0.70710678118654752f));
}
__device__ __forceinline__ float lrelu(float v) {
    return fmaxf(v, NEG_SLOPE * v);
}
__device__ __forceinline__ void fma8(float* acc, float a, uint4 u) {
    acc[0] = fmaf(a, bf2f(u.x & 0xFFFFu), acc[0]);
    acc[1] = fmaf(a, bf2f_hi(u.x),        acc[1]);
    acc[2] = fmaf(a, bf2f(u.y & 0xFFFFu), acc[2]);
    acc[3] = fmaf(a, bf2f_hi(u.y),        acc[3]);
    acc[4] = fmaf(a, bf2f(u.z & 0xFFFFu), acc[4]);
    acc[5] = fmaf(a, bf2f_hi(u.z),        acc[5]);
    acc[6] = fmaf(a, bf2f(u.w & 0xFFFFu), acc[6]);
    acc[7] = fmaf(a, bf2f_hi(u.w),        acc[7]);
}

__device__ __forceinline__ void gload_lds16(const void* g, void* l) {
    __builtin_amdgcn_global_load_lds(
        (__attribute__((address_space(1))) void*)(g),
        (__attribute__((address_space(3))) void*)(l), 16, 0, 0);
}

// ============================ CSR build ============================
__global__ void k_zero_i32(int* p, int n) {
    int i = blockIdx.x * 256 + threadIdx.x;
    if (i < n) p[i] = 0;
}

__global__ void k_deg(const int* __restrict__ ei, int* __restrict__ deg) {
    int i = blockIdx.x * 256 + threadIdx.x;
    if (i >= NE) return;
    int d = (i < EE) ? ei[EE + i] : (i - EE);
    atomicAdd(&deg[d], 1);
}

__global__ __launch_bounds__(256) void k_scan1(const int* __restrict__ deg,
                                               int* __restrict__ incl,
                                               int* __restrict__ bsums, int n) {
    __shared__ int sm[1024];
    int base = blockIdx.x * 1024;
    for (int i = threadIdx.x; i < 1024; i += 256)
        sm[i] = (base + i < n) ? deg[base + i] : 0;
    __syncthreads();
    for (int off = 1; off < 1024; off <<= 1) {
        int v[4];
#pragma unroll
        for (int j = 0; j < 4; j++) {
            int i = threadIdx.x + 256 * j;
            v[j] = (i >= off) ? sm[i - off] : 0;
        }
        __syncthreads();
#pragma unroll
        for (int j = 0; j < 4; j++) {
            int i = threadIdx.x + 256 * j;
            sm[i] += v[j];
        }
        __syncthreads();
    }
    for (int i = threadIdx.x; i < 1024; i += 256)
        if (base + i < n) incl[base + i] = sm[i];
    if (threadIdx.x == 0) bsums[blockIdx.x] = sm[1023];
}

__global__ void k_scan2(int* bsums, int nb) {
    if (threadIdx.x == 0 && blockIdx.x == 0) {
        int run = 0;
        for (int i = 0; i < nb; i++) { int v = bsums[i]; bsums[i] = run; run += v; }
    }
}

__global__ void k_scan3(const int* __restrict__ deg, int* __restrict__ rowptr,
                        int* __restrict__ cursor, const int* __restrict__ bsums,
                        int n, int ne) {
    int i = blockIdx.x * 256 + threadIdx.x;
    if (i < n) {
        int excl = rowptr[i] + bsums[i >> 10] - deg[i];
        rowptr[i] = excl;
        cursor[i] = excl;
    }
    if (i == n) rowptr[n] = ne;
}

__global__ void k_scatter(const int* __restrict__ ei, int* __restrict__ cursor,
                          int* __restrict__ col) {
    int i = blockIdx.x * 256 + threadIdx.x;
    if (i >= NE) return;
    int s, d;
    if (i < EE) { s = ei[i]; d = ei[EE + i]; }
    else        { s = i - EE; d = i - EE; }
    int p = atomicAdd(&cursor[d], 1);
    col[p] = s;
}

// ================= one-shot f32 -> bf16 cast for all three weight mats =================
__global__ void k_cast3(const float* __restrict__ w0, bf16u* __restrict__ o0,
                        const float* __restrict__ w1, bf16u* __restrict__ o1,
                        const float* __restrict__ w2, bf16u* __restrict__ o2) {
    int i = blockIdx.x * 256 + threadIdx.x;
    if (i < 65536) { o0[i] = f2bf(w0[i]); return; }
    i -= 65536;
    if (i < 262144) { o1[i] = f2bf(w1[i]); return; }
    i -= 262144;
    if (i < 262144) o2[i] = f2bf(w2[i]);
}

// ======== cast x -> LN'd bf16 (g0,b0 applied) + residual head ========
__global__ __launch_bounds__(256) void k_castres2(const float* __restrict__ x,
                                                  const float* __restrict__ rw,
                                                  const float* __restrict__ rb,
                                                  const float* __restrict__ g0,
                                                  const float* __restrict__ b0,
                                                  bf16u* __restrict__ abuf,
                                                  float* __restrict__ res, int n) {
    int row = (blockIdx.x * 256 + threadIdx.x) >> 6;
    int lane = threadIdx.x & 63;
    if (row >= n) return;
    float2 v = *(const float2*)(x + (size_t)row * 128 + lane * 2);
    float2 w0 = *(const float2*)(rw + 0 * 128 + lane * 2);
    float2 w1 = *(const float2*)(rw + 1 * 128 + lane * 2);
    float2 w2 = *(const float2*)(rw + 2 * 128 + lane * 2);
    float s = v.x + v.y, s2 = v.x * v.x + v.y * v.y;
    float a0 = v.x * w0.x + v.y * w0.y;
    float a1 = v.x * w1.x + v.y * w1.y;
    float a2 = v.x * w2.x + v.y * w2.y;
#pragma unroll
    for (int off = 32; off; off >>= 1) {
        s  += __shfl_xor(s, off);
        s2 += __shfl_xor(s2, off);
        a0 += __shfl_xor(a0, off);
        a1 += __shfl_xor(a1, off);
        a2 += __shfl_xor(a2, off);
    }
    float mu = s * (1.0f / 128.0f);
    float var = s2 * (1.0f / 128.0f) - mu * mu;
    float rs = rsqrtf(var + EPSV);
    float2 gg = *(const float2*)(g0 + lane * 2);
    float2 bb = *(const float2*)(b0 + lane * 2);
    float l0 = fmaf((v.x - mu) * rs, gg.x, bb.x);
    float l1 = fmaf((v.y - mu) * rs, gg.y, bb.y);
    *(unsigned int*)(abuf + (size_t)row * 128 + lane * 2) =
        (unsigned int)f2bf(l0) | ((unsigned int)f2bf(l1) << 16);
    if (lane == 0) {
        res[row * 3 + 0] = a0 + rb[0];
        res[row * 3 + 1] = a1 + rb[1];
        res[row * 3 + 2] = a2 + rb[2];
    }
}

// ============ Single-buffered pure bf16 MFMA GEMM + fused al epilogue ============
// m97 2-barrier structure; 32KB LDS -> ~5 blocks/CU so other blocks' MFMA covers
// the vmcnt(0) drain at each barrier. grid = (cols=4, rows=391) for A L3 reuse.
#define BM 128
#define BN 128
#define BK2 64
__global__ __launch_bounds__(256) void k_gemm_sb(const bf16u* __restrict__ A,
                                                 const bf16u* __restrict__ Wb,
                                                 bf16u* __restrict__ C,
                                                 const float* __restrict__ asr,
                                                 const float* __restrict__ adt,
                                                 float* __restrict__ alsrc,
                                                 float* __restrict__ aldst,
                                                 int Mreal, int ci, int K) {
    __shared__ __align__(16) bf16u As[BM * BK2];
    __shared__ __align__(16) bf16u Bs[BN * BK2];
    const int tid = threadIdx.x;
    const int w = tid >> 6, lane = tid & 63;
    const int row0 = blockIdx.y * BM, col0 = blockIdx.x * BN;
    const int wr = (w >> 1) * 64, wc = (w & 1) * 64;

    // staging: wave w covers rows [w*32, w*32+32), 4 issues of 8 rows (128B/row)
    const int lrow = lane >> 3;                            // row within issue
    const int scolx = ((lane & 7) * 8) ^ (lrow << 3);      // pre-swizzled source col
    const bf16u* gA = A + (size_t)(row0 + w * 32 + lrow) * ci + scolx;
    const bf16u* gB = Wb + (size_t)(col0 + w * 32 + lrow) * ci + scolx;

    const int nk = ci / BK2;

    f32x4 acc[4][4] = {};
    const int fr = lane & 15;
    const int fk = (lane >> 4) * 8;
    const int fxor = (fr & 7) << 3;

    for (int t = 0; t < nk; t++) {
        if (t) __syncthreads();            // all waves done reading previous tile
        const int k0 = t * BK2;
#pragma unroll
        for (int j = 0; j < 4; j++) {
            gload_lds16(gA + (size_t)(j * 8) * ci + k0, &As[(w * 32 + j * 8) * BK2]);
            gload_lds16(gB + (size_t)(j * 8) * ci + k0, &Bs[(w * 32 + j * 8) * BK2]);
        }
        __syncthreads();                   // drains vmcnt(0): tile ready
#pragma unroll
        for (int ks = 0; ks < 2; ks++) {
            bf8_t af[4], bfv[4];
#pragma unroll
            for (int m = 0; m < 4; m++)
                af[m] = *(const bf8_t*)&As[(wr + m * 16 + fr) * BK2 + ((ks * 32 + fk) ^ fxor)];
#pragma unroll
            for (int n = 0; n < 4; n++)
                bfv[n] = *(const bf8_t*)&Bs[(wc + n * 16 + fr) * BK2 + ((ks * 32 + fk) ^ fxor)];
#pragma unroll
            for (int m = 0; m < 4; m++)
#pragma unroll
                for (int n = 0; n < 4; n++)
                    acc[m][n] = __builtin_amdgcn_mfma_f32_16x16x32_bf16(af[m], bfv[n], acc[m][n], 0, 0, 0);
        }
    }

    const int fc = lane & 15;
    const int fq = (lane >> 4) * 4;

    // ---- C store ----
#pragma unroll
    for (int m = 0; m < 4; m++) {
#pragma unroll
        for (int r = 0; r < 4; r++) {
            int row = row0 + wr + m * 16 + fq + r;
            if (row >= Mreal) continue;
#pragma unroll
            for (int n = 0; n < 4; n++) {
                int col = col0 + wc + n * 16 + fc;
                C[(size_t)row * K + col] = f2bf(acc[m][n][r]);
            }
        }
    }

    // ---- fused attention-logit dots (head = this wave's 64 cols) ----
    const int head = blockIdx.x * 2 + (wc >> 6);
    float av[4], dv[4];
#pragma unroll
    for (int n = 0; n < 4; n++) {
        av[n] = asr[head * 64 + n * 16 + fc];
        dv[n] = adt[head * 64 + n * 16 + fc];
    }
#pragma unroll
    for (int m = 0; m < 4; m++) {
#pragma unroll
        for (int r = 0; r < 4; r++) {
            float s1 = acc[m][0][r] * av[0] + acc[m][1][r] * av[1]
                     + acc[m][2][r] * av[2] + acc[m][3][r] * av[3];
            float s2 = acc[m][0][r] * dv[0] + acc[m][1][r] * dv[1]
                     + acc[m][2][r] * dv[2] + acc[m][3][r] * dv[3];
#pragma unroll
            for (int o = 1; o < 16; o <<= 1) {
                s1 += __shfl_xor(s1, o);
                s2 += __shfl_xor(s2, o);
            }
            int row = row0 + wr + m * 16 + fq + r;
            if (fc == 0 && row < Mreal) {
                alsrc[row * 8 + head] = s1;
                aldst[row * 8 + head] = s2;
            }
        }
    }
}

// ============ layer-3 matvec + logits (input already LN'd) ============
__global__ __launch_bounds__(256) void k_lin3b(const bf16u* __restrict__ an,
                                               const float* __restrict__ W,
                                               const float* __restrict__ a_s,
                                               const float* __restrict__ a_d,
                                               bf16u* __restrict__ hlin3,
                                               float* __restrict__ alsrc,
                                               float* __restrict__ aldst, int n) {
    int row = (blockIdx.x * 256 + threadIdx.x) >> 6;
    int lane = threadIdx.x & 63;
    if (row >= n) return;
    uint4 r = *(const uint4*)(an + (size_t)row * 512 + lane * 8);
    unsigned int u[4] = {r.x, r.y, r.z, r.w};
    float ln[8];
#pragma unroll
    for (int j = 0; j < 4; j++) {
        ln[2 * j]     = bf2f(u[j] & 0xFFFFu);
        ln[2 * j + 1] = bf2f_hi(u[j]);
    }
    float a0 = 0.f, a1 = 0.f, a2 = 0.f;
#pragma unroll
    for (int j = 0; j < 8; j++) {
        int k = lane * 8 + j;
        a0 += ln[j] * W[k];
        a1 += ln[j] * W[512 + k];
        a2 += ln[j] * W[1024 + k];
    }
#pragma unroll
    for (int off = 32; off; off >>= 1) {
        a0 += __shfl_down(a0, off);
        a1 += __shfl_down(a1, off);
        a2 += __shfl_down(a2, off);
    }
    if (lane == 0) {
        *(unsigned int*)(hlin3 + (size_t)row * 4) =
            (unsigned int)f2bf(a0) | ((unsigned int)f2bf(a1) << 16);
        *(unsigned int*)(hlin3 + (size_t)row * 4 + 2) = (unsigned int)f2bf(a2);
        alsrc[row] = a0 * a_s[0] + a1 * a_s[1] + a2 * a_s[2];
        aldst[row] = a0 * a_d[0] + a1 * a_d[1] + a2 * a_d[2];
    }
}

// ============ aggregate + epilogue (gelu/residual) + writes LN'd row (next layer's A) ============
// wrh=0 skips the (dead) hio store on the last GAT layer.
__global__ __launch_bounds__(256) void k_aggN2(const bf16u* __restrict__ hlin,
                                               const float* __restrict__ alsrc,
                                               const float* __restrict__ aldst,
                                               const int* __restrict__ rowptr,
                                               const int* __restrict__ col,
                                               const float* __restrict__ bias,
                                               bf16u* __restrict__ hio,
                                               const float* __restrict__ gn,
                                               const float* __restrict__ bn,
                                               bf16u* __restrict__ abuf,
                                               int n, int dores, int wrh) {
    __shared__ uint2 aldsU[4][8][66];   // {exp bits (unnormalized), row byte offset}
    int wv = threadIdx.x >> 6;
    int node = (blockIdx.x * 256 + threadIdx.x) >> 6;
    int lane = threadIdx.x & 63;
    if (node >= n) return;
    int beg = rowptr[node], end = rowptr[node + 1];
    int deg = end - beg;

    const float4* dvv = (const float4*)(aldst + node * 8);
    float4 da = dvv[0], db = dvv[1];
    float ad[8] = {da.x, da.y, da.z, da.w, db.x, db.y, db.z, db.w};

    float s = 0.f, s2 = 0.f;
    float fin[8];

    if (deg <= 64) {
        // ---- prologue: lane j owns edge j; exp (no max shift; logits O(1)) ----
        unsigned int offb = 0;
        float ex[8];
        if (lane < deg) {
            int srcreg = col[beg + lane];
            offb = (unsigned int)srcreg << 10;
            const float4* sv = (const float4*)(alsrc + srcreg * 8);
            float4 sa = sv[0], sb = sv[1];
            float sl[8] = {sa.x, sa.y, sa.z, sa.w, sb.x, sb.y, sb.z, sb.w};
#pragma unroll
            for (int h = 0; h < 8; h++) ex[h] = __expf(lrelu(sl[h] + ad[h]));
        } else {
#pragma unroll
            for (int h = 0; h < 8; h++) ex[h] = 0.f;
        }
#pragma unroll
        for (int h = 0; h < 8; h++) {
            uint2 t;
            t.x = __float_as_uint(ex[h]);
            t.y = offb;
            aldsU[wv][h][lane] = t;
        }
        asm volatile("s_waitcnt lgkmcnt(0)" ::: "memory");

        // ---- group-sum: lane sums 8 entries of its head, 3-round shfl in 8-lane group ----
        int hl = lane >> 3, s8 = lane & 7;
        const uint2* hrow = &aldsU[wv][hl][0];
        float ps = 0.f;
#pragma unroll
        for (int k2 = 0; k2 < 4; k2++) {
            uint4 q = *(const uint4*)(hrow + s8 * 8 + k2 * 2);
            ps += __uint_as_float(q.x) + __uint_as_float(q.z);
        }
#pragma unroll
        for (int o = 1; o < 8; o <<= 1) ps += __shfl_xor(ps, o);
        float invs = 1.0f / ps;

        // ---- aggregate: one uint4 (8 ch) per lane per edge, 4-edge unroll, 2 acc sets ----
        const uint2* myal = hrow;
        const char* base2 = (const char*)hlin + (lane << 4);
        float acc0[8] = {}, acc1[8] = {};
        int e = 0;
        for (; e + 4 <= deg; e += 4) {
            uint2 t0 = myal[e];
            uint2 t1 = myal[e + 1];
            uint2 t2 = myal[e + 2];
            uint2 t3 = myal[e + 3];
            uint4 u0 = *(const uint4*)(base2 + t0.y);
            uint4 u1 = *(const uint4*)(base2 + t1.y);
            uint4 u2 = *(const uint4*)(base2 + t2.y);
            uint4 u3 = *(const uint4*)(base2 + t3.y);
            fma8(acc0, __uint_as_float(t0.x) * invs, u0);
            fma8(acc1, __uint_as_float(t1.x) * invs, u1);
            fma8(acc0, __uint_as_float(t2.x) * invs, u2);
            fma8(acc1, __uint_as_float(t3.x) * invs, u3);
        }
        if (e + 2 <= deg) {
            uint2 t0 = myal[e];
            uint2 t1 = myal[e + 1];
            uint4 u0 = *(const uint4*)(base2 + t0.y);
            uint4 u1 = *(const uint4*)(base2 + t1.y);
            fma8(acc0, __uint_as_float(t0.x) * invs, u0);
            fma8(acc1, __uint_as_float(t1.x) * invs, u1);
            e += 2;
        }
        if (e < deg) {
            uint2 t0 = myal[e];
            uint4 u0 = *(const uint4*)(base2 + t0.y);
            fma8(acc0, __uint_as_float(t0.x) * invs, u0);
        }

        size_t idx = (size_t)node * 512 + lane * 8;
        float4 b0 = *(const float4*)(bias + lane * 8);
        float4 b1 = *(const float4*)(bias + lane * 8 + 4);
        float bb[8] = {b0.x, b0.y, b0.z, b0.w, b1.x, b1.y, b1.z, b1.w};
#pragma unroll
        for (int j = 0; j < 8; j++) fin[j] = gelu_f(acc0[j] + acc1[j] + bb[j]);
        if (dores) {
            uint4 up = *(const uint4*)(hio + idx);
            fin[0] += bf2f(up.x & 0xFFFFu); fin[1] += bf2f_hi(up.x);
            fin[2] += bf2f(up.y & 0xFFFFu); fin[3] += bf2f_hi(up.y);
            fin[4] += bf2f(up.z & 0xFFFFu); fin[5] += bf2f_hi(up.z);
            fin[6] += bf2f(up.w & 0xFFFFu); fin[7] += bf2f_hi(up.w);
        }
        if (wrh) {
            uint4 pk;
            pk.x = (unsigned int)f2bf(fin[0]) | ((unsigned int)f2bf(fin[1]) << 16);
            pk.y = (unsigned int)f2bf(fin[2]) | ((unsigned int)f2bf(fin[3]) << 16);
            pk.z = (unsigned int)f2bf(fin[4]) | ((unsigned int)f2bf(fin[5]) << 16);
            pk.w = (unsigned int)f2bf(fin[6]) | ((unsigned int)f2bf(fin[7]) << 16);
            *(uint4*)(hio + idx) = pk;
        }
#pragma unroll
        for (int j = 0; j < 8; j++) { s += fin[j]; s2 += fin[j] * fin[j]; }

        // full-wave LN stats, then write the pre-normalized row for the next GEMM
#pragma unroll
        for (int off = 32; off; off >>= 1) {
            s  += __shfl_xor(s, off);
            s2 += __shfl_xor(s2, off);
        }
        float mu = s * (1.0f / 512.0f);
        float rs = rsqrtf(s2 * (1.0f / 512.0f) - mu * mu + EPSV);
        float4 g0 = *(const float4*)(gn + lane * 8);
        float4 g1 = *(const float4*)(gn + lane * 8 + 4);
        float4 n0 = *(const float4*)(bn + lane * 8);
        float4 n1 = *(const float4*)(bn + lane * 8 + 4);
        float gg[8] = {g0.x, g0.y, g0.z, g0.w, g1.x, g1.y, g1.z, g1.w};
        float nb[8] = {n0.x, n0.y, n0.z, n0.w, n1.x, n1.y, n1.z, n1.w};
        float lnv[8];
#pragma unroll
        for (int j = 0; j < 8; j++) lnv[j] = fmaf((fin[j] - mu) * rs, gg[j], nb[j]);
        uint4 pl;
        pl.x = (unsigned int)f2bf(lnv[0]) | ((unsigned int)f2bf(lnv[1]) << 16);
        pl.y = (unsigned int)f2bf(lnv[2]) | ((unsigned int)f2bf(lnv[3]) << 16);
        pl.z = (unsigned int)f2bf(lnv[4]) | ((unsigned int)f2bf(lnv[5]) << 16);
        pl.w = (unsigned int)f2bf(lnv[6]) | ((unsigned int)f2bf(lnv[7]) << 16);
        *(uint4*)(abuf + idx) = pl;
    } else {
        // fallback (deg > 64): per-head 3-pass with max; lane owns channels h*64+lane
        float fins[8];
        for (int h = 0; h < 8; h++) {
            float adh = ad[h];
            float m = -INFINITY;
            for (int e = beg + lane; e < end; e += 64)
                m = fmaxf(m, lrelu(alsrc[col[e] * 8 + h] + adh));
#pragma unroll
            for (int off = 32; off; off >>= 1) m = fmaxf(m, __shfl_xor(m, off));
            float sum = 0.f;
            for (int e = beg + lane; e < end; e += 64)
                sum += __expf(lrelu(alsrc[col[e] * 8 + h] + adh) - m);
#pragma unroll
            for (int off = 32; off; off >>= 1) sum += __shfl_xor(sum, off);
            float inv = 1.0f / sum;
            float acc = 0.f;
            for (int e = beg; e < end; e++) {
                int src = col[e];
                float alpha = __expf(lrelu(alsrc[src * 8 + h] + adh) - m) * inv;
                acc = fmaf(alpha, bf2f(hlin[((size_t)src << 9) + h * 64 + lane]), acc);
            }
            float fv = gelu_f(acc + bias[h * 64 + lane]);
            size_t idx = (size_t)node * 512 + h * 64 + lane;
            if (dores) fv += bf2f(hio[idx]);
            if (wrh) hio[idx] = f2bf(fv);
            fins[h] = fv;
            s += fv; s2 += fv * fv;
        }
#pragma unroll
        for (int off = 32; off; off >>= 1) {
            s  += __shfl_xor(s, off);
            s2 += __shfl_xor(s2, off);
        }
        float mu = s * (1.0f / 512.0f);
        float rs = rsqrtf(s2 * (1.0f / 512.0f) - mu * mu + EPSV);
        for (int h = 0; h < 8; h++) {
            int c = h * 64 + lane;
            abuf[(size_t)node * 512 + c] = f2bf(fmaf((fins[h] - mu) * rs, gn[c], bn[c]));
        }
    }
}

// ============================ final softmax+aggregate (heads=1, co=3) ============================
__global__ __launch_bounds__(256) void k_aggF(const bf16u* __restrict__ hlin3,
                                              const float* __restrict__ alsrc,
                                              const float* __restrict__ aldst,
                                              const int* __restrict__ rowptr,
                                              const int* __restrict__ col,
                                              const float* __restrict__ bias,
                                              float* __restrict__ outf,
                                              const float* __restrict__ resid, int n) {
    int node = (blockIdx.x * 256 + threadIdx.x) >> 6;
    int lane = threadIdx.x & 63;
    if (node >= n) return;
    int beg = rowptr[node], end = rowptr[node + 1];
    int deg = end - beg;
    float adh = aldst[node];

    if (deg <= 64) {
        int src = 0;
        float ex = 0.f;
        if (lane < deg) {
            src = col[beg + lane];
            ex = __expf(lrelu(alsrc[src] + adh));
        }
        float sum = ex;
#pragma unroll
        for (int off = 32; off; off >>= 1) sum += __shfl_xor(sum, off);
        float alpha = ex / sum;

        float c0 = 0.f, c1 = 0.f, c2 = 0.f;
        if (lane < deg) {
            uint2 u = *(const uint2*)(hlin3 + (size_t)src * 4);
            c0 = alpha * bf2f(u.x & 0xFFFFu);
            c1 = alpha * bf2f_hi(u.x);
            c2 = alpha * bf2f(u.y & 0xFFFFu);
        }
#pragma unroll
        for (int off = 32; off; off >>= 1) {
            c0 += __shfl_xor(c0, off);
            c1 += __shfl_xor(c1, off);
            c2 += __shfl_xor(c2, off);
        }
        if (lane == 0) {
            outf[node * 3 + 0] = c0 + bias[0] + resid[node * 3 + 0];
            outf[node * 3 + 1] = c1 + bias[1] + resid[node * 3 + 1];
            outf[node * 3 + 2] = c2 + bias[2] + resid[node * 3 + 2];
        }
    } else {
        float m = -INFINITY;
        for (int e = beg + lane; e < end; e += 64)
            m = fmaxf(m, lrelu(alsrc[col[e]] + adh));
#pragma unroll
        for (int off = 32; off; off >>= 1) m = fmaxf(m, __shfl_xor(m, off));
        float sum = 0.f;
        for (int e = beg + lane; e < end; e += 64)
            sum += __expf(lrelu(alsrc[col[e]] + adh) - m);
#pragma unroll
        for (int off = 32; off; off >>= 1) sum += __shfl_xor(sum, off);
        float inv = 1.0f / sum;
        float acc = 0.f;
        for (int e = beg; e < end; e++) {
            int src = col[e];
            float alpha = __expf(lrelu(alsrc[src] + adh) - m) * inv;
            if (lane < 3) acc += alpha * bf2f(hlin3[(size_t)src * 4 + lane]);
        }
        if (lane < 3)
            outf[node * 3 + lane] = acc + bias[lane] + resid[node * 3 + lane];
    }
}

// ============================ launch ============================
extern "C" void kernel_launch(void* const* d_in, const int* in_sizes, int n_in,
                              void* d_out, int out_size, void* d_ws, size_t ws_size,
                              hipStream_t stream) {
    const float* x    = (const float*)d_in[0];
    const int*   ei   = (const int*)d_in[1];
    const float* resW = (const float*)d_in[2];
    const float* resb = (const float*)d_in[3];
    const float *lng[4], *lnb[4], *Wm[4], *asr[4], *adt[4], *bias[4];
    int idx = 4;
    for (int i = 0; i < 4; i++) {
        lng[i]  = (const float*)d_in[idx++];
        lnb[i]  = (const float*)d_in[idx++];
        Wm[i]   = (const float*)d_in[idx++];
        asr[i]  = (const float*)d_in[idx++];
        adt[i]  = (const float*)d_in[idx++];
        bias[i] = (const float*)d_in[idx++];
    }

    char* base = (char*)d_ws;
    size_t off = 0;
    auto alloc = [&](size_t bytes) {
        void* p = base + off;
        off += (bytes + 255) & ~(size_t)255;
        return p;
    };
    float* alsrc = (float*)alloc((size_t)NN * 8 * 4);
    float* aldst = (float*)alloc((size_t)NN * 8 * 4);
    float* resid = (float*)alloc((size_t)NN * 3 * 4);
    int* rowptr  = (int*)alloc((size_t)(NN + 1) * 4);
    int* cursor  = (int*)alloc((size_t)NN * 4);
    int* deg     = (int*)alloc((size_t)NN * 4);
    int* colidx  = (int*)alloc((size_t)NE * 4);
    int* bsums   = (int*)alloc(256 * 4);
    bf16u* wb0   = (bf16u*)alloc((size_t)512 * 128 * 2);
    bf16u* wb1   = (bf16u*)alloc((size_t)512 * 512 * 2);
    bf16u* wb2   = (bf16u*)alloc((size_t)512 * 512 * 2);
    bf16u* hbuf  = (bf16u*)alloc((size_t)MPAD * 512 * 2);
    bf16u* lbuf  = (bf16u*)alloc((size_t)MPAD * 512 * 2);
    bf16u* abuf  = (bf16u*)alloc((size_t)MPAD * 512 * 2);
    if (off > ws_size) return;   // proven to fit in round 7

    float* out = (float*)d_out;

    // ---- CSR build ----
    k_zero_i32<<<(NN + 255) / 256, 256, 0, stream>>>(deg, NN);
    k_deg<<<(NE + 255) / 256, 256, 0, stream>>>(ei, deg);
    int nb = (NN + 1023) / 1024;
    k_scan1<<<nb, 256, 0, stream>>>(deg, rowptr, bsums, NN);
    k_scan2<<<1, 64, 0, stream>>>(bsums, nb);
    k_scan3<<<(NN + 1 + 255) / 256, 256, 0, stream>>>(deg, rowptr, cursor, bsums, NN, NE);
    k_scatter<<<(NE + 255) / 256, 256, 0, stream>>>(ei, cursor, colidx);

    int rowBlocks = (NN * 64 + 255) / 256;       // 12500
    k_cast3<<<(589824 + 255) / 256, 256, 0, stream>>>(Wm[0], wb0, Wm[1], wb1, Wm[2], wb2);

    const bf16u* wb[3] = {wb0, wb1, wb2};
    const int ci_a[3] = {128, 512, 512};
    dim3 ggrid(512 / BN, MPAD / BM);    // x = column blocks (4), y = row blocks (391)

    k_castres2<<<rowBlocks, 256, 0, stream>>>(x, resW, resb, lng[0], lnb[0],
                                              abuf, resid, NN);
    for (int i = 0; i < 3; i++) {
        int dores = (i >= 1) ? 1 : 0;
        int wrh = (i < 2) ? 1 : 0;       // layer 2's hio store is dead
        k_gemm_sb<<<ggrid, 256, 0, stream>>>(abuf, wb[i], lbuf,
                                             asr[i], adt[i], alsrc, aldst,
                                             NN, ci_a[i], 512);
        k_aggN2<<<rowBlocks, 256, 0, stream>>>(lbuf, alsrc, aldst, rowptr, colidx,
                                               bias[i], hbuf, lng[i + 1], lnb[i + 1],
                                               abuf, NN, dores, wrh);
    }
    k_lin3b<<<rowBlocks, 256, 0, stream>>>(abuf, Wm[3], asr[3], adt[3],
                                           lbuf, alsrc, aldst, NN);
    k_aggF<<<rowBlocks, 256, 0, stream>>>(lbuf, alsrc, aldst, rowptr, colidx,
                                          bias[3], out, resid, NN);
}

// Round 11
// 636.067 us; speedup vs baseline: 4.7152x; 1.0064x over previous
//
#include <hip/hip_runtime.h>
#include <math.h>

#define NN 50000
#define MPAD 50048          // 391 * 128
#define EE 400000
#define NE 450000           // EE + NN self loops
#define IN_F 128
#define NEG_SLOPE 0.2f
#define EPSV 1e-6f

typedef unsigned short bf16u;
typedef short bf8_t __attribute__((ext_vector_type(8)));
typedef float f32x4 __attribute__((ext_vector_type(4)));

__device__ __forceinline__ float bf2f(unsigned int u) {
    return __uint_as_float(u << 16);
}
__device__ __forceinline__ float bf2f_hi(unsigned int u) {
    return __uint_as_float(u & 0xFFFF0000u);
}
__device__ __forceinline__ bf16u f2bf(float f) {
    unsigned int u = __float_as_uint(f);
    unsigned int r = (u + 0x7FFFu + ((u >> 16) & 1u)) >> 16;
    return (bf16u)r;
}
__device__ __forceinline__ float gelu_f(float v) {
    return 0.5f * v * (1.0f + erff(v * 0.70710678118654752f));
}
__device__ __forceinline__ float lrelu(float v) {
    return fmaxf(v, NEG_SLOPE * v);
}
__device__ __forceinline__ void fma8(float* acc, float a, uint4 u) {
    acc[0] = fmaf(a, bf2f(u.x & 0xFFFFu), acc[0]);
    acc[1] = fmaf(a, bf2f_hi(u.x),        acc[1]);
    acc[2] = fmaf(a, bf2f(u.y & 0xFFFFu), acc[2]);
    acc[3] = fmaf(a, bf2f_hi(u.y),        acc[3]);
    acc[4] = fmaf(a, bf2f(u.z & 0xFFFFu), acc[4]);
    acc[5] = fmaf(a, bf2f_hi(u.z),        acc[5]);
    acc[6] = fmaf(a, bf2f(u.w & 0xFFFFu), acc[6]);
    acc[7] = fmaf(a, bf2f_hi(u.w),        acc[7]);
}

__device__ __forceinline__ void gload_lds16(const void* g, void* l) {
    __builtin_amdgcn_global_load_lds(
        (__attribute__((address_space(1))) void*)(g),
        (__attribute__((address_space(3))) void*)(l), 16, 0, 0);
}

// ============================ CSR build ============================
__global__ void k_zero_i32(int* p, int n) {
    int i = blockIdx.x * 256 + threadIdx.x;
    if (i < n) p[i] = 0;
}

__global__ void k_deg(const int* __restrict__ ei, int* __restrict__ deg) {
    int i = blockIdx.x * 256 + threadIdx.x;
    if (i >= NE) return;
    int d = (i < EE) ? ei[EE + i] : (i - EE);
    atomicAdd(&deg[d], 1);
}

__global__ __launch_bounds__(256) void k_scan1(const int* __restrict__ deg,
                                               int* __restrict__ incl,
                                               int* __restrict__ bsums, int n) {
    __shared__ int sm[1024];
    int base = blockIdx.x * 1024;
    for (int i = threadIdx.x; i < 1024; i += 256)
        sm[i] = (base + i < n) ? deg[base + i] : 0;
    __syncthreads();
    for (int off = 1; off < 1024; off <<= 1) {
        int v[4];
#pragma unroll
        for (int j = 0; j < 4; j++) {
            int i = threadIdx.x + 256 * j;
            v[j] = (i >= off) ? sm[i - off] : 0;
        }
        __syncthreads();
#pragma unroll
        for (int j = 0; j < 4; j++) {
            int i = threadIdx.x + 256 * j;
            sm[i] += v[j];
        }
        __syncthreads();
    }
    for (int i = threadIdx.x; i < 1024; i += 256)
        if (base + i < n) incl[base + i] = sm[i];
    if (threadIdx.x == 0) bsums[blockIdx.x] = sm[1023];
}

__global__ void k_scan2(int* bsums, int nb) {
    if (threadIdx.x == 0 && blockIdx.x == 0) {
        int run = 0;
        for (int i = 0; i < nb; i++) { int v = bsums[i]; bsums[i] = run; run += v; }
    }
}

__global__ void k_scan3(const int* __restrict__ deg, int* __restrict__ rowptr,
                        int* __restrict__ cursor, const int* __restrict__ bsums,
                        int n, int ne) {
    int i = blockIdx.x * 256 + threadIdx.x;
    if (i < n) {
        int excl = rowptr[i] + bsums[i >> 10] - deg[i];
        rowptr[i] = excl;
        cursor[i] = excl;
    }
    if (i == n) rowptr[n] = ne;
}

__global__ void k_scatter(const int* __restrict__ ei, int* __restrict__ cursor,
                          int* __restrict__ col) {
    int i = blockIdx.x * 256 + threadIdx.x;
    if (i >= NE) return;
    int s, d;
    if (i < EE) { s = ei[i]; d = ei[EE + i]; }
    else        { s = i - EE; d = i - EE; }
    int p = atomicAdd(&cursor[d], 1);
    col[p] = s;
}

// ================= prep: Wg = bf16(W*g); c1 = sum(W*g); bW = sum(W*b) =================
// wave per (layer, col); layers 0..2, 512 cols each.
__global__ __launch_bounds__(256) void k_prepw(
    const float* __restrict__ W0, const float* __restrict__ g0, const float* __restrict__ b0,
    bf16u* __restrict__ Wg0,
    const float* __restrict__ W1, const float* __restrict__ g1, const float* __restrict__ b1,
    bf16u* __restrict__ Wg1,
    const float* __restrict__ W2, const float* __restrict__ g2, const float* __restrict__ b2,
    bf16u* __restrict__ Wg2,
    float* __restrict__ c1, float* __restrict__ bW) {
    int wid = (blockIdx.x * 256 + threadIdx.x) >> 6;
    int lane = threadIdx.x & 63;
    if (wid >= 1536) return;
    int l = wid >> 9, col = wid & 511;
    const float *W, *g, *b; bf16u* Wg; int ci;
    if (l == 0)      { W = W0; g = g0; b = b0; Wg = Wg0; ci = 128; }
    else if (l == 1) { W = W1; g = g1; b = b1; Wg = Wg1; ci = 512; }
    else             { W = W2; g = g2; b = b2; Wg = Wg2; ci = 512; }
    float sc = 0.f, sb = 0.f;
    for (int k = lane; k < ci; k += 64) {
        float w = W[(size_t)col * ci + k];
        float wg = w * g[k];
        Wg[(size_t)col * ci + k] = f2bf(wg);
        sc += wg;
        sb += w * b[k];
    }
#pragma unroll
    for (int off = 32; off; off >>= 1) {
        sc += __shfl_xor(sc, off);
        sb += __shfl_xor(sb, off);
    }
    if (lane == 0) {
        c1[l * 512 + col] = sc;
        bW[l * 512 + col] = sb;
    }
}

// ===== prep: per-head affine constants for the al dots: C1A = sum(c1*a), BWA = sum(bW*a) =====
__global__ __launch_bounds__(256) void k_prepa(
    const float* __restrict__ c1, const float* __restrict__ bW,
    const float* __restrict__ asr0, const float* __restrict__ adt0,
    const float* __restrict__ asr1, const float* __restrict__ adt1,
    const float* __restrict__ asr2, const float* __restrict__ adt2,
    float* __restrict__ C1As, float* __restrict__ BWAs,
    float* __restrict__ C1Ad, float* __restrict__ BWAd) {
    int wid = (blockIdx.x * 256 + threadIdx.x) >> 6;
    int lane = threadIdx.x & 63;
    if (wid >= 24) return;
    int l = wid >> 3, h = wid & 7;
    const float* as = (l == 0) ? asr0 : (l == 1) ? asr1 : asr2;
    const float* ad = (l == 0) ? adt0 : (l == 1) ? adt1 : adt2;
    float c1v = c1[l * 512 + h * 64 + lane];
    float bWv = bW[l * 512 + h * 64 + lane];
    float av = as[h * 64 + lane], dv = ad[h * 64 + lane];
    float s1 = c1v * av, s2 = bWv * av, s3 = c1v * dv, s4 = bWv * dv;
#pragma unroll
    for (int off = 32; off; off >>= 1) {
        s1 += __shfl_xor(s1, off);
        s2 += __shfl_xor(s2, off);
        s3 += __shfl_xor(s3, off);
        s4 += __shfl_xor(s4, off);
    }
    if (lane == 0) {
        C1As[l * 8 + h] = s1;
        BWAs[l * 8 + h] = s2;
        C1Ad[l * 8 + h] = s3;
        BWAd[l * 8 + h] = s4;
    }
}

// ======== cast x -> raw bf16 + LN stats (ci=128) + residual head ========
__global__ __launch_bounds__(256) void k_castres(const float* __restrict__ x,
                                                 const float* __restrict__ rw,
                                                 const float* __restrict__ rb,
                                                 bf16u* __restrict__ xb,
                                                 float* __restrict__ stats,
                                                 float* __restrict__ res, int n) {
    int row = (blockIdx.x * 256 + threadIdx.x) >> 6;
    int lane = threadIdx.x & 63;
    if (row >= n) return;
    float2 v = *(const float2*)(x + (size_t)row * 128 + lane * 2);
    unsigned int pk = (unsigned int)f2bf(v.x) | ((unsigned int)f2bf(v.y) << 16);
    *(unsigned int*)(xb + (size_t)row * 128 + lane * 2) = pk;
    float2 w0 = *(const float2*)(rw + 0 * 128 + lane * 2);
    float2 w1 = *(const float2*)(rw + 1 * 128 + lane * 2);
    float2 w2 = *(const float2*)(rw + 2 * 128 + lane * 2);
    float s = v.x + v.y, s2 = v.x * v.x + v.y * v.y;
    float a0 = v.x * w0.x + v.y * w0.y;
    float a1 = v.x * w1.x + v.y * w1.y;
    float a2 = v.x * w2.x + v.y * w2.y;
#pragma unroll
    for (int off = 32; off; off >>= 1) {
        s  += __shfl_xor(s, off);
        s2 += __shfl_xor(s2, off);
        a0 += __shfl_xor(a0, off);
        a1 += __shfl_xor(a1, off);
        a2 += __shfl_xor(a2, off);
    }
    if (lane == 0) {
        float mu = s * (1.0f / 128.0f);
        float var = s2 * (1.0f / 128.0f) - mu * mu;
        stats[row * 2 + 0] = mu;
        stats[row * 2 + 1] = rsqrtf(var + EPSV);
        res[row * 3 + 0] = a0 + rb[0];
        res[row * 3 + 1] = a1 + rb[1];
        res[row * 3 + 2] = a2 + rb[2];
    }
}

// ============ Single-buffered bf16 MFMA GEMM, LN folded into the epilogue ============
// C = rs*(h @ Wg^T) + (-rs*mu)*c1 + bW   (per-row rs,mu from stats)
// grid = (cols=4, rows=391) for A L3 reuse.
#define BM 128
#define BN 128
#define BK2 64
__global__ __launch_bounds__(256) void k_gemm_sb(const bf16u* __restrict__ A,
                                                 const float* __restrict__ stats,
                                                 const bf16u* __restrict__ Wg,
                                                 const float* __restrict__ c1,
                                                 const float* __restrict__ bW,
                                                 bf16u* __restrict__ C,
                                                 const float* __restrict__ asr,
                                                 const float* __restrict__ adt,
                                                 const float* __restrict__ C1As,
                                                 const float* __restrict__ BWAs,
                                                 const float* __restrict__ C1Ad,
                                                 const float* __restrict__ BWAd,
                                                 float* __restrict__ alsrc,
                                                 float* __restrict__ aldst,
                                                 int Mreal, int ci, int K) {
    __shared__ __align__(16) bf16u As[BM * BK2];
    __shared__ __align__(16) bf16u Bs[BN * BK2];
    const int tid = threadIdx.x;
    const int w = tid >> 6, lane = tid & 63;
    const int row0 = blockIdx.y * BM, col0 = blockIdx.x * BN;
    const int wr = (w >> 1) * 64, wc = (w & 1) * 64;

    // staging: wave w covers rows [w*32, w*32+32), 4 issues of 8 rows (128B/row)
    const int lrow = lane >> 3;                            // row within issue
    const int scolx = ((lane & 7) * 8) ^ (lrow << 3);      // pre-swizzled source col
    const bf16u* gA = A + (size_t)(row0 + w * 32 + lrow) * ci + scolx;
    const bf16u* gB = Wg + (size_t)(col0 + w * 32 + lrow) * ci + scolx;

    const int nk = ci / BK2;

    f32x4 acc[4][4] = {};
    const int fr = lane & 15;
    const int fk = (lane >> 4) * 8;
    const int fxor = (fr & 7) << 3;

    for (int t = 0; t < nk; t++) {
        if (t) __syncthreads();            // all waves done reading previous tile
        const int k0 = t * BK2;
#pragma unroll
        for (int j = 0; j < 4; j++) {
            gload_lds16(gA + (size_t)(j * 8) * ci + k0, &As[(w * 32 + j * 8) * BK2]);
            gload_lds16(gB + (size_t)(j * 8) * ci + k0, &Bs[(w * 32 + j * 8) * BK2]);
        }
        __syncthreads();                   // drains vmcnt(0): tile ready
#pragma unroll
        for (int ks = 0; ks < 2; ks++) {
            bf8_t af[4], bfv[4];
#pragma unroll
            for (int m = 0; m < 4; m++)
                af[m] = *(const bf8_t*)&As[(wr + m * 16 + fr) * BK2 + ((ks * 32 + fk) ^ fxor)];
#pragma unroll
            for (int n = 0; n < 4; n++)
                bfv[n] = *(const bf8_t*)&Bs[(wc + n * 16 + fr) * BK2 + ((ks * 32 + fk) ^ fxor)];
#pragma unroll
            for (int m = 0; m < 4; m++)
#pragma unroll
                for (int n = 0; n < 4; n++)
                    acc[m][n] = __builtin_amdgcn_mfma_f32_16x16x32_bf16(af[m], bfv[n], acc[m][n], 0, 0, 0);
        }
    }

    const int fc = lane & 15;
    const int fq = (lane >> 4) * 4;
    const int head = blockIdx.x * 2 + (wc >> 6);

    float c1v[4], bWv[4], av[4], dv[4];
#pragma unroll
    for (int n = 0; n < 4; n++) {
        int col = col0 + wc + n * 16 + fc;
        c1v[n] = c1[col];
        bWv[n] = bW[col];
        av[n] = asr[head * 64 + n * 16 + fc];
        dv[n] = adt[head * 64 + n * 16 + fc];
    }
    const float c1as = C1As[head], bwas = BWAs[head];
    const float c1ad = C1Ad[head], bwad = BWAd[head];

#pragma unroll
    for (int m = 0; m < 4; m++) {
#pragma unroll
        for (int r = 0; r < 4; r++) {
            int row = row0 + wr + m * 16 + fq + r;
            float2 st = *(const float2*)(stats + (size_t)row * 2);
            float rs = st.y;
            float nrm = -rs * st.x;
            if (row < Mreal) {
#pragma unroll
                for (int n = 0; n < 4; n++) {
                    int col = col0 + wc + n * 16 + fc;
                    float val = fmaf(rs, acc[m][n][r], fmaf(nrm, c1v[n], bWv[n]));
                    C[(size_t)row * K + col] = f2bf(val);
                }
            }
            float s1 = acc[m][0][r] * av[0] + acc[m][1][r] * av[1]
                     + acc[m][2][r] * av[2] + acc[m][3][r] * av[3];
            float s2 = acc[m][0][r] * dv[0] + acc[m][1][r] * dv[1]
                     + acc[m][2][r] * dv[2] + acc[m][3][r] * dv[3];
#pragma unroll
            for (int o = 1; o < 16; o <<= 1) {
                s1 += __shfl_xor(s1, o);
                s2 += __shfl_xor(s2, o);
            }
            if (fc == 0 && row < Mreal) {
                alsrc[row * 8 + head] = fmaf(rs, s1, fmaf(nrm, c1as, bwas));
                aldst[row * 8 + head] = fmaf(rs, s2, fmaf(nrm, c1ad, bwad));
            }
        }
    }
}

// ============ layer-3 matvec + logits (LN applied inline from stats) ============
__global__ __launch_bounds__(256) void k_lin3(const bf16u* __restrict__ h,
                                              const float* __restrict__ stats,
                                              const float* __restrict__ g,
                                              const float* __restrict__ bb,
                                              const float* __restrict__ W,
                                              const float* __restrict__ a_s,
                                              const float* __restrict__ a_d,
                                              bf16u* __restrict__ hlin3,
                                              float* __restrict__ alsrc,
                                              float* __restrict__ aldst, int n) {
    int row = (blockIdx.x * 256 + threadIdx.x) >> 6;
    int lane = threadIdx.x & 63;
    if (row >= n) return;
    float mu = stats[row * 2 + 0], rs = stats[row * 2 + 1];
    uint4 r = *(const uint4*)(h + (size_t)row * 512 + lane * 8);
    float4 g0 = *(const float4*)(g + lane * 8);
    float4 g1 = *(const float4*)(g + lane * 8 + 4);
    float4 b0 = *(const float4*)(bb + lane * 8);
    float4 b1 = *(const float4*)(bb + lane * 8 + 4);
    float gg[8] = {g0.x, g0.y, g0.z, g0.w, g1.x, g1.y, g1.z, g1.w};
    float bv[8] = {b0.x, b0.y, b0.z, b0.w, b1.x, b1.y, b1.z, b1.w};
    unsigned int u[4] = {r.x, r.y, r.z, r.w};
    float ln[8];
#pragma unroll
    for (int j = 0; j < 4; j++) {
        ln[2 * j]     = fmaf((bf2f(u[j] & 0xFFFFu) - mu) * rs, gg[2 * j], bv[2 * j]);
        ln[2 * j + 1] = fmaf((bf2f_hi(u[j])         - mu) * rs, gg[2 * j + 1], bv[2 * j + 1]);
    }
    float a0 = 0.f, a1 = 0.f, a2 = 0.f;
#pragma unroll
    for (int j = 0; j < 8; j++) {
        int k = lane * 8 + j;
        a0 += ln[j] * W[k];
        a1 += ln[j] * W[512 + k];
        a2 += ln[j] * W[1024 + k];
    }
#pragma unroll
    for (int off = 32; off; off >>= 1) {
        a0 += __shfl_down(a0, off);
        a1 += __shfl_down(a1, off);
        a2 += __shfl_down(a2, off);
    }
    if (lane == 0) {
        *(unsigned int*)(hlin3 + (size_t)row * 4) =
            (unsigned int)f2bf(a0) | ((unsigned int)f2bf(a1) << 16);
        *(unsigned int*)(hlin3 + (size_t)row * 4 + 2) = (unsigned int)f2bf(a2);
        alsrc[row] = a0 * a_s[0] + a1 * a_s[1] + a2 * a_s[2];
        aldst[row] = a0 * a_d[0] + a1 * a_d[1] + a2 * a_d[2];
    }
}

// ==== aggregate + epilogue (gelu/residual) -> writes raw h (hio) + next-layer LN stats ====
__global__ __launch_bounds__(256) void k_aggN2(const bf16u* __restrict__ hlin,
                                               const float* __restrict__ alsrc,
                                               const float* __restrict__ aldst,
                                               const int* __restrict__ rowptr,
                                               const int* __restrict__ col,
                                               const float* __restrict__ bias,
                                               bf16u* __restrict__ hio,
                                               float* __restrict__ stats,
                                               int n, int dores) {
    __shared__ uint2 aldsU[4][8][66];   // {exp bits (unnormalized), row byte offset}
    int wv = threadIdx.x >> 6;
    int node = (blockIdx.x * 256 + threadIdx.x) >> 6;
    int lane = threadIdx.x & 63;
    if (node >= n) return;
    int beg = rowptr[node], end = rowptr[node + 1];
    int deg = end - beg;

    const float4* dvv = (const float4*)(aldst + node * 8);
    float4 da = dvv[0], db = dvv[1];
    float ad[8] = {da.x, da.y, da.z, da.w, db.x, db.y, db.z, db.w};

    float s = 0.f, s2 = 0.f;
    float fin[8];

    if (deg <= 64) {
        // ---- prologue: lane j owns edge j; exp (no max shift; logits O(1)) ----
        unsigned int offb = 0;
        float ex[8];
        if (lane < deg) {
            int srcreg = col[beg + lane];
            offb = (unsigned int)srcreg << 10;
            const float4* sv = (const float4*)(alsrc + srcreg * 8);
            float4 sa = sv[0], sb = sv[1];
            float sl[8] = {sa.x, sa.y, sa.z, sa.w, sb.x, sb.y, sb.z, sb.w};
#pragma unroll
            for (int h = 0; h < 8; h++) ex[h] = __expf(lrelu(sl[h] + ad[h]));
        } else {
#pragma unroll
            for (int h = 0; h < 8; h++) ex[h] = 0.f;
        }
#pragma unroll
        for (int h = 0; h < 8; h++) {
            uint2 t;
            t.x = __float_as_uint(ex[h]);
            t.y = offb;
            aldsU[wv][h][lane] = t;
        }
        asm volatile("s_waitcnt lgkmcnt(0)" ::: "memory");

        // ---- group-sum: lane sums 8 entries of its head, 3-round shfl in 8-lane group ----
        int hl = lane >> 3, s8 = lane & 7;
        const uint2* hrow = &aldsU[wv][hl][0];
        float ps = 0.f;
#pragma unroll
        for (int k2 = 0; k2 < 4; k2++) {
            uint4 q = *(const uint4*)(hrow + s8 * 8 + k2 * 2);
            ps += __uint_as_float(q.x) + __uint_as_float(q.z);
        }
#pragma unroll
        for (int o = 1; o < 8; o <<= 1) ps += __shfl_xor(ps, o);
        float invs = 1.0f / ps;

        // ---- aggregate: one uint4 (8 ch) per lane per edge, 2-edge unroll ----
        const uint2* myal = hrow;
        const char* base2 = (const char*)hlin + (lane << 4);
        float acc[8] = {};
        int e = 0;
        for (; e + 2 <= deg; e += 2) {
            uint2 t0 = myal[e];
            uint2 t1 = myal[e + 1];
            uint4 u0 = *(const uint4*)(base2 + t0.y);
            uint4 u1 = *(const uint4*)(base2 + t1.y);
            fma8(acc, __uint_as_float(t0.x) * invs, u0);
            fma8(acc, __uint_as_float(t1.x) * invs, u1);
        }
        if (e < deg) {
            uint2 t0 = myal[e];
            uint4 u0 = *(const uint4*)(base2 + t0.y);
            fma8(acc, __uint_as_float(t0.x) * invs, u0);
        }

        size_t idx = (size_t)node * 512 + lane * 8;
        float4 b0 = *(const float4*)(bias + lane * 8);
        float4 b1 = *(const float4*)(bias + lane * 8 + 4);
        float bb[8] = {b0.x, b0.y, b0.z, b0.w, b1.x, b1.y, b1.z, b1.w};
#pragma unroll
        for (int j = 0; j < 8; j++) fin[j] = gelu_f(acc[j] + bb[j]);
        if (dores) {
            uint4 up = *(const uint4*)(hio + idx);
            fin[0] += bf2f(up.x & 0xFFFFu); fin[1] += bf2f_hi(up.x);
            fin[2] += bf2f(up.y & 0xFFFFu); fin[3] += bf2f_hi(up.y);
            fin[4] += bf2f(up.z & 0xFFFFu); fin[5] += bf2f_hi(up.z);
            fin[6] += bf2f(up.w & 0xFFFFu); fin[7] += bf2f_hi(up.w);
        }
        uint4 pk;
        pk.x = (unsigned int)f2bf(fin[0]) | ((unsigned int)f2bf(fin[1]) << 16);
        pk.y = (unsigned int)f2bf(fin[2]) | ((unsigned int)f2bf(fin[3]) << 16);
        pk.z = (unsigned int)f2bf(fin[4]) | ((unsigned int)f2bf(fin[5]) << 16);
        pk.w = (unsigned int)f2bf(fin[6]) | ((unsigned int)f2bf(fin[7]) << 16);
        *(uint4*)(hio + idx) = pk;
#pragma unroll
        for (int j = 0; j < 8; j++) { s += fin[j]; s2 += fin[j] * fin[j]; }
    } else {
        // fallback (deg > 64): per-head 3-pass with max; lane owns channels h*64+lane
        for (int h = 0; h < 8; h++) {
            float adh = ad[h];
            float m = -INFINITY;
            for (int e = beg + lane; e < end; e += 64)
                m = fmaxf(m, lrelu(alsrc[col[e] * 8 + h] + adh));
#pragma unroll
            for (int off = 32; off; off >>= 1) m = fmaxf(m, __shfl_xor(m, off));
            float sum = 0.f;
            for (int e = beg + lane; e < end; e += 64)
                sum += __expf(lrelu(alsrc[col[e] * 8 + h] + adh) - m);
#pragma unroll
            for (int off = 32; off; off >>= 1) sum += __shfl_xor(sum, off);
            float inv = 1.0f / sum;
            float acc = 0.f;
            for (int e = beg; e < end; e++) {
                int src = col[e];
                float alpha = __expf(lrelu(alsrc[src * 8 + h] + adh) - m) * inv;
                acc = fmaf(alpha, bf2f(hlin[((size_t)src << 9) + h * 64 + lane]), acc);
            }
            float fv = gelu_f(acc + bias[h * 64 + lane]);
            size_t idx = (size_t)node * 512 + h * 64 + lane;
            if (dores) fv += bf2f(hio[idx]);
            hio[idx] = f2bf(fv);
            s += fv; s2 += fv * fv;
        }
    }

    // ---- LN stats for the next layer ----
#pragma unroll
    for (int off = 32; off; off >>= 1) {
        s  += __shfl_xor(s, off);
        s2 += __shfl_xor(s2, off);
    }
    if (lane == 0) {
        float mu = s * (1.0f / 512.0f);
        float var = s2 * (1.0f / 512.0f) - mu * mu;
        stats[node * 2 + 0] = mu;
        stats[node * 2 + 1] = rsqrtf(var + EPSV);
    }
}

// ============================ final softmax+aggregate (heads=1, co=3) ============================
__global__ __launch_bounds__(256) void k_aggF(const bf16u* __restrict__ hlin3,
                                              const float* __restrict__ alsrc,
                                              const float* __restrict__ aldst,
                                              const int* __restrict__ rowptr,
                                              const int* __restrict__ col,
                                              const float* __restrict__ bias,
                                              float* __restrict__ outf,
                                              const float* __restrict__ resid, int n) {
    int node = (blockIdx.x * 256 + threadIdx.x) >> 6;
    int lane = threadIdx.x & 63;
    if (node >= n) return;
    int beg = rowptr[node], end = rowptr[node + 1];
    int deg = end - beg;
    float adh = aldst[node];

    if (deg <= 64) {
        int src = 0;
        float ex = 0.f;
        if (lane < deg) {
            src = col[beg + lane];
            ex = __expf(lrelu(alsrc[src] + adh));
        }
        float sum = ex;
#pragma unroll
        for (int off = 32; off; off >>= 1) sum += __shfl_xor(sum, off);
        float alpha = ex / sum;

        float c0 = 0.f, c1 = 0.f, c2 = 0.f;
        if (lane < deg) {
            uint2 u = *(const uint2*)(hlin3 + (size_t)src * 4);
            c0 = alpha * bf2f(u.x & 0xFFFFu);
            c1 = alpha * bf2f_hi(u.x);
            c2 = alpha * bf2f(u.y & 0xFFFFu);
        }
#pragma unroll
        for (int off = 32; off; off >>= 1) {
            c0 += __shfl_xor(c0, off);
            c1 += __shfl_xor(c1, off);
            c2 += __shfl_xor(c2, off);
        }
        if (lane == 0) {
            outf[node * 3 + 0] = c0 + bias[0] + resid[node * 3 + 0];
            outf[node * 3 + 1] = c1 + bias[1] + resid[node * 3 + 1];
            outf[node * 3 + 2] = c2 + bias[2] + resid[node * 3 + 2];
        }
    } else {
        float m = -INFINITY;
        for (int e = beg + lane; e < end; e += 64)
            m = fmaxf(m, lrelu(alsrc[col[e]] + adh));
#pragma unroll
        for (int off = 32; off; off >>= 1) m = fmaxf(m, __shfl_xor(m, off));
        float sum = 0.f;
        for (int e = beg + lane; e < end; e += 64)
            sum += __expf(lrelu(alsrc[col[e]] + adh) - m);
#pragma unroll
        for (int off = 32; off; off >>= 1) sum += __shfl_xor(sum, off);
        float inv = 1.0f / sum;
        float acc = 0.f;
        for (int e = beg; e < end; e++) {
            int src = col[e];
            float alpha = __expf(lrelu(alsrc[src] + adh) - m) * inv;
            if (lane < 3) acc += alpha * bf2f(hlin3[(size_t)src * 4 + lane]);
        }
        if (lane < 3)
            outf[node * 3 + lane] = acc + bias[lane] + resid[node * 3 + lane];
    }
}

// ============================ launch ============================
extern "C" void kernel_launch(void* const* d_in, const int* in_sizes, int n_in,
                              void* d_out, int out_size, void* d_ws, size_t ws_size,
                              hipStream_t stream) {
    const float* x    = (const float*)d_in[0];
    const int*   ei   = (const int*)d_in[1];
    const float* resW = (const float*)d_in[2];
    const float* resb = (const float*)d_in[3];
    const float *lng[4], *lnb[4], *Wm[4], *asr[4], *adt[4], *bias[4];
    int idx = 4;
    for (int i = 0; i < 4; i++) {
        lng[i]  = (const float*)d_in[idx++];
        lnb[i]  = (const float*)d_in[idx++];
        Wm[i]   = (const float*)d_in[idx++];
        asr[i]  = (const float*)d_in[idx++];
        adt[i]  = (const float*)d_in[idx++];
        bias[i] = (const float*)d_in[idx++];
    }

    char* base = (char*)d_ws;
    size_t off = 0;
    auto alloc = [&](size_t bytes) {
        void* p = base + off;
        off += (bytes + 255) & ~(size_t)255;
        return p;
    };
    float* alsrc = (float*)alloc((size_t)NN * 8 * 4);
    float* aldst = (float*)alloc((size_t)NN * 8 * 4);
    float* resid = (float*)alloc((size_t)NN * 3 * 4);
    int* rowptr  = (int*)alloc((size_t)(NN + 1) * 4);
    int* cursor  = (int*)alloc((size_t)NN * 4);
    int* deg     = (int*)alloc((size_t)NN * 4);
    int* colidx  = (int*)alloc((size_t)NE * 4);
    int* bsums   = (int*)alloc(256 * 4);
    bf16u* wg0   = (bf16u*)alloc((size_t)512 * 128 * 2);
    bf16u* wg1   = (bf16u*)alloc((size_t)512 * 512 * 2);
    bf16u* wg2   = (bf16u*)alloc((size_t)512 * 512 * 2);
    float* c1    = (float*)alloc((size_t)3 * 512 * 4);
    float* bW    = (float*)alloc((size_t)3 * 512 * 4);
    float* C1As  = (float*)alloc(24 * 4);
    float* BWAs  = (float*)alloc(24 * 4);
    float* C1Ad  = (float*)alloc(24 * 4);
    float* BWAd  = (float*)alloc(24 * 4);
    float* stats = (float*)alloc((size_t)MPAD * 2 * 4);
    bf16u* xb    = (bf16u*)alloc((size_t)MPAD * 128 * 2);
    bf16u* hbuf  = (bf16u*)alloc((size_t)MPAD * 512 * 2);
    bf16u* lbuf  = (bf16u*)alloc((size_t)MPAD * 512 * 2);
    if (off > ws_size) return;   // smaller than the round-7-proven footprint

    float* out = (float*)d_out;

    // ---- CSR build ----
    k_zero_i32<<<(NN + 255) / 256, 256, 0, stream>>>(deg, NN);
    k_deg<<<(NE + 255) / 256, 256, 0, stream>>>(ei, deg);
    int nb = (NN + 1023) / 1024;
    k_scan1<<<nb, 256, 0, stream>>>(deg, rowptr, bsums, NN);
    k_scan2<<<1, 64, 0, stream>>>(bsums, nb);
    k_scan3<<<(NN + 1 + 255) / 256, 256, 0, stream>>>(deg, rowptr, cursor, bsums, NN, NE);
    k_scatter<<<(NE + 255) / 256, 256, 0, stream>>>(ei, cursor, colidx);

    // ---- prep: scaled weights + affine constants ----
    k_prepw<<<(1536 * 64 + 255) / 256, 256, 0, stream>>>(
        Wm[0], lng[0], lnb[0], wg0,
        Wm[1], lng[1], lnb[1], wg1,
        Wm[2], lng[2], lnb[2], wg2, c1, bW);
    k_prepa<<<6, 256, 0, stream>>>(c1, bW, asr[0], adt[0], asr[1], adt[1],
                                   asr[2], adt[2], C1As, BWAs, C1Ad, BWAd);

    int rowBlocks = (NN * 64 + 255) / 256;       // 12500
    k_castres<<<rowBlocks, 256, 0, stream>>>(x, resW, resb, xb, stats, resid, NN);

    const bf16u* wg[3] = {wg0, wg1, wg2};
    const int ci_a[3] = {128, 512, 512};
    dim3 ggrid(512 / BN, MPAD / BM);    // x = column blocks (4), y = row blocks (391)

    for (int i = 0; i < 3; i++) {
        int dores = (i >= 1) ? 1 : 0;
        const bf16u* ain = (i == 0) ? xb : hbuf;
        k_gemm_sb<<<ggrid, 256, 0, stream>>>(ain, stats, wg[i], c1 + 512 * i, bW + 512 * i,
                                             lbuf, asr[i], adt[i],
                                             C1As + 8 * i, BWAs + 8 * i,
                                             C1Ad + 8 * i, BWAd + 8 * i,
                                             alsrc, aldst, NN, ci_a[i], 512);
        k_aggN2<<<rowBlocks, 256, 0, stream>>>(lbuf, alsrc, aldst, rowptr, colidx,
                                               bias[i], hbuf, stats, NN, dores);
    }
    k_lin3<<<rowBlocks, 256, 0, stream>>>(hbuf, stats, lng[3], lnb[3], Wm[3],
                                          asr[3], adt[3], lbuf, alsrc, aldst, NN);
    k_aggF<<<rowBlocks, 256, 0, stream>>>(lbuf, alsrc, aldst, rowptr, colidx,
                                          bias[3], out, resid, NN);
}

// Round 12
// 618.686 us; speedup vs baseline: 4.8477x; 1.0281x over previous
//
#include <hip/hip_runtime.h>
#include <math.h>

#define NN 50000
#define MPAD 50048          // 391 * 128
#define EE 400000
#define NE 450000           // EE + NN self loops
#define IN_F 128
#define NEG_SLOPE 0.2f
#define EPSV 1e-6f

typedef unsigned short bf16u;
typedef short bf8_t __attribute__((ext_vector_type(8)));
typedef float f32x4 __attribute__((ext_vector_type(4)));

__device__ __forceinline__ float bf2f(unsigned int u) {
    return __uint_as_float(u << 16);
}
__device__ __forceinline__ float bf2f_hi(unsigned int u) {
    return __uint_as_float(u & 0xFFFF0000u);
}
__device__ __forceinline__ bf16u f2bf(float f) {
    unsigned int u = __float_as_uint(f);
    unsigned int r = (u + 0x7FFFu + ((u >> 16) & 1u)) >> 16;
    return (bf16u)r;
}
__device__ __forceinline__ float gelu_f(float v) {
    return 0.5f * v * (1.0f + erff(v * 0.70710678118654752f));
}
__device__ __forceinline__ float lrelu(float v) {
    return fmaxf(v, NEG_SLOPE * v);
}
__device__ __forceinline__ void fma8(float* acc, float a, uint4 u) {
    acc[0] = fmaf(a, bf2f(u.x & 0xFFFFu), acc[0]);
    acc[1] = fmaf(a, bf2f_hi(u.x),        acc[1]);
    acc[2] = fmaf(a, bf2f(u.y & 0xFFFFu), acc[2]);
    acc[3] = fmaf(a, bf2f_hi(u.y),        acc[3]);
    acc[4] = fmaf(a, bf2f(u.z & 0xFFFFu), acc[4]);
    acc[5] = fmaf(a, bf2f_hi(u.z),        acc[5]);
    acc[6] = fmaf(a, bf2f(u.w & 0xFFFFu), acc[6]);
    acc[7] = fmaf(a, bf2f_hi(u.w),        acc[7]);
}

__device__ __forceinline__ void gload_lds16(const void* g, void* l) {
    __builtin_amdgcn_global_load_lds(
        (__attribute__((address_space(1))) void*)(g),
        (__attribute__((address_space(3))) void*)(l), 16, 0, 0);
}

// ============================ CSR build ============================
__global__ void k_zero_i32(int* p, int n) {
    int i = blockIdx.x * 256 + threadIdx.x;
    if (i < n) p[i] = 0;
}

__global__ void k_deg(const int* __restrict__ ei, int* __restrict__ deg) {
    int i = blockIdx.x * 256 + threadIdx.x;
    if (i >= NE) return;
    int d = (i < EE) ? ei[EE + i] : (i - EE);
    atomicAdd(&deg[d], 1);
}

__global__ __launch_bounds__(256) void k_scan1(const int* __restrict__ deg,
                                               int* __restrict__ incl,
                                               int* __restrict__ bsums, int n) {
    __shared__ int sm[1024];
    int base = blockIdx.x * 1024;
    for (int i = threadIdx.x; i < 1024; i += 256)
        sm[i] = (base + i < n) ? deg[base + i] : 0;
    __syncthreads();
    for (int off = 1; off < 1024; off <<= 1) {
        int v[4];
#pragma unroll
        for (int j = 0; j < 4; j++) {
            int i = threadIdx.x + 256 * j;
            v[j] = (i >= off) ? sm[i - off] : 0;
        }
        __syncthreads();
#pragma unroll
        for (int j = 0; j < 4; j++) {
            int i = threadIdx.x + 256 * j;
            sm[i] += v[j];
        }
        __syncthreads();
    }
    for (int i = threadIdx.x; i < 1024; i += 256)
        if (base + i < n) incl[base + i] = sm[i];
    if (threadIdx.x == 0) bsums[blockIdx.x] = sm[1023];
}

__global__ void k_scan2(int* bsums, int nb) {
    if (threadIdx.x == 0 && blockIdx.x == 0) {
        int run = 0;
        for (int i = 0; i < nb; i++) { int v = bsums[i]; bsums[i] = run; run += v; }
    }
}

__global__ void k_scan3(const int* __restrict__ deg, int* __restrict__ rowptr,
                        int* __restrict__ cursor, const int* __restrict__ bsums,
                        int n, int ne) {
    int i = blockIdx.x * 256 + threadIdx.x;
    if (i < n) {
        int excl = rowptr[i] + bsums[i >> 10] - deg[i];
        rowptr[i] = excl;
        cursor[i] = excl;
    }
    if (i == n) rowptr[n] = ne;
}

__global__ void k_scatter(const int* __restrict__ ei, int* __restrict__ cursor,
                          int* __restrict__ col) {
    int i = blockIdx.x * 256 + threadIdx.x;
    if (i >= NE) return;
    int s, d;
    if (i < EE) { s = ei[i]; d = ei[EE + i]; }
    else        { s = i - EE; d = i - EE; }
    int p = atomicAdd(&cursor[d], 1);
    col[p] = s;
}

// ================= prep: Wg = bf16(W*g); c1 = sum(W*g); bW = sum(W*b) =================
__global__ __launch_bounds__(256) void k_prepw(
    const float* __restrict__ W0, const float* __restrict__ g0, const float* __restrict__ b0,
    bf16u* __restrict__ Wg0,
    const float* __restrict__ W1, const float* __restrict__ g1, const float* __restrict__ b1,
    bf16u* __restrict__ Wg1,
    const float* __restrict__ W2, const float* __restrict__ g2, const float* __restrict__ b2,
    bf16u* __restrict__ Wg2,
    float* __restrict__ c1, float* __restrict__ bW) {
    int wid = (blockIdx.x * 256 + threadIdx.x) >> 6;
    int lane = threadIdx.x & 63;
    if (wid >= 1536) return;
    int l = wid >> 9, col = wid & 511;
    const float *W, *g, *b; bf16u* Wg; int ci;
    if (l == 0)      { W = W0; g = g0; b = b0; Wg = Wg0; ci = 128; }
    else if (l == 1) { W = W1; g = g1; b = b1; Wg = Wg1; ci = 512; }
    else             { W = W2; g = g2; b = b2; Wg = Wg2; ci = 512; }
    float sc = 0.f, sb = 0.f;
    for (int k = lane; k < ci; k += 64) {
        float w = W[(size_t)col * ci + k];
        float wg = w * g[k];
        Wg[(size_t)col * ci + k] = f2bf(wg);
        sc += wg;
        sb += w * b[k];
    }
#pragma unroll
    for (int off = 32; off; off >>= 1) {
        sc += __shfl_xor(sc, off);
        sb += __shfl_xor(sb, off);
    }
    if (lane == 0) {
        c1[l * 512 + col] = sc;
        bW[l * 512 + col] = sb;
    }
}

// ===== prep: per-head affine constants for the al dots =====
__global__ __launch_bounds__(256) void k_prepa(
    const float* __restrict__ c1, const float* __restrict__ bW,
    const float* __restrict__ asr0, const float* __restrict__ adt0,
    const float* __restrict__ asr1, const float* __restrict__ adt1,
    const float* __restrict__ asr2, const float* __restrict__ adt2,
    float* __restrict__ C1As, float* __restrict__ BWAs,
    float* __restrict__ C1Ad, float* __restrict__ BWAd) {
    int wid = (blockIdx.x * 256 + threadIdx.x) >> 6;
    int lane = threadIdx.x & 63;
    if (wid >= 24) return;
    int l = wid >> 3, h = wid & 7;
    const float* as = (l == 0) ? asr0 : (l == 1) ? asr1 : asr2;
    const float* ad = (l == 0) ? adt0 : (l == 1) ? adt1 : adt2;
    float c1v = c1[l * 512 + h * 64 + lane];
    float bWv = bW[l * 512 + h * 64 + lane];
    float av = as[h * 64 + lane], dv = ad[h * 64 + lane];
    float s1 = c1v * av, s2 = bWv * av, s3 = c1v * dv, s4 = bWv * dv;
#pragma unroll
    for (int off = 32; off; off >>= 1) {
        s1 += __shfl_xor(s1, off);
        s2 += __shfl_xor(s2, off);
        s3 += __shfl_xor(s3, off);
        s4 += __shfl_xor(s4, off);
    }
    if (lane == 0) {
        C1As[l * 8 + h] = s1;
        BWAs[l * 8 + h] = s2;
        C1Ad[l * 8 + h] = s3;
        BWAd[l * 8 + h] = s4;
    }
}

// ======== cast x -> raw bf16 + LN stats (ci=128) + residual head ========
__global__ __launch_bounds__(256) void k_castres(const float* __restrict__ x,
                                                 const float* __restrict__ rw,
                                                 const float* __restrict__ rb,
                                                 bf16u* __restrict__ xb,
                                                 float* __restrict__ stats,
                                                 float* __restrict__ res, int n) {
    int row = (blockIdx.x * 256 + threadIdx.x) >> 6;
    int lane = threadIdx.x & 63;
    if (row >= n) return;
    float2 v = *(const float2*)(x + (size_t)row * 128 + lane * 2);
    unsigned int pk = (unsigned int)f2bf(v.x) | ((unsigned int)f2bf(v.y) << 16);
    *(unsigned int*)(xb + (size_t)row * 128 + lane * 2) = pk;
    float2 w0 = *(const float2*)(rw + 0 * 128 + lane * 2);
    float2 w1 = *(const float2*)(rw + 1 * 128 + lane * 2);
    float2 w2 = *(const float2*)(rw + 2 * 128 + lane * 2);
    float s = v.x + v.y, s2 = v.x * v.x + v.y * v.y;
    float a0 = v.x * w0.x + v.y * w0.y;
    float a1 = v.x * w1.x + v.y * w1.y;
    float a2 = v.x * w2.x + v.y * w2.y;
#pragma unroll
    for (int off = 32; off; off >>= 1) {
        s  += __shfl_xor(s, off);
        s2 += __shfl_xor(s2, off);
        a0 += __shfl_xor(a0, off);
        a1 += __shfl_xor(a1, off);
        a2 += __shfl_xor(a2, off);
    }
    if (lane == 0) {
        float mu = s * (1.0f / 128.0f);
        float var = s2 * (1.0f / 128.0f) - mu * mu;
        stats[row * 2 + 0] = mu;
        stats[row * 2 + 1] = rsqrtf(var + EPSV);
        res[row * 3 + 0] = a0 + rb[0];
        res[row * 3 + 1] = a1 + rb[1];
        res[row * 3 + 2] = a2 + rb[2];
    }
}

// ============ Single-buffered bf16 MFMA GEMM, LN folded into the epilogue ============
#define BM 128
#define BN 128
#define BK2 64
__global__ __launch_bounds__(256) void k_gemm_sb(const bf16u* __restrict__ A,
                                                 const float* __restrict__ stats,
                                                 const bf16u* __restrict__ Wg,
                                                 const float* __restrict__ c1,
                                                 const float* __restrict__ bW,
                                                 bf16u* __restrict__ C,
                                                 const float* __restrict__ asr,
                                                 const float* __restrict__ adt,
                                                 const float* __restrict__ C1As,
                                                 const float* __restrict__ BWAs,
                                                 const float* __restrict__ C1Ad,
                                                 const float* __restrict__ BWAd,
                                                 float* __restrict__ alsrc,
                                                 float* __restrict__ aldst,
                                                 int Mreal, int ci, int K) {
    __shared__ __align__(16) bf16u As[BM * BK2];
    __shared__ __align__(16) bf16u Bs[BN * BK2];
    const int tid = threadIdx.x;
    const int w = tid >> 6, lane = tid & 63;
    const int row0 = blockIdx.y * BM, col0 = blockIdx.x * BN;
    const int wr = (w >> 1) * 64, wc = (w & 1) * 64;

    const int lrow = lane >> 3;
    const int scolx = ((lane & 7) * 8) ^ (lrow << 3);
    const bf16u* gA = A + (size_t)(row0 + w * 32 + lrow) * ci + scolx;
    const bf16u* gB = Wg + (size_t)(col0 + w * 32 + lrow) * ci + scolx;

    const int nk = ci / BK2;

    f32x4 acc[4][4] = {};
    const int fr = lane & 15;
    const int fk = (lane >> 4) * 8;
    const int fxor = (fr & 7) << 3;

    for (int t = 0; t < nk; t++) {
        if (t) __syncthreads();
        const int k0 = t * BK2;
#pragma unroll
        for (int j = 0; j < 4; j++) {
            gload_lds16(gA + (size_t)(j * 8) * ci + k0, &As[(w * 32 + j * 8) * BK2]);
            gload_lds16(gB + (size_t)(j * 8) * ci + k0, &Bs[(w * 32 + j * 8) * BK2]);
        }
        __syncthreads();
#pragma unroll
        for (int ks = 0; ks < 2; ks++) {
            bf8_t af[4], bfv[4];
#pragma unroll
            for (int m = 0; m < 4; m++)
                af[m] = *(const bf8_t*)&As[(wr + m * 16 + fr) * BK2 + ((ks * 32 + fk) ^ fxor)];
#pragma unroll
            for (int n = 0; n < 4; n++)
                bfv[n] = *(const bf8_t*)&Bs[(wc + n * 16 + fr) * BK2 + ((ks * 32 + fk) ^ fxor)];
#pragma unroll
            for (int m = 0; m < 4; m++)
#pragma unroll
                for (int n = 0; n < 4; n++)
                    acc[m][n] = __builtin_amdgcn_mfma_f32_16x16x32_bf16(af[m], bfv[n], acc[m][n], 0, 0, 0);
        }
    }

    const int fc = lane & 15;
    const int fq = (lane >> 4) * 4;
    const int head = blockIdx.x * 2 + (wc >> 6);

    float c1v[4], bWv[4], av[4], dv[4];
#pragma unroll
    for (int n = 0; n < 4; n++) {
        int col = col0 + wc + n * 16 + fc;
        c1v[n] = c1[col];
        bWv[n] = bW[col];
        av[n] = asr[head * 64 + n * 16 + fc];
        dv[n] = adt[head * 64 + n * 16 + fc];
    }
    const float c1as = C1As[head], bwas = BWAs[head];
    const float c1ad = C1Ad[head], bwad = BWAd[head];

#pragma unroll
    for (int m = 0; m < 4; m++) {
#pragma unroll
        for (int r = 0; r < 4; r++) {
            int row = row0 + wr + m * 16 + fq + r;
            float2 st = *(const float2*)(stats + (size_t)row * 2);
            float rs = st.y;
            float nrm = -rs * st.x;
            if (row < Mreal) {
#pragma unroll
                for (int n = 0; n < 4; n++) {
                    int col = col0 + wc + n * 16 + fc;
                    float val = fmaf(rs, acc[m][n][r], fmaf(nrm, c1v[n], bWv[n]));
                    C[(size_t)row * K + col] = f2bf(val);
                }
            }
            float s1 = acc[m][0][r] * av[0] + acc[m][1][r] * av[1]
                     + acc[m][2][r] * av[2] + acc[m][3][r] * av[3];
            float s2 = acc[m][0][r] * dv[0] + acc[m][1][r] * dv[1]
                     + acc[m][2][r] * dv[2] + acc[m][3][r] * dv[3];
#pragma unroll
            for (int o = 1; o < 16; o <<= 1) {
                s1 += __shfl_xor(s1, o);
                s2 += __shfl_xor(s2, o);
            }
            if (fc == 0 && row < Mreal) {
                alsrc[row * 8 + head] = fmaf(rs, s1, fmaf(nrm, c1as, bwas));
                aldst[row * 8 + head] = fmaf(rs, s2, fmaf(nrm, c1ad, bwad));
            }
        }
    }
}

// ==== layers 0/1: aggregate + epilogue -> writes raw h (hio) + next-layer LN stats ====
__global__ __launch_bounds__(256) void k_aggN2(const bf16u* __restrict__ hlin,
                                               const float* __restrict__ alsrc,
                                               const float* __restrict__ aldst,
                                               const int* __restrict__ rowptr,
                                               const int* __restrict__ col,
                                               const float* __restrict__ bias,
                                               bf16u* __restrict__ hio,
                                               float* __restrict__ stats,
                                               int n, int dores) {
    __shared__ uint2 aldsU[4][8][66];
    int wv = threadIdx.x >> 6;
    int node = (blockIdx.x * 256 + threadIdx.x) >> 6;
    int lane = threadIdx.x & 63;
    if (node >= n) return;
    int beg = rowptr[node], end = rowptr[node + 1];
    int deg = end - beg;

    const float4* dvv = (const float4*)(aldst + node * 8);
    float4 da = dvv[0], db = dvv[1];
    float ad[8] = {da.x, da.y, da.z, da.w, db.x, db.y, db.z, db.w};

    float s = 0.f, s2 = 0.f;
    float fin[8];

    if (deg <= 64) {
        unsigned int offb = 0;
        float ex[8];
        if (lane < deg) {
            int srcreg = col[beg + lane];
            offb = (unsigned int)srcreg << 10;
            const float4* sv = (const float4*)(alsrc + srcreg * 8);
            float4 sa = sv[0], sb = sv[1];
            float sl[8] = {sa.x, sa.y, sa.z, sa.w, sb.x, sb.y, sb.z, sb.w};
#pragma unroll
            for (int h = 0; h < 8; h++) ex[h] = __expf(lrelu(sl[h] + ad[h]));
        } else {
#pragma unroll
            for (int h = 0; h < 8; h++) ex[h] = 0.f;
        }
#pragma unroll
        for (int h = 0; h < 8; h++) {
            uint2 t;
            t.x = __float_as_uint(ex[h]);
            t.y = offb;
            aldsU[wv][h][lane] = t;
        }
        asm volatile("s_waitcnt lgkmcnt(0)" ::: "memory");

        int hl = lane >> 3, s8 = lane & 7;
        const uint2* hrow = &aldsU[wv][hl][0];
        float ps = 0.f;
#pragma unroll
        for (int k2 = 0; k2 < 4; k2++) {
            uint4 q = *(const uint4*)(hrow + s8 * 8 + k2 * 2);
            ps += __uint_as_float(q.x) + __uint_as_float(q.z);
        }
#pragma unroll
        for (int o = 1; o < 8; o <<= 1) ps += __shfl_xor(ps, o);
        float invs = 1.0f / ps;

        const uint2* myal = hrow;
        const char* base2 = (const char*)hlin + (lane << 4);
        float acc[8] = {};
        int e = 0;
        for (; e + 2 <= deg; e += 2) {
            uint2 t0 = myal[e];
            uint2 t1 = myal[e + 1];
            uint4 u0 = *(const uint4*)(base2 + t0.y);
            uint4 u1 = *(const uint4*)(base2 + t1.y);
            fma8(acc, __uint_as_float(t0.x) * invs, u0);
            fma8(acc, __uint_as_float(t1.x) * invs, u1);
        }
        if (e < deg) {
            uint2 t0 = myal[e];
            uint4 u0 = *(const uint4*)(base2 + t0.y);
            fma8(acc, __uint_as_float(t0.x) * invs, u0);
        }

        size_t idx = (size_t)node * 512 + lane * 8;
        float4 b0 = *(const float4*)(bias + lane * 8);
        float4 b1 = *(const float4*)(bias + lane * 8 + 4);
        float bb[8] = {b0.x, b0.y, b0.z, b0.w, b1.x, b1.y, b1.z, b1.w};
#pragma unroll
        for (int j = 0; j < 8; j++) fin[j] = gelu_f(acc[j] + bb[j]);
        if (dores) {
            uint4 up = *(const uint4*)(hio + idx);
            fin[0] += bf2f(up.x & 0xFFFFu); fin[1] += bf2f_hi(up.x);
            fin[2] += bf2f(up.y & 0xFFFFu); fin[3] += bf2f_hi(up.y);
            fin[4] += bf2f(up.z & 0xFFFFu); fin[5] += bf2f_hi(up.z);
            fin[6] += bf2f(up.w & 0xFFFFu); fin[7] += bf2f_hi(up.w);
        }
        uint4 pk;
        pk.x = (unsigned int)f2bf(fin[0]) | ((unsigned int)f2bf(fin[1]) << 16);
        pk.y = (unsigned int)f2bf(fin[2]) | ((unsigned int)f2bf(fin[3]) << 16);
        pk.z = (unsigned int)f2bf(fin[4]) | ((unsigned int)f2bf(fin[5]) << 16);
        pk.w = (unsigned int)f2bf(fin[6]) | ((unsigned int)f2bf(fin[7]) << 16);
        *(uint4*)(hio + idx) = pk;
#pragma unroll
        for (int j = 0; j < 8; j++) { s += fin[j]; s2 += fin[j] * fin[j]; }
    } else {
        for (int h = 0; h < 8; h++) {
            float adh = ad[h];
            float m = -INFINITY;
            for (int e = beg + lane; e < end; e += 64)
                m = fmaxf(m, lrelu(alsrc[col[e] * 8 + h] + adh));
#pragma unroll
            for (int off = 32; off; off >>= 1) m = fmaxf(m, __shfl_xor(m, off));
            float sum = 0.f;
            for (int e = beg + lane; e < end; e += 64)
                sum += __expf(lrelu(alsrc[col[e] * 8 + h] + adh) - m);
#pragma unroll
            for (int off = 32; off; off >>= 1) sum += __shfl_xor(sum, off);
            float inv = 1.0f / sum;
            float acc = 0.f;
            for (int e = beg; e < end; e++) {
                int src = col[e];
                float alpha = __expf(lrelu(alsrc[src * 8 + h] + adh) - m) * inv;
                acc = fmaf(alpha, bf2f(hlin[((size_t)src << 9) + h * 64 + lane]), acc);
            }
            float fv = gelu_f(acc + bias[h * 64 + lane]);
            size_t idx = (size_t)node * 512 + h * 64 + lane;
            if (dores) fv += bf2f(hio[idx]);
            hio[idx] = f2bf(fv);
            s += fv; s2 += fv * fv;
        }
    }

#pragma unroll
    for (int off = 32; off; off >>= 1) {
        s  += __shfl_xor(s, off);
        s2 += __shfl_xor(s2, off);
    }
    if (lane == 0) {
        float mu = s * (1.0f / 512.0f);
        float var = s2 * (1.0f / 512.0f) - mu * mu;
        stats[node * 2 + 0] = mu;
        stats[node * 2 + 1] = rsqrtf(var + EPSV);
    }
}

// ==== layer 2: aggregate + epilogue + FUSED layer-3 LN+matvec+logits ====
// No hio/stats writes; outputs hlin3 (8B/node) + 1-head logits.
__global__ __launch_bounds__(256) void k_aggN3(const bf16u* __restrict__ hlin,
                                               const float* __restrict__ alsrc,
                                               const float* __restrict__ aldst,
                                               const int* __restrict__ rowptr,
                                               const int* __restrict__ col,
                                               const float* __restrict__ bias,
                                               const bf16u* __restrict__ hio,
                                               const float* __restrict__ g3,
                                               const float* __restrict__ b3,
                                               const float* __restrict__ W3,
                                               const float* __restrict__ a_s3,
                                               const float* __restrict__ a_d3,
                                               bf16u* __restrict__ hlin3,
                                               float* __restrict__ alsrc3,
                                               float* __restrict__ aldst3, int n) {
    __shared__ uint2 aldsU[4][8][66];
    int wv = threadIdx.x >> 6;
    int node = (blockIdx.x * 256 + threadIdx.x) >> 6;
    int lane = threadIdx.x & 63;
    if (node >= n) return;
    int beg = rowptr[node], end = rowptr[node + 1];
    int deg = end - beg;

    const float4* dvv = (const float4*)(aldst + node * 8);
    float4 da = dvv[0], db = dvv[1];
    float ad[8] = {da.x, da.y, da.z, da.w, db.x, db.y, db.z, db.w};

    float s = 0.f, s2 = 0.f;
    float fin[8];
    int kbase;   // channel index of fin[0] for this lane

    if (deg <= 64) {
        kbase = lane * 8;
        unsigned int offb = 0;
        float ex[8];
        if (lane < deg) {
            int srcreg = col[beg + lane];
            offb = (unsigned int)srcreg << 10;
            const float4* sv = (const float4*)(alsrc + srcreg * 8);
            float4 sa = sv[0], sb = sv[1];
            float sl[8] = {sa.x, sa.y, sa.z, sa.w, sb.x, sb.y, sb.z, sb.w};
#pragma unroll
            for (int h = 0; h < 8; h++) ex[h] = __expf(lrelu(sl[h] + ad[h]));
        } else {
#pragma unroll
            for (int h = 0; h < 8; h++) ex[h] = 0.f;
        }
#pragma unroll
        for (int h = 0; h < 8; h++) {
            uint2 t;
            t.x = __float_as_uint(ex[h]);
            t.y = offb;
            aldsU[wv][h][lane] = t;
        }
        asm volatile("s_waitcnt lgkmcnt(0)" ::: "memory");

        int hl = lane >> 3, s8 = lane & 7;
        const uint2* hrow = &aldsU[wv][hl][0];
        float ps = 0.f;
#pragma unroll
        for (int k2 = 0; k2 < 4; k2++) {
            uint4 q = *(const uint4*)(hrow + s8 * 8 + k2 * 2);
            ps += __uint_as_float(q.x) + __uint_as_float(q.z);
        }
#pragma unroll
        for (int o = 1; o < 8; o <<= 1) ps += __shfl_xor(ps, o);
        float invs = 1.0f / ps;

        const uint2* myal = hrow;
        const char* base2 = (const char*)hlin + (lane << 4);
        float acc[8] = {};
        int e = 0;
        for (; e + 2 <= deg; e += 2) {
            uint2 t0 = myal[e];
            uint2 t1 = myal[e + 1];
            uint4 u0 = *(const uint4*)(base2 + t0.y);
            uint4 u1 = *(const uint4*)(base2 + t1.y);
            fma8(acc, __uint_as_float(t0.x) * invs, u0);
            fma8(acc, __uint_as_float(t1.x) * invs, u1);
        }
        if (e < deg) {
            uint2 t0 = myal[e];
            uint4 u0 = *(const uint4*)(base2 + t0.y);
            fma8(acc, __uint_as_float(t0.x) * invs, u0);
        }

        size_t idx = (size_t)node * 512 + lane * 8;
        float4 b0 = *(const float4*)(bias + lane * 8);
        float4 b1 = *(const float4*)(bias + lane * 8 + 4);
        float bb[8] = {b0.x, b0.y, b0.z, b0.w, b1.x, b1.y, b1.z, b1.w};
#pragma unroll
        for (int j = 0; j < 8; j++) fin[j] = gelu_f(acc[j] + bb[j]);
        {   // residual (dores always 1 on layer 2)
            uint4 up = *(const uint4*)(hio + idx);
            fin[0] += bf2f(up.x & 0xFFFFu); fin[1] += bf2f_hi(up.x);
            fin[2] += bf2f(up.y & 0xFFFFu); fin[3] += bf2f_hi(up.y);
            fin[4] += bf2f(up.z & 0xFFFFu); fin[5] += bf2f_hi(up.z);
            fin[6] += bf2f(up.w & 0xFFFFu); fin[7] += bf2f_hi(up.w);
        }
#pragma unroll
        for (int j = 0; j < 8; j++) { s += fin[j]; s2 += fin[j] * fin[j]; }
    } else {
        kbase = -1;   // fallback layout: channel = h*64+lane
        for (int h = 0; h < 8; h++) {
            float adh = ad[h];
            float m = -INFINITY;
            for (int e = beg + lane; e < end; e += 64)
                m = fmaxf(m, lrelu(alsrc[col[e] * 8 + h] + adh));
#pragma unroll
            for (int off = 32; off; off >>= 1) m = fmaxf(m, __shfl_xor(m, off));
            float sum = 0.f;
            for (int e = beg + lane; e < end; e += 64)
                sum += __expf(lrelu(alsrc[col[e] * 8 + h] + adh) - m);
#pragma unroll
            for (int off = 32; off; off >>= 1) sum += __shfl_xor(sum, off);
            float inv = 1.0f / sum;
            float acc = 0.f;
            for (int e = beg; e < end; e++) {
                int src = col[e];
                float alpha = __expf(lrelu(alsrc[src * 8 + h] + adh) - m) * inv;
                acc = fmaf(alpha, bf2f(hlin[((size_t)src << 9) + h * 64 + lane]), acc);
            }
            float fv = gelu_f(acc + bias[h * 64 + lane]);
            fv += bf2f(hio[(size_t)node * 512 + h * 64 + lane]);
            fin[h] = fv;
            s += fv; s2 += fv * fv;
        }
    }

    // ---- LN stats across wave ----
#pragma unroll
    for (int off = 32; off; off >>= 1) {
        s  += __shfl_xor(s, off);
        s2 += __shfl_xor(s2, off);
    }
    float mu = s * (1.0f / 512.0f);
    float rs = rsqrtf(s2 * (1.0f / 512.0f) - mu * mu + EPSV);

    // ---- fused layer-3: LN + 512x3 matvec ----
    float a0 = 0.f, a1 = 0.f, a2 = 0.f;
    if (kbase >= 0) {
        float4 g0 = *(const float4*)(g3 + kbase);
        float4 g1 = *(const float4*)(g3 + kbase + 4);
        float4 n0 = *(const float4*)(b3 + kbase);
        float4 n1 = *(const float4*)(b3 + kbase + 4);
        float gg[8] = {g0.x, g0.y, g0.z, g0.w, g1.x, g1.y, g1.z, g1.w};
        float nb[8] = {n0.x, n0.y, n0.z, n0.w, n1.x, n1.y, n1.z, n1.w};
        float4 w00 = *(const float4*)(W3 + kbase);
        float4 w01 = *(const float4*)(W3 + kbase + 4);
        float4 w10 = *(const float4*)(W3 + 512 + kbase);
        float4 w11 = *(const float4*)(W3 + 512 + kbase + 4);
        float4 w20 = *(const float4*)(W3 + 1024 + kbase);
        float4 w21 = *(const float4*)(W3 + 1024 + kbase + 4);
        float wa[8] = {w00.x, w00.y, w00.z, w00.w, w01.x, w01.y, w01.z, w01.w};
        float wbm[8] = {w10.x, w10.y, w10.z, w10.w, w11.x, w11.y, w11.z, w11.w};
        float wcm[8] = {w20.x, w20.y, w20.z, w20.w, w21.x, w21.y, w21.z, w21.w};
#pragma unroll
        for (int j = 0; j < 8; j++) {
            float lnv = fmaf((fin[j] - mu) * rs, gg[j], nb[j]);
            a0 = fmaf(lnv, wa[j], a0);
            a1 = fmaf(lnv, wbm[j], a1);
            a2 = fmaf(lnv, wcm[j], a2);
        }
    } else {
#pragma unroll
        for (int h = 0; h < 8; h++) {
            int k = h * 64 + lane;
            float lnv = fmaf((fin[h] - mu) * rs, g3[k], b3[k]);
            a0 = fmaf(lnv, W3[k], a0);
            a1 = fmaf(lnv, W3[512 + k], a1);
            a2 = fmaf(lnv, W3[1024 + k], a2);
        }
    }
#pragma unroll
    for (int off = 32; off; off >>= 1) {
        a0 += __shfl_xor(a0, off);
        a1 += __shfl_xor(a1, off);
        a2 += __shfl_xor(a2, off);
    }
    if (lane == 0) {
        *(unsigned int*)(hlin3 + (size_t)node * 4) =
            (unsigned int)f2bf(a0) | ((unsigned int)f2bf(a1) << 16);
        *(unsigned int*)(hlin3 + (size_t)node * 4 + 2) = (unsigned int)f2bf(a2);
        alsrc3[node] = a0 * a_s3[0] + a1 * a_s3[1] + a2 * a_s3[2];
        aldst3[node] = a0 * a_d3[0] + a1 * a_d3[1] + a2 * a_d3[2];
    }
}

// ============================ final softmax+aggregate (heads=1, co=3) ============================
__global__ __launch_bounds__(256) void k_aggF(const bf16u* __restrict__ hlin3,
                                              const float* __restrict__ alsrc,
                                              const float* __restrict__ aldst,
                                              const int* __restrict__ rowptr,
                                              const int* __restrict__ col,
                                              const float* __restrict__ bias,
                                              float* __restrict__ outf,
                                              const float* __restrict__ resid, int n) {
    int node = (blockIdx.x * 256 + threadIdx.x) >> 6;
    int lane = threadIdx.x & 63;
    if (node >= n) return;
    int beg = rowptr[node], end = rowptr[node + 1];
    int deg = end - beg;
    float adh = aldst[node];

    if (deg <= 64) {
        int src = 0;
        float ex = 0.f;
        if (lane < deg) {
            src = col[beg + lane];
            ex = __expf(lrelu(alsrc[src] + adh));
        }
        float sum = ex;
#pragma unroll
        for (int off = 32; off; off >>= 1) sum += __shfl_xor(sum, off);
        float alpha = ex / sum;

        float c0 = 0.f, c1 = 0.f, c2 = 0.f;
        if (lane < deg) {
            uint2 u = *(const uint2*)(hlin3 + (size_t)src * 4);
            c0 = alpha * bf2f(u.x & 0xFFFFu);
            c1 = alpha * bf2f_hi(u.x);
            c2 = alpha * bf2f(u.y & 0xFFFFu);
        }
#pragma unroll
        for (int off = 32; off; off >>= 1) {
            c0 += __shfl_xor(c0, off);
            c1 += __shfl_xor(c1, off);
            c2 += __shfl_xor(c2, off);
        }
        if (lane == 0) {
            outf[node * 3 + 0] = c0 + bias[0] + resid[node * 3 + 0];
            outf[node * 3 + 1] = c1 + bias[1] + resid[node * 3 + 1];
            outf[node * 3 + 2] = c2 + bias[2] + resid[node * 3 + 2];
        }
    } else {
        float m = -INFINITY;
        for (int e = beg + lane; e < end; e += 64)
            m = fmaxf(m, lrelu(alsrc[col[e]] + adh));
#pragma unroll
        for (int off = 32; off; off >>= 1) m = fmaxf(m, __shfl_xor(m, off));
        float sum = 0.f;
        for (int e = beg + lane; e < end; e += 64)
            sum += __expf(lrelu(alsrc[col[e]] + adh) - m);
#pragma unroll
        for (int off = 32; off; off >>= 1) sum += __shfl_xor(sum, off);
        float inv = 1.0f / sum;
        float acc = 0.f;
        for (int e = beg; e < end; e++) {
            int src = col[e];
            float alpha = __expf(lrelu(alsrc[src] + adh) - m) * inv;
            if (lane < 3) acc += alpha * bf2f(hlin3[(size_t)src * 4 + lane]);
        }
        if (lane < 3)
            outf[node * 3 + lane] = acc + bias[lane] + resid[node * 3 + lane];
    }
}

// ============================ launch ============================
extern "C" void kernel_launch(void* const* d_in, const int* in_sizes, int n_in,
                              void* d_out, int out_size, void* d_ws, size_t ws_size,
                              hipStream_t stream) {
    const float* x    = (const float*)d_in[0];
    const int*   ei   = (const int*)d_in[1];
    const float* resW = (const float*)d_in[2];
    const float* resb = (const float*)d_in[3];
    const float *lng[4], *lnb[4], *Wm[4], *asr[4], *adt[4], *bias[4];
    int idx = 4;
    for (int i = 0; i < 4; i++) {
        lng[i]  = (const float*)d_in[idx++];
        lnb[i]  = (const float*)d_in[idx++];
        Wm[i]   = (const float*)d_in[idx++];
        asr[i]  = (const float*)d_in[idx++];
        adt[i]  = (const float*)d_in[idx++];
        bias[i] = (const float*)d_in[idx++];
    }

    char* base = (char*)d_ws;
    size_t off = 0;
    auto alloc = [&](size_t bytes) {
        void* p = base + off;
        off += (bytes + 255) & ~(size_t)255;
        return p;
    };
    float* alsrc = (float*)alloc((size_t)NN * 8 * 4);
    float* aldst = (float*)alloc((size_t)NN * 8 * 4);
    float* alsrc3 = (float*)alloc((size_t)NN * 4);
    float* aldst3 = (float*)alloc((size_t)NN * 4);
    float* resid = (float*)alloc((size_t)NN * 3 * 4);
    int* rowptr  = (int*)alloc((size_t)(NN + 1) * 4);
    int* cursor  = (int*)alloc((size_t)NN * 4);
    int* deg     = (int*)alloc((size_t)NN * 4);
    int* colidx  = (int*)alloc((size_t)NE * 4);
    int* bsums   = (int*)alloc(256 * 4);
    bf16u* wg0   = (bf16u*)alloc((size_t)512 * 128 * 2);
    bf16u* wg1   = (bf16u*)alloc((size_t)512 * 512 * 2);
    bf16u* wg2   = (bf16u*)alloc((size_t)512 * 512 * 2);
    float* c1    = (float*)alloc((size_t)3 * 512 * 4);
    float* bW    = (float*)alloc((size_t)3 * 512 * 4);
    float* C1As  = (float*)alloc(24 * 4);
    float* BWAs  = (float*)alloc(24 * 4);
    float* C1Ad  = (float*)alloc(24 * 4);
    float* BWAd  = (float*)alloc(24 * 4);
    float* stats = (float*)alloc((size_t)MPAD * 2 * 4);
    bf16u* xb    = (bf16u*)alloc((size_t)MPAD * 128 * 2);
    bf16u* hlin3 = (bf16u*)alloc((size_t)NN * 4 * 2);
    bf16u* hbuf  = (bf16u*)alloc((size_t)MPAD * 512 * 2);
    bf16u* lbuf  = (bf16u*)alloc((size_t)MPAD * 512 * 2);
    if (off > ws_size) return;

    float* out = (float*)d_out;

    // ---- CSR build ----
    k_zero_i32<<<(NN + 255) / 256, 256, 0, stream>>>(deg, NN);
    k_deg<<<(NE + 255) / 256, 256, 0, stream>>>(ei, deg);
    int nb = (NN + 1023) / 1024;
    k_scan1<<<nb, 256, 0, stream>>>(deg, rowptr, bsums, NN);
    k_scan2<<<1, 64, 0, stream>>>(bsums, nb);
    k_scan3<<<(NN + 1 + 255) / 256, 256, 0, stream>>>(deg, rowptr, cursor, bsums, NN, NE);
    k_scatter<<<(NE + 255) / 256, 256, 0, stream>>>(ei, cursor, colidx);

    // ---- prep: scaled weights + affine constants ----
    k_prepw<<<(1536 * 64 + 255) / 256, 256, 0, stream>>>(
        Wm[0], lng[0], lnb[0], wg0,
        Wm[1], lng[1], lnb[1], wg1,
        Wm[2], lng[2], lnb[2], wg2, c1, bW);
    k_prepa<<<6, 256, 0, stream>>>(c1, bW, asr[0], adt[0], asr[1], adt[1],
                                   asr[2], adt[2], C1As, BWAs, C1Ad, BWAd);

    int rowBlocks = (NN * 64 + 255) / 256;       // 12500
    k_castres<<<rowBlocks, 256, 0, stream>>>(x, resW, resb, xb, stats, resid, NN);

    const bf16u* wg[3] = {wg0, wg1, wg2};
    const int ci_a[3] = {128, 512, 512};
    dim3 ggrid(512 / BN, MPAD / BM);    // x = column blocks (4), y = row blocks (391)

    for (int i = 0; i < 3; i++) {
        const bf16u* ain = (i == 0) ? xb : hbuf;
        k_gemm_sb<<<ggrid, 256, 0, stream>>>(ain, stats, wg[i], c1 + 512 * i, bW + 512 * i,
                                             lbuf, asr[i], adt[i],
                                             C1As + 8 * i, BWAs + 8 * i,
                                             C1Ad + 8 * i, BWAd + 8 * i,
                                             alsrc, aldst, NN, ci_a[i], 512);
        if (i < 2) {
            k_aggN2<<<rowBlocks, 256, 0, stream>>>(lbuf, alsrc, aldst, rowptr, colidx,
                                                   bias[i], hbuf, stats, NN, i >= 1);
        } else {
            k_aggN3<<<rowBlocks, 256, 0, stream>>>(lbuf, alsrc, aldst, rowptr, colidx,
                                                   bias[2], hbuf,
                                                   lng[3], lnb[3], Wm[3],
                                                   asr[3], adt[3],
                                                   hlin3, alsrc3, aldst3, NN);
        }
    }
    k_aggF<<<rowBlocks, 256, 0, stream>>>(hlin3, alsrc3, aldst3, rowptr, colidx,
                                          bias[3], out, resid, NN);
}